// Round 6
// baseline (431.574 us; speedup 1.0000x reference)
//
#include <hip/hip_runtime.h>

typedef unsigned short u16;
typedef unsigned int u32;
typedef u16 u16x4 __attribute__((ext_vector_type(4)));
typedef u16 u16x8 __attribute__((ext_vector_type(8)));
typedef float f32x4 __attribute__((ext_vector_type(4)));
typedef __bf16 bf16x8 __attribute__((ext_vector_type(8)));

#define DEV static __device__ __forceinline__

DEV float bf2f(u16 u) { u32 v = ((u32)u) << 16; float f; __builtin_memcpy(&f, &v, 4); return f; }
DEV u16 f2bf(float f) { u32 v; __builtin_memcpy(&v, &f, 4); v += 0x7fffu + ((v >> 16) & 1u); return (u16)(v >> 16); }
DEV bf16x8 ld_frag(const u16* p) { u16x8 v = *(const u16x8*)p; return __builtin_bit_cast(bf16x8, v); }

#define LOG10000 9.210340372f

// ---------------- elementwise f32 -> bf16 (n = grid*256*8) ----------------
__global__ __launch_bounds__(256) void k_cvt(const float* __restrict__ in, u16* __restrict__ out) {
  size_t i = ((size_t)blockIdx.x * 256 + threadIdx.x) * 8;
  f32x4 a = *(const f32x4*)(in + i);
  f32x4 b = *(const f32x4*)(in + i + 4);
  u16x8 o = { f2bf(a[0]), f2bf(a[1]), f2bf(a[2]), f2bf(a[3]),
              f2bf(b[0]), f2bf(b[1]), f2bf(b[2]), f2bf(b[3]) };
  *(u16x8*)(out + i) = o;
}

// ------- transpose f32 (R,C) -> bf16 (Cp,Rp), zero-padded. grid(Cp/32,Rp/32), block 256 -------
__global__ __launch_bounds__(256) void k_wtrans(const float* __restrict__ in, u16* __restrict__ out,
                                                int R, int C, int Rp) {
  __shared__ float tile[32][33];
  int c0 = blockIdx.x * 32, r0 = blockIdx.y * 32;
  int tx = threadIdx.x & 31, ty = threadIdx.x >> 5;
#pragma unroll
  for (int p = 0; p < 4; p++) {
    int r = r0 + ty + p * 8, c = c0 + tx;
    tile[ty + p * 8][tx] = (r < R && c < C) ? in[(size_t)r * C + c] : 0.f;
  }
  __syncthreads();
#pragma unroll
  for (int p = 0; p < 4; p++)
    out[(size_t)(c0 + ty + p * 8) * Rp + r0 + tx] = f2bf(tile[tx][ty + p * 8]);
}

// ---------------- GEMM: C(M,N) = A(M,K)bf16 * Bt(N,K)bf16, 128x128 tile, 4 waves ----------------
template <int OUT_BF16>
__global__ __launch_bounds__(256) void k_gemm(const u16* __restrict__ A, const u16* __restrict__ Bt,
                                              void* __restrict__ Cv, int M, int N, int K) {
  constexpr int LSTR = 40;
  __shared__ u16 As[128 * LSTR], Bs[128 * LSTR];
  const int tid = threadIdx.x, l = tid & 63, w = tid >> 6;
  const int m0 = blockIdx.y * 128, n0 = blockIdx.x * 128;
  const int wr = (w >> 1) * 64, wc = (w & 1) * 64;
  const int lr = l & 15, lk = (l >> 4) * 8;
  const int sr = tid >> 2, sc = (tid & 3) * 8;
  f32x4 acc[4][4] = {};
  const u16* pa0 = A + (size_t)(m0 + sr) * K + sc;
  const u16* pa1 = A + (size_t)(m0 + 64 + sr) * K + sc;
  const u16* pb0 = Bt + (size_t)(n0 + sr) * K + sc;
  const u16* pb1 = Bt + (size_t)(n0 + 64 + sr) * K + sc;
  u16x8 va0 = *(const u16x8*)pa0, va1 = *(const u16x8*)pa1;
  u16x8 vb0 = *(const u16x8*)pb0, vb1 = *(const u16x8*)pb1;
  for (int k0 = 0; k0 < K; k0 += 32) {
    *(u16x8*)&As[sr * LSTR + sc] = va0;
    *(u16x8*)&As[(64 + sr) * LSTR + sc] = va1;
    *(u16x8*)&Bs[sr * LSTR + sc] = vb0;
    *(u16x8*)&Bs[(64 + sr) * LSTR + sc] = vb1;
    __syncthreads();
    if (k0 + 32 < K) {
      va0 = *(const u16x8*)(pa0 + k0 + 32);
      va1 = *(const u16x8*)(pa1 + k0 + 32);
      vb0 = *(const u16x8*)(pb0 + k0 + 32);
      vb1 = *(const u16x8*)(pb1 + k0 + 32);
    }
    bf16x8 af[4], bf[4];
#pragma unroll
    for (int i = 0; i < 4; i++) af[i] = ld_frag(&As[(wr + i * 16 + lr) * LSTR + lk]);
#pragma unroll
    for (int j = 0; j < 4; j++) bf[j] = ld_frag(&Bs[(wc + j * 16 + lr) * LSTR + lk]);
#pragma unroll
    for (int i = 0; i < 4; i++)
#pragma unroll
      for (int j = 0; j < 4; j++)
        acc[i][j] = __builtin_amdgcn_mfma_f32_16x16x32_bf16(af[i], bf[j], acc[i][j], 0, 0, 0);
    __syncthreads();
  }
#pragma unroll
  for (int i = 0; i < 4; i++)
#pragma unroll
    for (int j = 0; j < 4; j++) {
      int row = m0 + wr + i * 16 + (l >> 4) * 4;
      int col = n0 + wc + j * 16 + lr;
#pragma unroll
      for (int r = 0; r < 4; r++) {
        if (OUT_BF16) ((u16*)Cv)[(size_t)(row + r) * N + col] = f2bf(acc[i][j][r]);
        else          ((float*)Cv)[(size_t)(row + r) * N + col] = acc[i][j][r];
      }
    }
}

// ---------------- GEMM 64x64 tile (for small-N projections; 4x the block parallelism) ----------------
template <int OUT_BF16>
__global__ __launch_bounds__(256) void k_gemm64(const u16* __restrict__ A, const u16* __restrict__ Bt,
                                                void* __restrict__ Cv, int M, int N, int K) {
  constexpr int LSTR = 40;
  __shared__ u16 As[64 * LSTR], Bs[64 * LSTR];
  const int tid = threadIdx.x, l = tid & 63, w = tid >> 6;
  const int m0 = blockIdx.y * 64, n0 = blockIdx.x * 64;
  const int wr = (w >> 1) * 32, wc = (w & 1) * 32;
  const int lr = l & 15, lk = (l >> 4) * 8;
  const int sr = tid >> 2, sc = (tid & 3) * 8;
  f32x4 acc[2][2] = {};
  const u16* pa0 = A + (size_t)(m0 + sr) * K + sc;
  const u16* pb0 = Bt + (size_t)(n0 + sr) * K + sc;
  u16x8 va0 = *(const u16x8*)pa0;
  u16x8 vb0 = *(const u16x8*)pb0;
  for (int k0 = 0; k0 < K; k0 += 32) {
    *(u16x8*)&As[sr * LSTR + sc] = va0;
    *(u16x8*)&Bs[sr * LSTR + sc] = vb0;
    __syncthreads();
    if (k0 + 32 < K) {
      va0 = *(const u16x8*)(pa0 + k0 + 32);
      vb0 = *(const u16x8*)(pb0 + k0 + 32);
    }
    bf16x8 af[2], bf[2];
#pragma unroll
    for (int i = 0; i < 2; i++) af[i] = ld_frag(&As[(wr + i * 16 + lr) * LSTR + lk]);
#pragma unroll
    for (int j = 0; j < 2; j++) bf[j] = ld_frag(&Bs[(wc + j * 16 + lr) * LSTR + lk]);
#pragma unroll
    for (int i = 0; i < 2; i++)
#pragma unroll
      for (int j = 0; j < 2; j++)
        acc[i][j] = __builtin_amdgcn_mfma_f32_16x16x32_bf16(af[i], bf[j], acc[i][j], 0, 0, 0);
    __syncthreads();
  }
#pragma unroll
  for (int i = 0; i < 2; i++)
#pragma unroll
    for (int j = 0; j < 2; j++) {
      int row = m0 + wr + i * 16 + (l >> 4) * 4;
      int col = n0 + wc + j * 16 + lr;
#pragma unroll
      for (int r = 0; r < 4; r++) {
        if (OUT_BF16) ((u16*)Cv)[(size_t)(row + r) * N + col] = f2bf(acc[i][j][r]);
        else          ((float*)Cv)[(size_t)(row + r) * N + col] = acc[i][j][r];
      }
    }
}

// ---------------- kv-down epilogue: rms_norm(16) + rope(64). one wave per row ----------------
__global__ __launch_bounds__(64) void k_kvnorm(const float* __restrict__ ckvf, const float* __restrict__ nw,
                                               const int* __restrict__ pos, u16* __restrict__ ckvn,
                                               u16* __restrict__ kropeb) {
  int row = blockIdx.x, l = threadIdx.x;
  const float* x = ckvf + (size_t)row * 128;
  float v = (l < 16) ? x[l] : 0.f;
  float ss = v * v;
  ss += __shfl_xor(ss, 1); ss += __shfl_xor(ss, 2); ss += __shfl_xor(ss, 4); ss += __shfl_xor(ss, 8);
  if (l < 16) ckvn[(size_t)row * 32 + l] = f2bf(v * rsqrtf(ss * (1.f / 16.f) + 1e-7f) * nw[l]);
  if (l >= 16 && l < 32) ckvn[(size_t)row * 32 + l] = 0;
  if (l < 32) {
    float invf = __expf(-(LOG10000 / 32.f) * (float)l);
    float ang = (float)pos[row] * invf;
    float c = cosf(ang), s = sinf(ang);
    float e = x[16 + 2 * l], o = x[17 + 2 * l];
    kropeb[(size_t)row * 64 + l]      = f2bf(e * c - o * s);
    kropeb[(size_t)row * 64 + l + 32] = f2bf(o * c + e * s);
  }
}

// ---------------- q rms_norm over 256 (scale = 1/sqrt(192) folded in). wave per row ----------------
__global__ __launch_bounds__(256) void k_rms256(const float* __restrict__ in, const float* __restrict__ w,
                                                u16* __restrict__ out, float scale) {
  int row = blockIdx.x * 4 + (threadIdx.x >> 6);
  int l = threadIdx.x & 63;
  const float* x = in + (size_t)row * 256;
  f32x4 v = *(const f32x4*)(x + l * 4);
  float ss = v[0] * v[0] + v[1] * v[1] + v[2] * v[2] + v[3] * v[3];
#pragma unroll
  for (int m = 1; m < 64; m <<= 1) ss += __shfl_xor(ss, m);
  float rinv = rsqrtf(ss * (1.f / 256.f) + 1e-7f) * scale;
  const f32x4 wv = *(const f32x4*)(w + l * 4);
  u16x4 o = { f2bf(v[0] * rinv * wv[0]), f2bf(v[1] * rinv * wv[1]),
              f2bf(v[2] * rinv * wv[2]), f2bf(v[3] * rinv * wv[3]) };
  *(u16x4*)(out + (size_t)row * 256 + l * 4) = o;
}

// ---------------- in-place rope on qproj (B,SQ,H,192): dims 128..191 per head ----------------
__global__ __launch_bounds__(256) void k_qrope(u16* __restrict__ q, const int* __restrict__ pos) {
  __shared__ float cs[32], sn[32];
  int bs = blockIdx.x, tid = threadIdx.x;
  if (tid < 32) {
    float invf = __expf(-(LOG10000 / 32.f) * (float)tid);
    float ang = (float)pos[bs] * invf;
    cs[tid] = cosf(ang); sn[tid] = sinf(ang);
  }
  __syncthreads();
  u16* base = q + (size_t)bs * 3072;
  int h0 = tid >> 5, p0 = tid & 31;
  int h1 = h0 + 8, p1 = p0;
  u16* r0p = base + h0 * 192 + 128;
  u16* r1p = base + h1 * 192 + 128;
  float e0 = bf2f(r0p[2 * p0]), o0 = bf2f(r0p[2 * p0 + 1]);
  float e1 = bf2f(r1p[2 * p1]), o1 = bf2f(r1p[2 * p1 + 1]);
  __syncthreads();
  r0p[p0]      = f2bf(e0 * cs[p0] - o0 * sn[p0]);
  r0p[p0 + 32] = f2bf(o0 * cs[p0] + e0 * sn[p0]);
  r1p[p1]      = f2bf(e1 * cs[p1] - o1 * sn[p1]);
  r1p[p1 + 32] = f2bf(o1 * cs[p1] + e1 * sn[p1]);
}

// ---------------- V^T extraction: Ckv(B*SKV, H*256)[.,h*256+128..] -> VT(BH,128,SKV) ----------------
__global__ void k_vt(const u16* __restrict__ Ckv, u16* __restrict__ VT) {
  __shared__ u16 tile[32][40];
  int bh = blockIdx.z, b = bh >> 4, h = bh & 15;
  int d0 = blockIdx.x * 32, s0 = blockIdx.y * 32;
  int tx = threadIdx.x, ty = threadIdx.y;
  const u16* src = Ckv + ((size_t)(b * 2048 + s0)) * 4096 + h * 256 + 128 + d0;
#pragma unroll
  for (int p = 0; p < 4; p++) tile[ty + p * 8][tx] = src[(size_t)(ty + p * 8) * 4096 + tx];
  __syncthreads();
  u16* dst = VT + ((size_t)bh * 128 + d0) * 2048 + s0;
#pragma unroll
  for (int p = 0; p < 4; p++) dst[(size_t)(ty + p * 8) * 2048 + tx] = tile[tx][ty + p * 8];
}

// ---- fused attention v6: 128 q-rows/block, 4 waves x 32 rows, shared K/V frag reads ----
// Each LDS fragment read feeds TWO MFMAs (2 A-frags per wave) -> halves LDS read traffic per FLOP.
__global__ __launch_bounds__(256, 2) void k_attn(const u16* __restrict__ Qp, const u16* __restrict__ Ckv,
                                                 const u16* __restrict__ kropeb, const u16* __restrict__ VT,
                                                 u16* __restrict__ AO) {
  __shared__ u16 Ks[64 * 192];   // 24KB, XOR-swizzled
  __shared__ u16 Vs[128 * 64];   // 16KB, d-major, XOR-swizzled
  __shared__ u16 Ps[128 * 64];   // 16KB: per-wave 32-row strip (same-wave write->read)
  const int tid = threadIdx.x, l = tid & 63, w = tid >> 6;
  const int lr = l & 15, h4 = l >> 4, lk = h4 * 8;
  const int bid = blockIdx.x, bh = bid & 31, qt = bid >> 5;  // bh%8 fixes XCD for K/V L2 reuse
  const int b = bh >> 4, hh = bh & 15;
  const int m0 = qt * 128;
  const u32 swz = (u32)(lr & 7) << 3;  // read-side swizzle (row&7 == lr&7 for all frag reads)

  // Q fragments: wave w owns q-rows m0 + w*32 .. +31 (2 groups of 16)
  bf16x8 qa[2][6];
#pragma unroll
  for (int g = 0; g < 2; g++) {
    const u16* qrow = Qp + (size_t)(b * 2048 + m0 + w * 32 + g * 16 + lr) * 3072 + hh * 192;
#pragma unroll
    for (int kk = 0; kk < 6; kk++) qa[g][kk] = ld_frag(qrow + kk * 32 + lk);
  }

  // staging: K = 64x192 (6 chunks/thread @256), V = 128x64 d-major (4 chunks/thread)
  const u16* kptr[6]; int kstep[6]; u32 klds[6];
#pragma unroll
  for (int p = 0; p < 6; p++) {
    int c2 = tid + p * 256;
    int r = c2 / 24, cc = c2 - r * 24;
    klds[p] = (u32)(r * 192 + cc * 8) ^ ((u32)(r & 7) << 3);
    if (cc < 16) { kptr[p] = Ckv + ((size_t)(b * 2048 + r)) * 4096 + hh * 256 + cc * 8; kstep[p] = 64 * 4096; }
    else         { kptr[p] = kropeb + ((size_t)(b * 2048 + r)) * 64 + (cc - 16) * 8;    kstep[p] = 64 * 64; }
  }
  const u16* vptr[4]; u32 vlds[4];
#pragma unroll
  for (int p = 0; p < 4; p++) {
    int c2 = tid + p * 256;
    int d = c2 >> 3, cc = c2 & 7;
    vlds[p] = (u32)(d * 64 + cc * 8) ^ ((u32)(d & 7) << 3);
    vptr[p] = VT + ((size_t)bh * 128 + d) * 2048 + cc * 8;
  }
  u16x8 kreg[6], vreg[4];
#pragma unroll
  for (int p = 0; p < 6; p++) { kreg[p] = *(const u16x8*)kptr[p]; kptr[p] += kstep[p]; }
#pragma unroll
  for (int p = 0; p < 4; p++) { vreg[p] = *(const u16x8*)vptr[p]; vptr[p] += 64; }

  f32x4 oacc[2][8] = {};
  float lsum[2][4] = {};
  const int odd = l & 1;

  for (int t = 0; t < 32; t++) {
    // write staged regs -> LDS (vmcnt wait auto-inserted for in-flight prefetch)
#pragma unroll
    for (int p = 0; p < 6; p++) *(u16x8*)&Ks[klds[p]] = kreg[p];
#pragma unroll
    for (int p = 0; p < 4; p++) *(u16x8*)&Vs[vlds[p]] = vreg[p];
    __syncthreads();
    if (t + 1 < 32) {  // issue next-tile loads; latency hides under compute below
#pragma unroll
      for (int p = 0; p < 6; p++) { kreg[p] = *(const u16x8*)kptr[p]; kptr[p] += kstep[p]; }
#pragma unroll
      for (int p = 0; p < 4; p++) { vreg[p] = *(const u16x8*)vptr[p]; vptr[p] += 64; }
    }
    // S = Q * K^T: each K frag read shared by both A-frags
    f32x4 sacc[2][4] = {};
    __builtin_amdgcn_s_setprio(1);
#pragma unroll
    for (int n = 0; n < 4; n++)
#pragma unroll
      for (int kk = 0; kk < 6; kk++) {
        bf16x8 kb = ld_frag(&Ks[(u32)((n * 16 + lr) * 192 + kk * 32 + lk) ^ swz]);
        sacc[0][n] = __builtin_amdgcn_mfma_f32_16x16x32_bf16(qa[0][kk], kb, sacc[0][n], 0, 0, 0);
        sacc[1][n] = __builtin_amdgcn_mfma_f32_16x16x32_bf16(qa[1][kk], kb, sacc[1][n], 0, 0, 0);
      }
    __builtin_amdgcn_s_setprio(0);
    // P = exp(S): packed u32 writes, adjacent cols paired via one shfl_xor
#pragma unroll
    for (int g = 0; g < 2; g++) {
      const int prow = w * 32 + g * 16 + 4 * h4;
#pragma unroll
      for (int n = 0; n < 4; n++) {
        float o0 = __expf(sacc[g][n][0]), o1 = __expf(sacc[g][n][1]),
              o2 = __expf(sacc[g][n][2]), o3 = __expf(sacc[g][n][3]);
        lsum[g][0] += o0; lsum[g][1] += o1; lsum[g][2] += o2; lsum[g][3] += o3;
        float p0 = __shfl_xor(o0, 1), p1 = __shfl_xor(o1, 1),
              p2 = __shfl_xor(o2, 1), p3 = __shfl_xor(o3, 1);
        float lo0 = odd ? p2 : o0, hi0 = odd ? o2 : p0;
        float lo1 = odd ? p3 : o1, hi1 = odd ? o3 : p1;
        int r0 = odd ? 2 : 0;
        u32 w0 = (u32)f2bf(lo0) | ((u32)f2bf(hi0) << 16);
        u32 w1 = (u32)f2bf(lo1) | ((u32)f2bf(hi1) << 16);
        int col = n * 16 + (lr & ~1);
        int row0 = prow + r0, row1 = prow + r0 + 1;
        *(u32*)&Ps[(u32)(row0 * 64 + col) ^ ((u32)(row0 & 7) << 3)] = w0;
        *(u32*)&Ps[(u32)(row1 * 64 + col) ^ ((u32)(row1 & 7) << 3)] = w1;
      }
    }
    // O += P * V: each V frag read shared by both P rows-groups (same-wave P write->read in-order)
    __builtin_amdgcn_s_setprio(1);
#pragma unroll
    for (int kk = 0; kk < 2; kk++) {
      bf16x8 pa0 = ld_frag(&Ps[(u32)((w * 32 + lr) * 64 + kk * 32 + lk) ^ swz]);
      bf16x8 pa1 = ld_frag(&Ps[(u32)((w * 32 + 16 + lr) * 64 + kk * 32 + lk) ^ swz]);
#pragma unroll
      for (int n2 = 0; n2 < 8; n2++) {
        bf16x8 vb = ld_frag(&Vs[(u32)((n2 * 16 + lr) * 64 + kk * 32 + lk) ^ swz]);
        oacc[0][n2] = __builtin_amdgcn_mfma_f32_16x16x32_bf16(pa0, vb, oacc[0][n2], 0, 0, 0);
        oacc[1][n2] = __builtin_amdgcn_mfma_f32_16x16x32_bf16(pa1, vb, oacc[1][n2], 0, 0, 0);
      }
    }
    __builtin_amdgcn_s_setprio(0);
    __syncthreads();
  }
  // epilogue: deferred row-sum reduce (over the 16 lr lanes), then normalize + store
#pragma unroll
  for (int g = 0; g < 2; g++) {
    float rl[4];
#pragma unroll
    for (int r = 0; r < 4; r++) {
      float s = lsum[g][r];
      s += __shfl_xor(s, 1); s += __shfl_xor(s, 2); s += __shfl_xor(s, 4); s += __shfl_xor(s, 8);
      rl[r] = 1.f / s;
    }
#pragma unroll
    for (int n2 = 0; n2 < 8; n2++)
#pragma unroll
      for (int r = 0; r < 4; r++) {
        int row = m0 + w * 32 + g * 16 + h4 * 4 + r;
        AO[((size_t)(b * 2048 + row) * 16 + hh) * 128 + n2 * 16 + lr] = f2bf(oacc[g][n2][r] * rl[r]);
      }
  }
}

extern "C" void kernel_launch(void* const* d_in, const int* in_sizes, int n_in,
                              void* d_out, int out_size, void* d_ws, size_t ws_size,
                              hipStream_t stream) {
  const float* q_in  = (const float*)d_in[0];
  const float* kv_in = (const float*)d_in[1];
  const int*   qpos  = (const int*)d_in[2];
  const int*   kpos  = (const int*)d_in[3];
  const float* Wqd   = (const float*)d_in[4];
  const float* qnw   = (const float*)d_in[5];
  const float* Wqu   = (const float*)d_in[6];
  const float* Wkvd  = (const float*)d_in[7];
  const float* kvnw  = (const float*)d_in[8];
  const float* Wkvu  = (const float*)d_in[9];
  const float* Wo    = (const float*)d_in[10];
  float* out = (float*)d_out;
  char* ws = (char*)d_ws;
  size_t off = 0;
  auto alloc = [&](size_t bytes) -> void* {
    void* p = ws + off; off += (bytes + 255) & ~(size_t)255; return p;
  };
  u16*   Aq     = (u16*)alloc(4096ull * 1024 * 2);
  u16*   Akv    = (u16*)alloc(4096ull * 1024 * 2);
  u16*   WqdT   = (u16*)alloc(256ull * 1024 * 2);
  u16*   WquT   = (u16*)alloc(3072ull * 256 * 2);
  u16*   WkvdT  = (u16*)alloc(128ull * 1024 * 2);
  u16*   WkvuT  = (u16*)alloc(4096ull * 32 * 2);
  u16*   WoT    = (u16*)alloc(1024ull * 2048 * 2);
  float* ckvf   = (float*)alloc(4096ull * 128 * 4);
  u16*   ckvn   = (u16*)alloc(4096ull * 32 * 2);
  u16*   kropeb = (u16*)alloc(4096ull * 64 * 2);
  u16*   Ckv    = (u16*)alloc(4096ull * 4096 * 2);
  u16*   VTb    = (u16*)alloc(32ull * 128 * 2048 * 2);
  float* cq     = (float*)alloc(4096ull * 256 * 4);
  u16*   cqn    = (u16*)alloc(4096ull * 256 * 2);
  u16*   qproj  = (u16*)alloc(4096ull * 3072 * 2);
  u16*   AOb    = (u16*)alloc(4096ull * 2048 * 2);
  (void)in_sizes; (void)n_in; (void)out_size; (void)ws_size;

  k_cvt<<<2048, 256, 0, stream>>>(q_in, Aq);
  k_cvt<<<2048, 256, 0, stream>>>(kv_in, Akv);
  k_wtrans<<<dim3(8, 32), 256, 0, stream>>>(Wqd, WqdT, 1024, 256, 1024);
  k_wtrans<<<dim3(96, 8), 256, 0, stream>>>(Wqu, WquT, 256, 3072, 256);
  k_wtrans<<<dim3(4, 32), 256, 0, stream>>>(Wkvd, WkvdT, 1024, 80, 1024);
  k_wtrans<<<dim3(128, 1), 256, 0, stream>>>(Wkvu, WkvuT, 16, 4096, 32);
  k_wtrans<<<dim3(32, 64), 256, 0, stream>>>(Wo, WoT, 2048, 1024, 2048);
  // kv path (64x64-tile GEMM: 128 blocks instead of 32)
  k_gemm64<0><<<dim3(2, 64), 256, 0, stream>>>(Akv, WkvdT, ckvf, 4096, 128, 1024);
  k_kvnorm<<<4096, 64, 0, stream>>>(ckvf, kvnw, kpos, ckvn, kropeb);
  k_gemm<1><<<dim3(32, 32), 256, 0, stream>>>(ckvn, WkvuT, Ckv, 4096, 4096, 32);
  k_vt<<<dim3(4, 64, 32), dim3(32, 8), 0, stream>>>(Ckv, VTb);
  // q path (64x64-tile GEMM: 256 blocks instead of 64)
  k_gemm64<0><<<dim3(4, 64), 256, 0, stream>>>(Aq, WqdT, cq, 4096, 256, 1024);
  k_rms256<<<1024, 256, 0, stream>>>(cq, qnw, cqn, 0.07216878364870322f);
  k_gemm<1><<<dim3(24, 32), 256, 0, stream>>>(cqn, WquT, qproj, 4096, 3072, 256);
  k_qrope<<<4096, 256, 0, stream>>>(qproj, qpos);
  // attention (256-thread blocks: 4 waves x 32 q-rows, shared frag reads)
  k_attn<<<512, 256, 0, stream>>>(qproj, Ckv, kropeb, VTb, AOb);
  // output projection
  k_gemm<0><<<dim3(8, 32), 256, 0, stream>>>(AOb, WoT, out, 4096, 1024, 2048);
}

// Round 7
// 328.768 us; speedup vs baseline: 1.3127x; 1.3127x over previous
//
#include <hip/hip_runtime.h>

typedef unsigned short u16;
typedef unsigned int u32;
typedef u16 u16x4 __attribute__((ext_vector_type(4)));
typedef u16 u16x8 __attribute__((ext_vector_type(8)));
typedef float f32x4 __attribute__((ext_vector_type(4)));
typedef __bf16 bf16x8 __attribute__((ext_vector_type(8)));

#define DEV static __device__ __forceinline__

DEV float bf2f(u16 u) { u32 v = ((u32)u) << 16; float f; __builtin_memcpy(&f, &v, 4); return f; }
DEV u16 f2bf(float f) { u32 v; __builtin_memcpy(&v, &f, 4); v += 0x7fffu + ((v >> 16) & 1u); return (u16)(v >> 16); }
DEV bf16x8 ld_frag(const u16* p) { u16x8 v = *(const u16x8*)p; return __builtin_bit_cast(bf16x8, v); }

#define LOG10000 9.210340372f

// ---------------- elementwise f32 -> bf16 (n = grid*256*8) ----------------
__global__ __launch_bounds__(256) void k_cvt(const float* __restrict__ in, u16* __restrict__ out) {
  size_t i = ((size_t)blockIdx.x * 256 + threadIdx.x) * 8;
  f32x4 a = *(const f32x4*)(in + i);
  f32x4 b = *(const f32x4*)(in + i + 4);
  u16x8 o = { f2bf(a[0]), f2bf(a[1]), f2bf(a[2]), f2bf(a[3]),
              f2bf(b[0]), f2bf(b[1]), f2bf(b[2]), f2bf(b[3]) };
  *(u16x8*)(out + i) = o;
}

// ------- transpose f32 (R,C) -> bf16 (Cp,Rp), zero-padded. grid(Cp/32,Rp/32), block 256 -------
__global__ __launch_bounds__(256) void k_wtrans(const float* __restrict__ in, u16* __restrict__ out,
                                                int R, int C, int Rp) {
  __shared__ float tile[32][33];
  int c0 = blockIdx.x * 32, r0 = blockIdx.y * 32;
  int tx = threadIdx.x & 31, ty = threadIdx.x >> 5;
#pragma unroll
  for (int p = 0; p < 4; p++) {
    int r = r0 + ty + p * 8, c = c0 + tx;
    tile[ty + p * 8][tx] = (r < R && c < C) ? in[(size_t)r * C + c] : 0.f;
  }
  __syncthreads();
#pragma unroll
  for (int p = 0; p < 4; p++)
    out[(size_t)(c0 + ty + p * 8) * Rp + r0 + tx] = f2bf(tile[tx][ty + p * 8]);
}

// ---------------- GEMM: C(M,N) = A(M,K)bf16 * Bt(N,K)bf16, 128x128 tile, 4 waves ----------------
template <int OUT_BF16>
__global__ __launch_bounds__(256) void k_gemm(const u16* __restrict__ A, const u16* __restrict__ Bt,
                                              void* __restrict__ Cv, int M, int N, int K) {
  constexpr int LSTR = 40;
  __shared__ u16 As[128 * LSTR], Bs[128 * LSTR];
  const int tid = threadIdx.x, l = tid & 63, w = tid >> 6;
  const int m0 = blockIdx.y * 128, n0 = blockIdx.x * 128;
  const int wr = (w >> 1) * 64, wc = (w & 1) * 64;
  const int lr = l & 15, lk = (l >> 4) * 8;
  const int sr = tid >> 2, sc = (tid & 3) * 8;
  f32x4 acc[4][4] = {};
  const u16* pa0 = A + (size_t)(m0 + sr) * K + sc;
  const u16* pa1 = A + (size_t)(m0 + 64 + sr) * K + sc;
  const u16* pb0 = Bt + (size_t)(n0 + sr) * K + sc;
  const u16* pb1 = Bt + (size_t)(n0 + 64 + sr) * K + sc;
  u16x8 va0 = *(const u16x8*)pa0, va1 = *(const u16x8*)pa1;
  u16x8 vb0 = *(const u16x8*)pb0, vb1 = *(const u16x8*)pb1;
  for (int k0 = 0; k0 < K; k0 += 32) {
    *(u16x8*)&As[sr * LSTR + sc] = va0;
    *(u16x8*)&As[(64 + sr) * LSTR + sc] = va1;
    *(u16x8*)&Bs[sr * LSTR + sc] = vb0;
    *(u16x8*)&Bs[(64 + sr) * LSTR + sc] = vb1;
    __syncthreads();
    if (k0 + 32 < K) {
      va0 = *(const u16x8*)(pa0 + k0 + 32);
      va1 = *(const u16x8*)(pa1 + k0 + 32);
      vb0 = *(const u16x8*)(pb0 + k0 + 32);
      vb1 = *(const u16x8*)(pb1 + k0 + 32);
    }
    bf16x8 af[4], bf[4];
#pragma unroll
    for (int i = 0; i < 4; i++) af[i] = ld_frag(&As[(wr + i * 16 + lr) * LSTR + lk]);
#pragma unroll
    for (int j = 0; j < 4; j++) bf[j] = ld_frag(&Bs[(wc + j * 16 + lr) * LSTR + lk]);
#pragma unroll
    for (int i = 0; i < 4; i++)
#pragma unroll
      for (int j = 0; j < 4; j++)
        acc[i][j] = __builtin_amdgcn_mfma_f32_16x16x32_bf16(af[i], bf[j], acc[i][j], 0, 0, 0);
    __syncthreads();
  }
#pragma unroll
  for (int i = 0; i < 4; i++)
#pragma unroll
    for (int j = 0; j < 4; j++) {
      int row = m0 + wr + i * 16 + (l >> 4) * 4;
      int col = n0 + wc + j * 16 + lr;
#pragma unroll
      for (int r = 0; r < 4; r++) {
        if (OUT_BF16) ((u16*)Cv)[(size_t)(row + r) * N + col] = f2bf(acc[i][j][r]);
        else          ((float*)Cv)[(size_t)(row + r) * N + col] = acc[i][j][r];
      }
    }
}

// ---------------- GEMM 64x64 tile (for small-N projections; 4x the block parallelism) ----------------
template <int OUT_BF16>
__global__ __launch_bounds__(256) void k_gemm64(const u16* __restrict__ A, const u16* __restrict__ Bt,
                                                void* __restrict__ Cv, int M, int N, int K) {
  constexpr int LSTR = 40;
  __shared__ u16 As[64 * LSTR], Bs[64 * LSTR];
  const int tid = threadIdx.x, l = tid & 63, w = tid >> 6;
  const int m0 = blockIdx.y * 64, n0 = blockIdx.x * 64;
  const int wr = (w >> 1) * 32, wc = (w & 1) * 32;
  const int lr = l & 15, lk = (l >> 4) * 8;
  const int sr = tid >> 2, sc = (tid & 3) * 8;
  f32x4 acc[2][2] = {};
  const u16* pa0 = A + (size_t)(m0 + sr) * K + sc;
  const u16* pb0 = Bt + (size_t)(n0 + sr) * K + sc;
  u16x8 va0 = *(const u16x8*)pa0;
  u16x8 vb0 = *(const u16x8*)pb0;
  for (int k0 = 0; k0 < K; k0 += 32) {
    *(u16x8*)&As[sr * LSTR + sc] = va0;
    *(u16x8*)&Bs[sr * LSTR + sc] = vb0;
    __syncthreads();
    if (k0 + 32 < K) {
      va0 = *(const u16x8*)(pa0 + k0 + 32);
      vb0 = *(const u16x8*)(pb0 + k0 + 32);
    }
    bf16x8 af[2], bf[2];
#pragma unroll
    for (int i = 0; i < 2; i++) af[i] = ld_frag(&As[(wr + i * 16 + lr) * LSTR + lk]);
#pragma unroll
    for (int j = 0; j < 2; j++) bf[j] = ld_frag(&Bs[(wc + j * 16 + lr) * LSTR + lk]);
#pragma unroll
    for (int i = 0; i < 2; i++)
#pragma unroll
      for (int j = 0; j < 2; j++)
        acc[i][j] = __builtin_amdgcn_mfma_f32_16x16x32_bf16(af[i], bf[j], acc[i][j], 0, 0, 0);
    __syncthreads();
  }
#pragma unroll
  for (int i = 0; i < 2; i++)
#pragma unroll
    for (int j = 0; j < 2; j++) {
      int row = m0 + wr + i * 16 + (l >> 4) * 4;
      int col = n0 + wc + j * 16 + lr;
#pragma unroll
      for (int r = 0; r < 4; r++) {
        if (OUT_BF16) ((u16*)Cv)[(size_t)(row + r) * N + col] = f2bf(acc[i][j][r]);
        else          ((float*)Cv)[(size_t)(row + r) * N + col] = acc[i][j][r];
      }
    }
}

// ---------------- kv-down epilogue: rms_norm(16) + rope(64). one wave per row ----------------
__global__ __launch_bounds__(64) void k_kvnorm(const float* __restrict__ ckvf, const float* __restrict__ nw,
                                               const int* __restrict__ pos, u16* __restrict__ ckvn,
                                               u16* __restrict__ kropeb) {
  int row = blockIdx.x, l = threadIdx.x;
  const float* x = ckvf + (size_t)row * 128;
  float v = (l < 16) ? x[l] : 0.f;
  float ss = v * v;
  ss += __shfl_xor(ss, 1); ss += __shfl_xor(ss, 2); ss += __shfl_xor(ss, 4); ss += __shfl_xor(ss, 8);
  if (l < 16) ckvn[(size_t)row * 32 + l] = f2bf(v * rsqrtf(ss * (1.f / 16.f) + 1e-7f) * nw[l]);
  if (l >= 16 && l < 32) ckvn[(size_t)row * 32 + l] = 0;
  if (l < 32) {
    float invf = __expf(-(LOG10000 / 32.f) * (float)l);
    float ang = (float)pos[row] * invf;
    float c = cosf(ang), s = sinf(ang);
    float e = x[16 + 2 * l], o = x[17 + 2 * l];
    kropeb[(size_t)row * 64 + l]      = f2bf(e * c - o * s);
    kropeb[(size_t)row * 64 + l + 32] = f2bf(o * c + e * s);
  }
}

// ---------------- q rms_norm over 256 (scale = 1/sqrt(192) folded in). wave per row ----------------
__global__ __launch_bounds__(256) void k_rms256(const float* __restrict__ in, const float* __restrict__ w,
                                                u16* __restrict__ out, float scale) {
  int row = blockIdx.x * 4 + (threadIdx.x >> 6);
  int l = threadIdx.x & 63;
  const float* x = in + (size_t)row * 256;
  f32x4 v = *(const f32x4*)(x + l * 4);
  float ss = v[0] * v[0] + v[1] * v[1] + v[2] * v[2] + v[3] * v[3];
#pragma unroll
  for (int m = 1; m < 64; m <<= 1) ss += __shfl_xor(ss, m);
  float rinv = rsqrtf(ss * (1.f / 256.f) + 1e-7f) * scale;
  const f32x4 wv = *(const f32x4*)(w + l * 4);
  u16x4 o = { f2bf(v[0] * rinv * wv[0]), f2bf(v[1] * rinv * wv[1]),
              f2bf(v[2] * rinv * wv[2]), f2bf(v[3] * rinv * wv[3]) };
  *(u16x4*)(out + (size_t)row * 256 + l * 4) = o;
}

// ---------------- in-place rope on qproj (B,SQ,H,192): dims 128..191 per head ----------------
__global__ __launch_bounds__(256) void k_qrope(u16* __restrict__ q, const int* __restrict__ pos) {
  __shared__ float cs[32], sn[32];
  int bs = blockIdx.x, tid = threadIdx.x;
  if (tid < 32) {
    float invf = __expf(-(LOG10000 / 32.f) * (float)tid);
    float ang = (float)pos[bs] * invf;
    cs[tid] = cosf(ang); sn[tid] = sinf(ang);
  }
  __syncthreads();
  u16* base = q + (size_t)bs * 3072;
  int h0 = tid >> 5, p0 = tid & 31;
  int h1 = h0 + 8, p1 = p0;
  u16* r0p = base + h0 * 192 + 128;
  u16* r1p = base + h1 * 192 + 128;
  float e0 = bf2f(r0p[2 * p0]), o0 = bf2f(r0p[2 * p0 + 1]);
  float e1 = bf2f(r1p[2 * p1]), o1 = bf2f(r1p[2 * p1 + 1]);
  __syncthreads();
  r0p[p0]      = f2bf(e0 * cs[p0] - o0 * sn[p0]);
  r0p[p0 + 32] = f2bf(o0 * cs[p0] + e0 * sn[p0]);
  r1p[p1]      = f2bf(e1 * cs[p1] - o1 * sn[p1]);
  r1p[p1 + 32] = f2bf(o1 * cs[p1] + e1 * sn[p1]);
}

// ---------------- V^T extraction: Ckv(B*SKV, H*256)[.,h*256+128..] -> VT(BH,128,SKV) ----------------
__global__ void k_vt(const u16* __restrict__ Ckv, u16* __restrict__ VT) {
  __shared__ u16 tile[32][40];
  int bh = blockIdx.z, b = bh >> 4, h = bh & 15;
  int d0 = blockIdx.x * 32, s0 = blockIdx.y * 32;
  int tx = threadIdx.x, ty = threadIdx.y;
  const u16* src = Ckv + ((size_t)(b * 2048 + s0)) * 4096 + h * 256 + 128 + d0;
#pragma unroll
  for (int p = 0; p < 4; p++) tile[ty + p * 8][tx] = src[(size_t)(ty + p * 8) * 4096 + tx];
  __syncthreads();
  u16* dst = VT + ((size_t)bh * 128 + d0) * 2048 + s0;
#pragma unroll
  for (int p = 0; p < 4; p++) dst[(size_t)(ty + p * 8) * 2048 + tx] = tile[tx][ty + p * 8];
}

// ---- fused attention v7: R6 body + __launch_bounds__(256,1) to lift the 128-VGPR clamp ----
// 4 waves x 32 rows, shared K/V frag reads (each LDS frag feeds 2 MFMAs). ~230 VGPR natural,
// 2 waves/SIMD by VGPR, 2 blocks/CU by LDS (56KB) -- same residency as v5, half the LDS reads.
__global__ __launch_bounds__(256, 1) void k_attn(const u16* __restrict__ Qp, const u16* __restrict__ Ckv,
                                                 const u16* __restrict__ kropeb, const u16* __restrict__ VT,
                                                 u16* __restrict__ AO) {
  __shared__ u16 Ks[64 * 192];   // 24KB, XOR-swizzled
  __shared__ u16 Vs[128 * 64];   // 16KB, d-major, XOR-swizzled
  __shared__ u16 Ps[128 * 64];   // 16KB: per-wave 32-row strip (same-wave write->read)
  const int tid = threadIdx.x, l = tid & 63, w = tid >> 6;
  const int lr = l & 15, h4 = l >> 4, lk = h4 * 8;
  const int bid = blockIdx.x, bh = bid & 31, qt = bid >> 5;  // bh%8 fixes XCD for K/V L2 reuse
  const int b = bh >> 4, hh = bh & 15;
  const int m0 = qt * 128;
  const u32 swz = (u32)(lr & 7) << 3;  // read-side swizzle (row&7 == lr&7 for all frag reads)

  // Q fragments: wave w owns q-rows m0 + w*32 .. +31 (2 groups of 16)
  bf16x8 qa[2][6];
#pragma unroll
  for (int g = 0; g < 2; g++) {
    const u16* qrow = Qp + (size_t)(b * 2048 + m0 + w * 32 + g * 16 + lr) * 3072 + hh * 192;
#pragma unroll
    for (int kk = 0; kk < 6; kk++) qa[g][kk] = ld_frag(qrow + kk * 32 + lk);
  }

  // staging: K = 64x192 (6 chunks/thread @256), V = 128x64 d-major (4 chunks/thread)
  const u16* kptr[6]; int kstep[6]; u32 klds[6];
#pragma unroll
  for (int p = 0; p < 6; p++) {
    int c2 = tid + p * 256;
    int r = c2 / 24, cc = c2 - r * 24;
    klds[p] = (u32)(r * 192 + cc * 8) ^ ((u32)(r & 7) << 3);
    if (cc < 16) { kptr[p] = Ckv + ((size_t)(b * 2048 + r)) * 4096 + hh * 256 + cc * 8; kstep[p] = 64 * 4096; }
    else         { kptr[p] = kropeb + ((size_t)(b * 2048 + r)) * 64 + (cc - 16) * 8;    kstep[p] = 64 * 64; }
  }
  const u16* vptr[4]; u32 vlds[4];
#pragma unroll
  for (int p = 0; p < 4; p++) {
    int c2 = tid + p * 256;
    int d = c2 >> 3, cc = c2 & 7;
    vlds[p] = (u32)(d * 64 + cc * 8) ^ ((u32)(d & 7) << 3);
    vptr[p] = VT + ((size_t)bh * 128 + d) * 2048 + cc * 8;
  }
  u16x8 kreg[6], vreg[4];
#pragma unroll
  for (int p = 0; p < 6; p++) { kreg[p] = *(const u16x8*)kptr[p]; kptr[p] += kstep[p]; }
#pragma unroll
  for (int p = 0; p < 4; p++) { vreg[p] = *(const u16x8*)vptr[p]; vptr[p] += 64; }

  f32x4 oacc[2][8] = {};
  float lsum[2][4] = {};
  const int odd = l & 1;

  for (int t = 0; t < 32; t++) {
    // write staged regs -> LDS (vmcnt wait auto-inserted for in-flight prefetch)
#pragma unroll
    for (int p = 0; p < 6; p++) *(u16x8*)&Ks[klds[p]] = kreg[p];
#pragma unroll
    for (int p = 0; p < 4; p++) *(u16x8*)&Vs[vlds[p]] = vreg[p];
    __syncthreads();
    if (t + 1 < 32) {  // issue next-tile loads; latency hides under compute below
#pragma unroll
      for (int p = 0; p < 6; p++) { kreg[p] = *(const u16x8*)kptr[p]; kptr[p] += kstep[p]; }
#pragma unroll
      for (int p = 0; p < 4; p++) { vreg[p] = *(const u16x8*)vptr[p]; vptr[p] += 64; }
    }
    // S = Q * K^T: each K frag read shared by both A-frags
    f32x4 sacc[2][4] = {};
    __builtin_amdgcn_s_setprio(1);
#pragma unroll
    for (int n = 0; n < 4; n++)
#pragma unroll
      for (int kk = 0; kk < 6; kk++) {
        bf16x8 kb = ld_frag(&Ks[(u32)((n * 16 + lr) * 192 + kk * 32 + lk) ^ swz]);
        sacc[0][n] = __builtin_amdgcn_mfma_f32_16x16x32_bf16(qa[0][kk], kb, sacc[0][n], 0, 0, 0);
        sacc[1][n] = __builtin_amdgcn_mfma_f32_16x16x32_bf16(qa[1][kk], kb, sacc[1][n], 0, 0, 0);
      }
    __builtin_amdgcn_s_setprio(0);
    // P = exp(S): packed u32 writes, adjacent cols paired via one shfl_xor
#pragma unroll
    for (int g = 0; g < 2; g++) {
      const int prow = w * 32 + g * 16 + 4 * h4;
#pragma unroll
      for (int n = 0; n < 4; n++) {
        float o0 = __expf(sacc[g][n][0]), o1 = __expf(sacc[g][n][1]),
              o2 = __expf(sacc[g][n][2]), o3 = __expf(sacc[g][n][3]);
        lsum[g][0] += o0; lsum[g][1] += o1; lsum[g][2] += o2; lsum[g][3] += o3;
        float p0 = __shfl_xor(o0, 1), p1 = __shfl_xor(o1, 1),
              p2 = __shfl_xor(o2, 1), p3 = __shfl_xor(o3, 1);
        float lo0 = odd ? p2 : o0, hi0 = odd ? o2 : p0;
        float lo1 = odd ? p3 : o1, hi1 = odd ? o3 : p1;
        int r0 = odd ? 2 : 0;
        u32 w0 = (u32)f2bf(lo0) | ((u32)f2bf(hi0) << 16);
        u32 w1 = (u32)f2bf(lo1) | ((u32)f2bf(hi1) << 16);
        int col = n * 16 + (lr & ~1);
        int row0 = prow + r0, row1 = prow + r0 + 1;
        *(u32*)&Ps[(u32)(row0 * 64 + col) ^ ((u32)(row0 & 7) << 3)] = w0;
        *(u32*)&Ps[(u32)(row1 * 64 + col) ^ ((u32)(row1 & 7) << 3)] = w1;
      }
    }
    // O += P * V: each V frag read shared by both P rows-groups (same-wave P write->read in-order)
    __builtin_amdgcn_s_setprio(1);
#pragma unroll
    for (int kk = 0; kk < 2; kk++) {
      bf16x8 pa0 = ld_frag(&Ps[(u32)((w * 32 + lr) * 64 + kk * 32 + lk) ^ swz]);
      bf16x8 pa1 = ld_frag(&Ps[(u32)((w * 32 + 16 + lr) * 64 + kk * 32 + lk) ^ swz]);
#pragma unroll
      for (int n2 = 0; n2 < 8; n2++) {
        bf16x8 vb = ld_frag(&Vs[(u32)((n2 * 16 + lr) * 64 + kk * 32 + lk) ^ swz]);
        oacc[0][n2] = __builtin_amdgcn_mfma_f32_16x16x32_bf16(pa0, vb, oacc[0][n2], 0, 0, 0);
        oacc[1][n2] = __builtin_amdgcn_mfma_f32_16x16x32_bf16(pa1, vb, oacc[1][n2], 0, 0, 0);
      }
    }
    __builtin_amdgcn_s_setprio(0);
    __syncthreads();
  }
  // epilogue: deferred row-sum reduce (over the 16 lr lanes), then normalize + store
#pragma unroll
  for (int g = 0; g < 2; g++) {
    float rl[4];
#pragma unroll
    for (int r = 0; r < 4; r++) {
      float s = lsum[g][r];
      s += __shfl_xor(s, 1); s += __shfl_xor(s, 2); s += __shfl_xor(s, 4); s += __shfl_xor(s, 8);
      rl[r] = 1.f / s;
    }
#pragma unroll
    for (int n2 = 0; n2 < 8; n2++)
#pragma unroll
      for (int r = 0; r < 4; r++) {
        int row = m0 + w * 32 + g * 16 + h4 * 4 + r;
        AO[((size_t)(b * 2048 + row) * 16 + hh) * 128 + n2 * 16 + lr] = f2bf(oacc[g][n2][r] * rl[r]);
      }
  }
}

extern "C" void kernel_launch(void* const* d_in, const int* in_sizes, int n_in,
                              void* d_out, int out_size, void* d_ws, size_t ws_size,
                              hipStream_t stream) {
  const float* q_in  = (const float*)d_in[0];
  const float* kv_in = (const float*)d_in[1];
  const int*   qpos  = (const int*)d_in[2];
  const int*   kpos  = (const int*)d_in[3];
  const float* Wqd   = (const float*)d_in[4];
  const float* qnw   = (const float*)d_in[5];
  const float* Wqu   = (const float*)d_in[6];
  const float* Wkvd  = (const float*)d_in[7];
  const float* kvnw  = (const float*)d_in[8];
  const float* Wkvu  = (const float*)d_in[9];
  const float* Wo    = (const float*)d_in[10];
  float* out = (float*)d_out;
  char* ws = (char*)d_ws;
  size_t off = 0;
  auto alloc = [&](size_t bytes) -> void* {
    void* p = ws + off; off += (bytes + 255) & ~(size_t)255; return p;
  };
  u16*   Aq     = (u16*)alloc(4096ull * 1024 * 2);
  u16*   Akv    = (u16*)alloc(4096ull * 1024 * 2);
  u16*   WqdT   = (u16*)alloc(256ull * 1024 * 2);
  u16*   WquT   = (u16*)alloc(3072ull * 256 * 2);
  u16*   WkvdT  = (u16*)alloc(128ull * 1024 * 2);
  u16*   WkvuT  = (u16*)alloc(4096ull * 32 * 2);
  u16*   WoT    = (u16*)alloc(1024ull * 2048 * 2);
  float* ckvf   = (float*)alloc(4096ull * 128 * 4);
  u16*   ckvn   = (u16*)alloc(4096ull * 32 * 2);
  u16*   kropeb = (u16*)alloc(4096ull * 64 * 2);
  u16*   Ckv    = (u16*)alloc(4096ull * 4096 * 2);
  u16*   VTb    = (u16*)alloc(32ull * 128 * 2048 * 2);
  float* cq     = (float*)alloc(4096ull * 256 * 4);
  u16*   cqn    = (u16*)alloc(4096ull * 256 * 2);
  u16*   qproj  = (u16*)alloc(4096ull * 3072 * 2);
  u16*   AOb    = (u16*)alloc(4096ull * 2048 * 2);
  (void)in_sizes; (void)n_in; (void)out_size; (void)ws_size;

  k_cvt<<<2048, 256, 0, stream>>>(q_in, Aq);
  k_cvt<<<2048, 256, 0, stream>>>(kv_in, Akv);
  k_wtrans<<<dim3(8, 32), 256, 0, stream>>>(Wqd, WqdT, 1024, 256, 1024);
  k_wtrans<<<dim3(96, 8), 256, 0, stream>>>(Wqu, WquT, 256, 3072, 256);
  k_wtrans<<<dim3(4, 32), 256, 0, stream>>>(Wkvd, WkvdT, 1024, 80, 1024);
  k_wtrans<<<dim3(128, 1), 256, 0, stream>>>(Wkvu, WkvuT, 16, 4096, 32);
  k_wtrans<<<dim3(32, 64), 256, 0, stream>>>(Wo, WoT, 2048, 1024, 2048);
  // kv path (64x64-tile GEMM: 128 blocks instead of 32)
  k_gemm64<0><<<dim3(2, 64), 256, 0, stream>>>(Akv, WkvdT, ckvf, 4096, 128, 1024);
  k_kvnorm<<<4096, 64, 0, stream>>>(ckvf, kvnw, kpos, ckvn, kropeb);
  k_gemm<1><<<dim3(32, 32), 256, 0, stream>>>(ckvn, WkvuT, Ckv, 4096, 4096, 32);
  k_vt<<<dim3(4, 64, 32), dim3(32, 8), 0, stream>>>(Ckv, VTb);
  // q path (64x64-tile GEMM: 256 blocks instead of 64)
  k_gemm64<0><<<dim3(4, 64), 256, 0, stream>>>(Aq, WqdT, cq, 4096, 256, 1024);
  k_rms256<<<1024, 256, 0, stream>>>(cq, qnw, cqn, 0.07216878364870322f);
  k_gemm<1><<<dim3(24, 32), 256, 0, stream>>>(cqn, WquT, qproj, 4096, 3072, 256);
  k_qrope<<<4096, 256, 0, stream>>>(qproj, qpos);
  // attention (256-thread blocks: 4 waves x 32 q-rows, shared frag reads, VGPR cap lifted)
  k_attn<<<512, 256, 0, stream>>>(qproj, Ckv, kropeb, VTb, AOb);
  // output projection
  k_gemm<0><<<dim3(8, 32), 256, 0, stream>>>(AOb, WoT, out, 4096, 1024, 2048);
}

// Round 8
// 275.550 us; speedup vs baseline: 1.5662x; 1.1931x over previous
//
#include <hip/hip_runtime.h>

typedef unsigned short u16;
typedef unsigned int u32;
typedef u16 u16x4 __attribute__((ext_vector_type(4)));
typedef u16 u16x8 __attribute__((ext_vector_type(8)));
typedef float f32x4 __attribute__((ext_vector_type(4)));
typedef __bf16 bf16x8 __attribute__((ext_vector_type(8)));

#define DEV static __device__ __forceinline__

DEV float bf2f(u16 u) { u32 v = ((u32)u) << 16; float f; __builtin_memcpy(&f, &v, 4); return f; }
DEV u16 f2bf(float f) { u32 v; __builtin_memcpy(&v, &f, 4); v += 0x7fffu + ((v >> 16) & 1u); return (u16)(v >> 16); }
DEV bf16x8 ld_frag(const u16* p) { u16x8 v = *(const u16x8*)p; return __builtin_bit_cast(bf16x8, v); }

#define LOG10000 9.210340372f

// ---------------- elementwise f32 -> bf16 (n = grid*256*8) ----------------
__global__ __launch_bounds__(256) void k_cvt(const float* __restrict__ in, u16* __restrict__ out) {
  size_t i = ((size_t)blockIdx.x * 256 + threadIdx.x) * 8;
  f32x4 a = *(const f32x4*)(in + i);
  f32x4 b = *(const f32x4*)(in + i + 4);
  u16x8 o = { f2bf(a[0]), f2bf(a[1]), f2bf(a[2]), f2bf(a[3]),
              f2bf(b[0]), f2bf(b[1]), f2bf(b[2]), f2bf(b[3]) };
  *(u16x8*)(out + i) = o;
}

// ------- transpose f32 (R,C) -> bf16 (Cp,Rp), zero-padded. grid(Cp/32,Rp/32), block 256 -------
__global__ __launch_bounds__(256) void k_wtrans(const float* __restrict__ in, u16* __restrict__ out,
                                                int R, int C, int Rp) {
  __shared__ float tile[32][33];
  int c0 = blockIdx.x * 32, r0 = blockIdx.y * 32;
  int tx = threadIdx.x & 31, ty = threadIdx.x >> 5;
#pragma unroll
  for (int p = 0; p < 4; p++) {
    int r = r0 + ty + p * 8, c = c0 + tx;
    tile[ty + p * 8][tx] = (r < R && c < C) ? in[(size_t)r * C + c] : 0.f;
  }
  __syncthreads();
#pragma unroll
  for (int p = 0; p < 4; p++)
    out[(size_t)(c0 + ty + p * 8) * Rp + r0 + tx] = f2bf(tile[tx][ty + p * 8]);
}

// ---------------- GEMM: C(M,N) = A(M,K)bf16 * Bt(N,K)bf16, 128x128 tile, 4 waves ----------------
// XCD-chunked bid swizzle (grids are %8==0): each XCD gets contiguous row-major chunk -> A-strip L2 reuse.
template <int OUT_BF16>
__global__ __launch_bounds__(256) void k_gemm(const u16* __restrict__ A, const u16* __restrict__ Bt,
                                              void* __restrict__ Cv, int M, int N, int K) {
  constexpr int LSTR = 40;
  __shared__ u16 As[128 * LSTR], Bs[128 * LSTR];
  const int tid = threadIdx.x, l = tid & 63, w = tid >> 6;
  const int nwg = gridDim.x * gridDim.y;
  const int lin = blockIdx.y * gridDim.x + blockIdx.x;
  const int swzb = (lin & 7) * (nwg >> 3) + (lin >> 3);
  const int m0 = (swzb / gridDim.x) * 128, n0 = (swzb % gridDim.x) * 128;
  const int wr = (w >> 1) * 64, wc = (w & 1) * 64;
  const int lr = l & 15, lk = (l >> 4) * 8;
  const int sr = tid >> 2, sc = (tid & 3) * 8;
  f32x4 acc[4][4] = {};
  const u16* pa0 = A + (size_t)(m0 + sr) * K + sc;
  const u16* pa1 = A + (size_t)(m0 + 64 + sr) * K + sc;
  const u16* pb0 = Bt + (size_t)(n0 + sr) * K + sc;
  const u16* pb1 = Bt + (size_t)(n0 + 64 + sr) * K + sc;
  u16x8 va0 = *(const u16x8*)pa0, va1 = *(const u16x8*)pa1;
  u16x8 vb0 = *(const u16x8*)pb0, vb1 = *(const u16x8*)pb1;
  for (int k0 = 0; k0 < K; k0 += 32) {
    *(u16x8*)&As[sr * LSTR + sc] = va0;
    *(u16x8*)&As[(64 + sr) * LSTR + sc] = va1;
    *(u16x8*)&Bs[sr * LSTR + sc] = vb0;
    *(u16x8*)&Bs[(64 + sr) * LSTR + sc] = vb1;
    __syncthreads();
    if (k0 + 32 < K) {
      va0 = *(const u16x8*)(pa0 + k0 + 32);
      va1 = *(const u16x8*)(pa1 + k0 + 32);
      vb0 = *(const u16x8*)(pb0 + k0 + 32);
      vb1 = *(const u16x8*)(pb1 + k0 + 32);
    }
    bf16x8 af[4], bf[4];
#pragma unroll
    for (int i = 0; i < 4; i++) af[i] = ld_frag(&As[(wr + i * 16 + lr) * LSTR + lk]);
#pragma unroll
    for (int j = 0; j < 4; j++) bf[j] = ld_frag(&Bs[(wc + j * 16 + lr) * LSTR + lk]);
#pragma unroll
    for (int i = 0; i < 4; i++)
#pragma unroll
      for (int j = 0; j < 4; j++)
        acc[i][j] = __builtin_amdgcn_mfma_f32_16x16x32_bf16(af[i], bf[j], acc[i][j], 0, 0, 0);
    __syncthreads();
  }
#pragma unroll
  for (int i = 0; i < 4; i++)
#pragma unroll
    for (int j = 0; j < 4; j++) {
      int row = m0 + wr + i * 16 + (l >> 4) * 4;
      int col = n0 + wc + j * 16 + lr;
#pragma unroll
      for (int r = 0; r < 4; r++) {
        if (OUT_BF16) ((u16*)Cv)[(size_t)(row + r) * N + col] = f2bf(acc[i][j][r]);
        else          ((float*)Cv)[(size_t)(row + r) * N + col] = acc[i][j][r];
      }
    }
}

// ---------------- GEMM 64x64 tile (for small-N projections; 4x the block parallelism) ----------------
template <int OUT_BF16>
__global__ __launch_bounds__(256) void k_gemm64(const u16* __restrict__ A, const u16* __restrict__ Bt,
                                                void* __restrict__ Cv, int M, int N, int K) {
  constexpr int LSTR = 40;
  __shared__ u16 As[64 * LSTR], Bs[64 * LSTR];
  const int tid = threadIdx.x, l = tid & 63, w = tid >> 6;
  const int nwg = gridDim.x * gridDim.y;
  const int lin = blockIdx.y * gridDim.x + blockIdx.x;
  const int swzb = (lin & 7) * (nwg >> 3) + (lin >> 3);
  const int m0 = (swzb / gridDim.x) * 64, n0 = (swzb % gridDim.x) * 64;
  const int wr = (w >> 1) * 32, wc = (w & 1) * 32;
  const int lr = l & 15, lk = (l >> 4) * 8;
  const int sr = tid >> 2, sc = (tid & 3) * 8;
  f32x4 acc[2][2] = {};
  const u16* pa0 = A + (size_t)(m0 + sr) * K + sc;
  const u16* pb0 = Bt + (size_t)(n0 + sr) * K + sc;
  u16x8 va0 = *(const u16x8*)pa0;
  u16x8 vb0 = *(const u16x8*)pb0;
  for (int k0 = 0; k0 < K; k0 += 32) {
    *(u16x8*)&As[sr * LSTR + sc] = va0;
    *(u16x8*)&Bs[sr * LSTR + sc] = vb0;
    __syncthreads();
    if (k0 + 32 < K) {
      va0 = *(const u16x8*)(pa0 + k0 + 32);
      vb0 = *(const u16x8*)(pb0 + k0 + 32);
    }
    bf16x8 af[2], bf[2];
#pragma unroll
    for (int i = 0; i < 2; i++) af[i] = ld_frag(&As[(wr + i * 16 + lr) * LSTR + lk]);
#pragma unroll
    for (int j = 0; j < 2; j++) bf[j] = ld_frag(&Bs[(wc + j * 16 + lr) * LSTR + lk]);
#pragma unroll
    for (int i = 0; i < 2; i++)
#pragma unroll
      for (int j = 0; j < 2; j++)
        acc[i][j] = __builtin_amdgcn_mfma_f32_16x16x32_bf16(af[i], bf[j], acc[i][j], 0, 0, 0);
    __syncthreads();
  }
#pragma unroll
  for (int i = 0; i < 2; i++)
#pragma unroll
    for (int j = 0; j < 2; j++) {
      int row = m0 + wr + i * 16 + (l >> 4) * 4;
      int col = n0 + wc + j * 16 + lr;
#pragma unroll
      for (int r = 0; r < 4; r++) {
        if (OUT_BF16) ((u16*)Cv)[(size_t)(row + r) * N + col] = f2bf(acc[i][j][r]);
        else          ((float*)Cv)[(size_t)(row + r) * N + col] = acc[i][j][r];
      }
    }
}

// ---------------- kv-down epilogue: rms_norm(16) + rope(64). one wave per row ----------------
__global__ __launch_bounds__(64) void k_kvnorm(const float* __restrict__ ckvf, const float* __restrict__ nw,
                                               const int* __restrict__ pos, u16* __restrict__ ckvn,
                                               u16* __restrict__ kropeb) {
  int row = blockIdx.x, l = threadIdx.x;
  const float* x = ckvf + (size_t)row * 128;
  float v = (l < 16) ? x[l] : 0.f;
  float ss = v * v;
  ss += __shfl_xor(ss, 1); ss += __shfl_xor(ss, 2); ss += __shfl_xor(ss, 4); ss += __shfl_xor(ss, 8);
  if (l < 16) ckvn[(size_t)row * 32 + l] = f2bf(v * rsqrtf(ss * (1.f / 16.f) + 1e-7f) * nw[l]);
  if (l >= 16 && l < 32) ckvn[(size_t)row * 32 + l] = 0;
  if (l < 32) {
    float invf = __expf(-(LOG10000 / 32.f) * (float)l);
    float ang = (float)pos[row] * invf;
    float c = cosf(ang), s = sinf(ang);
    float e = x[16 + 2 * l], o = x[17 + 2 * l];
    kropeb[(size_t)row * 64 + l]      = f2bf(e * c - o * s);
    kropeb[(size_t)row * 64 + l + 32] = f2bf(o * c + e * s);
  }
}

// ---------------- q rms_norm over 256 (scale = log2(e)/sqrt(192) folded in). wave per row ----------------
__global__ __launch_bounds__(256) void k_rms256(const float* __restrict__ in, const float* __restrict__ w,
                                                u16* __restrict__ out, float scale) {
  int row = blockIdx.x * 4 + (threadIdx.x >> 6);
  int l = threadIdx.x & 63;
  const float* x = in + (size_t)row * 256;
  f32x4 v = *(const f32x4*)(x + l * 4);
  float ss = v[0] * v[0] + v[1] * v[1] + v[2] * v[2] + v[3] * v[3];
#pragma unroll
  for (int m = 1; m < 64; m <<= 1) ss += __shfl_xor(ss, m);
  float rinv = rsqrtf(ss * (1.f / 256.f) + 1e-7f) * scale;
  const f32x4 wv = *(const f32x4*)(w + l * 4);
  u16x4 o = { f2bf(v[0] * rinv * wv[0]), f2bf(v[1] * rinv * wv[1]),
              f2bf(v[2] * rinv * wv[2]), f2bf(v[3] * rinv * wv[3]) };
  *(u16x4*)(out + (size_t)row * 256 + l * 4) = o;
}

// ---------------- in-place rope on qproj (B,SQ,H,192): dims 128..191 per head ----------------
__global__ __launch_bounds__(256) void k_qrope(u16* __restrict__ q, const int* __restrict__ pos) {
  __shared__ float cs[32], sn[32];
  int bs = blockIdx.x, tid = threadIdx.x;
  if (tid < 32) {
    float invf = __expf(-(LOG10000 / 32.f) * (float)tid);
    float ang = (float)pos[bs] * invf;
    cs[tid] = cosf(ang); sn[tid] = sinf(ang);
  }
  __syncthreads();
  u16* base = q + (size_t)bs * 3072;
  int h0 = tid >> 5, p0 = tid & 31;
  int h1 = h0 + 8, p1 = p0;
  u16* r0p = base + h0 * 192 + 128;
  u16* r1p = base + h1 * 192 + 128;
  float e0 = bf2f(r0p[2 * p0]), o0 = bf2f(r0p[2 * p0 + 1]);
  float e1 = bf2f(r1p[2 * p1]), o1 = bf2f(r1p[2 * p1 + 1]);
  __syncthreads();
  r0p[p0]      = f2bf(e0 * cs[p0] - o0 * sn[p0]);
  r0p[p0 + 32] = f2bf(o0 * cs[p0] + e0 * sn[p0]);
  r1p[p1]      = f2bf(e1 * cs[p1] - o1 * sn[p1]);
  r1p[p1 + 32] = f2bf(o1 * cs[p1] + e1 * sn[p1]);
}

// ---------------- V^T extraction: Ckv(B*SKV, H*256)[.,h*256+128..] -> VT(BH,128,SKV) ----------------
__global__ void k_vt(const u16* __restrict__ Ckv, u16* __restrict__ VT) {
  __shared__ u16 tile[32][40];
  int bh = blockIdx.z, b = bh >> 4, h = bh & 15;
  int d0 = blockIdx.x * 32, s0 = blockIdx.y * 32;
  int tx = threadIdx.x, ty = threadIdx.y;
  const u16* src = Ckv + ((size_t)(b * 2048 + s0)) * 4096 + h * 256 + 128 + d0;
#pragma unroll
  for (int p = 0; p < 4; p++) tile[ty + p * 8][tx] = src[(size_t)(ty + p * 8) * 4096 + tx];
  __syncthreads();
  u16* dst = VT + ((size_t)bh * 128 + d0) * 2048 + s0;
#pragma unroll
  for (int p = 0; p < 4; p++) dst[(size_t)(ty + p * 8) * 2048 + tx] = tile[tx][ty + p * 8];
}

// ---- fused attention v8 (= v5 structure, best measured): 128 q-rows/block, 8 waves x 16 rows ----
// 96 VGPR -> 4 waves/SIMD; 2 blocks/CU x 8 waves = 16 waves/CU. exp2 (log2e folded into q scale).
__global__ __launch_bounds__(512, 2) void k_attn(const u16* __restrict__ Qp, const u16* __restrict__ Ckv,
                                                 const u16* __restrict__ kropeb, const u16* __restrict__ VT,
                                                 u16* __restrict__ AO) {
  __shared__ u16 Ks[64 * 192];   // 24KB, XOR-swizzled
  __shared__ u16 Vs[128 * 64];   // 16KB, d-major, XOR-swizzled
  __shared__ u16 Ps[128 * 64];   // 16KB: per-wave 16-row strip (same-wave write->read)
  const int tid = threadIdx.x, l = tid & 63, w = tid >> 6;
  const int lr = l & 15, h4 = l >> 4, lk = h4 * 8;
  const int bid = blockIdx.x, bh = bid & 31, qt = bid >> 5;  // bh%8 fixes XCD for K/V L2 reuse
  const int b = bh >> 4, hh = bh & 15;
  const int m0 = qt * 128;
  const u32 swz = (u32)(lr & 7) << 3;  // read-side swizzle (row&7 == lr&7 for all frag reads)

  // Q fragments: wave w owns q-rows m0 + w*16 .. +15
  bf16x8 qa[6];
  {
    const u16* qrow = Qp + (size_t)(b * 2048 + m0 + w * 16 + lr) * 3072 + hh * 192;
#pragma unroll
    for (int kk = 0; kk < 6; kk++) qa[kk] = ld_frag(qrow + kk * 32 + lk);
  }

  // staging: K = 64x192 (3 chunks/thread @512), V = 128x64 d-major (2 chunks/thread)
  const u16* kptr[3]; int kstep[3]; u32 klds[3];
#pragma unroll
  for (int p = 0; p < 3; p++) {
    int c2 = tid + p * 512;
    int r = c2 / 24, cc = c2 - r * 24;
    klds[p] = (u32)(r * 192 + cc * 8) ^ ((u32)(r & 7) << 3);
    if (cc < 16) { kptr[p] = Ckv + ((size_t)(b * 2048 + r)) * 4096 + hh * 256 + cc * 8; kstep[p] = 64 * 4096; }
    else         { kptr[p] = kropeb + ((size_t)(b * 2048 + r)) * 64 + (cc - 16) * 8;    kstep[p] = 64 * 64; }
  }
  const u16* vptr[2]; u32 vlds[2];
#pragma unroll
  for (int p = 0; p < 2; p++) {
    int c2 = tid + p * 512;
    int d = c2 >> 3, cc = c2 & 7;
    vlds[p] = (u32)(d * 64 + cc * 8) ^ ((u32)(d & 7) << 3);
    vptr[p] = VT + ((size_t)bh * 128 + d) * 2048 + cc * 8;
  }
  u16x8 kreg[3], vreg[2];
#pragma unroll
  for (int p = 0; p < 3; p++) { kreg[p] = *(const u16x8*)kptr[p]; kptr[p] += kstep[p]; }
#pragma unroll
  for (int p = 0; p < 2; p++) { vreg[p] = *(const u16x8*)vptr[p]; vptr[p] += 64; }

  f32x4 oacc[8] = {};
  float lsum[4] = {};
  const int odd = l & 1;

  for (int t = 0; t < 32; t++) {
    // write staged regs -> LDS (vmcnt wait auto-inserted for in-flight prefetch)
#pragma unroll
    for (int p = 0; p < 3; p++) *(u16x8*)&Ks[klds[p]] = kreg[p];
#pragma unroll
    for (int p = 0; p < 2; p++) *(u16x8*)&Vs[vlds[p]] = vreg[p];
    __syncthreads();
    if (t + 1 < 32) {  // issue next-tile loads; latency hides under compute below
#pragma unroll
      for (int p = 0; p < 3; p++) { kreg[p] = *(const u16x8*)kptr[p]; kptr[p] += kstep[p]; }
#pragma unroll
      for (int p = 0; p < 2; p++) { vreg[p] = *(const u16x8*)vptr[p]; vptr[p] += 64; }
    }
    // S = Q * K^T (scale*log2e pre-folded into Q)
    f32x4 sacc[4] = {};
    __builtin_amdgcn_s_setprio(1);
#pragma unroll
    for (int n = 0; n < 4; n++)
#pragma unroll
      for (int kk = 0; kk < 6; kk++)
        sacc[n] = __builtin_amdgcn_mfma_f32_16x16x32_bf16(
            qa[kk], ld_frag(&Ks[(u32)((n * 16 + lr) * 192 + kk * 32 + lk) ^ swz]), sacc[n], 0, 0, 0);
    __builtin_amdgcn_s_setprio(0);
    // P = exp2(S) (== exp of pre-scaled S): packed u32 writes, adjacent cols paired via one shfl_xor
    const int prow = w * 16 + 4 * h4;
#pragma unroll
    for (int n = 0; n < 4; n++) {
      float o0 = exp2f(sacc[n][0]), o1 = exp2f(sacc[n][1]),
            o2 = exp2f(sacc[n][2]), o3 = exp2f(sacc[n][3]);
      lsum[0] += o0; lsum[1] += o1; lsum[2] += o2; lsum[3] += o3;
      float p0 = __shfl_xor(o0, 1), p1 = __shfl_xor(o1, 1),
            p2 = __shfl_xor(o2, 1), p3 = __shfl_xor(o3, 1);
      float lo0 = odd ? p2 : o0, hi0 = odd ? o2 : p0;
      float lo1 = odd ? p3 : o1, hi1 = odd ? o3 : p1;
      int r0 = odd ? 2 : 0;
      u32 w0 = (u32)f2bf(lo0) | ((u32)f2bf(hi0) << 16);
      u32 w1 = (u32)f2bf(lo1) | ((u32)f2bf(hi1) << 16);
      int col = n * 16 + (lr & ~1);
      int row0 = prow + r0, row1 = prow + r0 + 1;
      *(u32*)&Ps[(u32)(row0 * 64 + col) ^ ((u32)(row0 & 7) << 3)] = w0;
      *(u32*)&Ps[(u32)(row1 * 64 + col) ^ ((u32)(row1 & 7) << 3)] = w1;
    }
    // O += P * V   (same-wave P write->read: DS ops are in-order per wave; compiler adds lgkmcnt)
    __builtin_amdgcn_s_setprio(1);
#pragma unroll
    for (int kk = 0; kk < 2; kk++) {
      bf16x8 pa = ld_frag(&Ps[(u32)((w * 16 + lr) * 64 + kk * 32 + lk) ^ swz]);
#pragma unroll
      for (int n2 = 0; n2 < 8; n2++)
        oacc[n2] = __builtin_amdgcn_mfma_f32_16x16x32_bf16(
            pa, ld_frag(&Vs[(u32)((n2 * 16 + lr) * 64 + kk * 32 + lk) ^ swz]), oacc[n2], 0, 0, 0);
    }
    __builtin_amdgcn_s_setprio(0);
    __syncthreads();
  }
  // epilogue: deferred row-sum reduce (over the 16 lr lanes), then normalize + store
  float rl[4];
#pragma unroll
  for (int r = 0; r < 4; r++) {
    float s = lsum[r];
    s += __shfl_xor(s, 1); s += __shfl_xor(s, 2); s += __shfl_xor(s, 4); s += __shfl_xor(s, 8);
    rl[r] = 1.f / s;
  }
#pragma unroll
  for (int n2 = 0; n2 < 8; n2++)
#pragma unroll
    for (int r = 0; r < 4; r++) {
      int row = m0 + w * 16 + h4 * 4 + r;
      AO[((size_t)(b * 2048 + row) * 16 + hh) * 128 + n2 * 16 + lr] = f2bf(oacc[n2][r] * rl[r]);
    }
}

extern "C" void kernel_launch(void* const* d_in, const int* in_sizes, int n_in,
                              void* d_out, int out_size, void* d_ws, size_t ws_size,
                              hipStream_t stream) {
  const float* q_in  = (const float*)d_in[0];
  const float* kv_in = (const float*)d_in[1];
  const int*   qpos  = (const int*)d_in[2];
  const int*   kpos  = (const int*)d_in[3];
  const float* Wqd   = (const float*)d_in[4];
  const float* qnw   = (const float*)d_in[5];
  const float* Wqu   = (const float*)d_in[6];
  const float* Wkvd  = (const float*)d_in[7];
  const float* kvnw  = (const float*)d_in[8];
  const float* Wkvu  = (const float*)d_in[9];
  const float* Wo    = (const float*)d_in[10];
  float* out = (float*)d_out;
  char* ws = (char*)d_ws;
  size_t off = 0;
  auto alloc = [&](size_t bytes) -> void* {
    void* p = ws + off; off += (bytes + 255) & ~(size_t)255; return p;
  };
  u16*   Aq     = (u16*)alloc(4096ull * 1024 * 2);
  u16*   Akv    = (u16*)alloc(4096ull * 1024 * 2);
  u16*   WqdT   = (u16*)alloc(256ull * 1024 * 2);
  u16*   WquT   = (u16*)alloc(3072ull * 256 * 2);
  u16*   WkvdT  = (u16*)alloc(128ull * 1024 * 2);
  u16*   WkvuT  = (u16*)alloc(4096ull * 32 * 2);
  u16*   WoT    = (u16*)alloc(1024ull * 2048 * 2);
  float* ckvf   = (float*)alloc(4096ull * 128 * 4);
  u16*   ckvn   = (u16*)alloc(4096ull * 32 * 2);
  u16*   kropeb = (u16*)alloc(4096ull * 64 * 2);
  u16*   Ckv    = (u16*)alloc(4096ull * 4096 * 2);
  u16*   VTb    = (u16*)alloc(32ull * 128 * 2048 * 2);
  float* cq     = (float*)alloc(4096ull * 256 * 4);
  u16*   cqn    = (u16*)alloc(4096ull * 256 * 2);
  u16*   qproj  = (u16*)alloc(4096ull * 3072 * 2);
  u16*   AOb    = (u16*)alloc(4096ull * 2048 * 2);
  (void)in_sizes; (void)n_in; (void)out_size; (void)ws_size;

  k_cvt<<<2048, 256, 0, stream>>>(q_in, Aq);
  k_cvt<<<2048, 256, 0, stream>>>(kv_in, Akv);
  k_wtrans<<<dim3(8, 32), 256, 0, stream>>>(Wqd, WqdT, 1024, 256, 1024);
  k_wtrans<<<dim3(96, 8), 256, 0, stream>>>(Wqu, WquT, 256, 3072, 256);
  k_wtrans<<<dim3(4, 32), 256, 0, stream>>>(Wkvd, WkvdT, 1024, 80, 1024);
  k_wtrans<<<dim3(128, 1), 256, 0, stream>>>(Wkvu, WkvuT, 16, 4096, 32);
  k_wtrans<<<dim3(32, 64), 256, 0, stream>>>(Wo, WoT, 2048, 1024, 2048);
  // kv path (64x64-tile GEMM: 128 blocks instead of 32)
  k_gemm64<0><<<dim3(2, 64), 256, 0, stream>>>(Akv, WkvdT, ckvf, 4096, 128, 1024);
  k_kvnorm<<<4096, 64, 0, stream>>>(ckvf, kvnw, kpos, ckvn, kropeb);
  k_gemm<1><<<dim3(32, 32), 256, 0, stream>>>(ckvn, WkvuT, Ckv, 4096, 4096, 32);
  k_vt<<<dim3(4, 64, 32), dim3(32, 8), 0, stream>>>(Ckv, VTb);
  // q path (64x64-tile GEMM: 256 blocks instead of 64)
  k_gemm64<0><<<dim3(4, 64), 256, 0, stream>>>(Aq, WqdT, cq, 4096, 256, 1024);
  // scale = log2(e)/sqrt(192): softmax via exp2 (exact: 2^(S*log2e) == e^S)
  k_rms256<<<1024, 256, 0, stream>>>(cq, qnw, cqn, 0.10411755454f);
  k_gemm<1><<<dim3(24, 32), 256, 0, stream>>>(cqn, WquT, qproj, 4096, 3072, 256);
  k_qrope<<<4096, 256, 0, stream>>>(qproj, qpos);
  // attention (512-thread blocks: 8 waves x 16 q-rows)
  k_attn<<<512, 512, 0, stream>>>(qproj, Ckv, kropeb, VTb, AOb);
  // output projection
  k_gemm<0><<<dim3(8, 32), 256, 0, stream>>>(AOb, WoT, out, 4096, 1024, 2048);
}

// Round 9
// 259.488 us; speedup vs baseline: 1.6632x; 1.0619x over previous
//
#include <hip/hip_runtime.h>

typedef unsigned short u16;
typedef unsigned int u32;
typedef u16 u16x4 __attribute__((ext_vector_type(4)));
typedef u16 u16x8 __attribute__((ext_vector_type(8)));
typedef float f32x4 __attribute__((ext_vector_type(4)));
typedef __bf16 bf16x8 __attribute__((ext_vector_type(8)));

#define DEV static __device__ __forceinline__

DEV float bf2f(u16 u) { u32 v = ((u32)u) << 16; float f; __builtin_memcpy(&f, &v, 4); return f; }
DEV u16 f2bf(float f) { u32 v; __builtin_memcpy(&v, &f, 4); v += 0x7fffu + ((v >> 16) & 1u); return (u16)(v >> 16); }
DEV bf16x8 ld_frag(const u16* p) { u16x8 v = *(const u16x8*)p; return __builtin_bit_cast(bf16x8, v); }

#define LOG10000 9.210340372f

// ---------------- elementwise f32 -> bf16 (n = grid*256*8) ----------------
__global__ __launch_bounds__(256) void k_cvt(const float* __restrict__ in, u16* __restrict__ out) {
  size_t i = ((size_t)blockIdx.x * 256 + threadIdx.x) * 8;
  f32x4 a = *(const f32x4*)(in + i);
  f32x4 b = *(const f32x4*)(in + i + 4);
  u16x8 o = { f2bf(a[0]), f2bf(a[1]), f2bf(a[2]), f2bf(a[3]),
              f2bf(b[0]), f2bf(b[1]), f2bf(b[2]), f2bf(b[3]) };
  *(u16x8*)(out + i) = o;
}

// ------- transpose f32 (R,C) -> bf16 (Cp,Rp), zero-padded. grid(Cp/32,Rp/32), block 256 -------
__global__ __launch_bounds__(256) void k_wtrans(const float* __restrict__ in, u16* __restrict__ out,
                                                int R, int C, int Rp) {
  __shared__ float tile[32][33];
  int c0 = blockIdx.x * 32, r0 = blockIdx.y * 32;
  int tx = threadIdx.x & 31, ty = threadIdx.x >> 5;
#pragma unroll
  for (int p = 0; p < 4; p++) {
    int r = r0 + ty + p * 8, c = c0 + tx;
    tile[ty + p * 8][tx] = (r < R && c < C) ? in[(size_t)r * C + c] : 0.f;
  }
  __syncthreads();
#pragma unroll
  for (int p = 0; p < 4; p++)
    out[(size_t)(c0 + ty + p * 8) * Rp + r0 + tx] = f2bf(tile[tx][ty + p * 8]);
}

// ---------------- GEMM: C(M,N) = A(M,K)bf16 * Bt(N,K)bf16, 128x128 tile, 4 waves ----------------
// XCD-chunked bid swizzle (grids are %8==0): each XCD gets contiguous row-major chunk -> A-strip L2 reuse.
template <int OUT_BF16>
__global__ __launch_bounds__(256) void k_gemm(const u16* __restrict__ A, const u16* __restrict__ Bt,
                                              void* __restrict__ Cv, int M, int N, int K) {
  constexpr int LSTR = 40;
  __shared__ u16 As[128 * LSTR], Bs[128 * LSTR];
  const int tid = threadIdx.x, l = tid & 63, w = tid >> 6;
  const int nwg = gridDim.x * gridDim.y;
  const int lin = blockIdx.y * gridDim.x + blockIdx.x;
  const int swzb = (lin & 7) * (nwg >> 3) + (lin >> 3);
  const int m0 = (swzb / gridDim.x) * 128, n0 = (swzb % gridDim.x) * 128;
  const int wr = (w >> 1) * 64, wc = (w & 1) * 64;
  const int lr = l & 15, lk = (l >> 4) * 8;
  const int sr = tid >> 2, sc = (tid & 3) * 8;
  f32x4 acc[4][4] = {};
  const u16* pa0 = A + (size_t)(m0 + sr) * K + sc;
  const u16* pa1 = A + (size_t)(m0 + 64 + sr) * K + sc;
  const u16* pb0 = Bt + (size_t)(n0 + sr) * K + sc;
  const u16* pb1 = Bt + (size_t)(n0 + 64 + sr) * K + sc;
  u16x8 va0 = *(const u16x8*)pa0, va1 = *(const u16x8*)pa1;
  u16x8 vb0 = *(const u16x8*)pb0, vb1 = *(const u16x8*)pb1;
  for (int k0 = 0; k0 < K; k0 += 32) {
    *(u16x8*)&As[sr * LSTR + sc] = va0;
    *(u16x8*)&As[(64 + sr) * LSTR + sc] = va1;
    *(u16x8*)&Bs[sr * LSTR + sc] = vb0;
    *(u16x8*)&Bs[(64 + sr) * LSTR + sc] = vb1;
    __syncthreads();
    if (k0 + 32 < K) {
      va0 = *(const u16x8*)(pa0 + k0 + 32);
      va1 = *(const u16x8*)(pa1 + k0 + 32);
      vb0 = *(const u16x8*)(pb0 + k0 + 32);
      vb1 = *(const u16x8*)(pb1 + k0 + 32);
    }
    bf16x8 af[4], bf[4];
#pragma unroll
    for (int i = 0; i < 4; i++) af[i] = ld_frag(&As[(wr + i * 16 + lr) * LSTR + lk]);
#pragma unroll
    for (int j = 0; j < 4; j++) bf[j] = ld_frag(&Bs[(wc + j * 16 + lr) * LSTR + lk]);
#pragma unroll
    for (int i = 0; i < 4; i++)
#pragma unroll
      for (int j = 0; j < 4; j++)
        acc[i][j] = __builtin_amdgcn_mfma_f32_16x16x32_bf16(af[i], bf[j], acc[i][j], 0, 0, 0);
    __syncthreads();
  }
#pragma unroll
  for (int i = 0; i < 4; i++)
#pragma unroll
    for (int j = 0; j < 4; j++) {
      int row = m0 + wr + i * 16 + (l >> 4) * 4;
      int col = n0 + wc + j * 16 + lr;
#pragma unroll
      for (int r = 0; r < 4; r++) {
        if (OUT_BF16) ((u16*)Cv)[(size_t)(row + r) * N + col] = f2bf(acc[i][j][r]);
        else          ((float*)Cv)[(size_t)(row + r) * N + col] = acc[i][j][r];
      }
    }
}

// ---------------- GEMM 64(M)x128(N) tile, 4 waves (2M x 2N): for grids needing more blocks ----------------
template <int OUT_BF16>
__global__ __launch_bounds__(256) void k_gemmh(const u16* __restrict__ A, const u16* __restrict__ Bt,
                                               void* __restrict__ Cv, int M, int N, int K) {
  constexpr int LSTR = 40;
  __shared__ u16 As[64 * LSTR], Bs[128 * LSTR];
  const int tid = threadIdx.x, l = tid & 63, w = tid >> 6;
  const int nwg = gridDim.x * gridDim.y;
  const int lin = blockIdx.y * gridDim.x + blockIdx.x;
  const int swzb = (lin & 7) * (nwg >> 3) + (lin >> 3);
  const int m0 = (swzb / gridDim.x) * 64, n0 = (swzb % gridDim.x) * 128;
  const int wr = (w >> 1) * 32, wc = (w & 1) * 64;
  const int lr = l & 15, lk = (l >> 4) * 8;
  const int sr = tid >> 2, sc = (tid & 3) * 8;
  f32x4 acc[2][4] = {};
  const u16* pa0 = A + (size_t)(m0 + sr) * K + sc;
  const u16* pb0 = Bt + (size_t)(n0 + sr) * K + sc;
  const u16* pb1 = Bt + (size_t)(n0 + 64 + sr) * K + sc;
  u16x8 va0 = *(const u16x8*)pa0;
  u16x8 vb0 = *(const u16x8*)pb0, vb1 = *(const u16x8*)pb1;
  for (int k0 = 0; k0 < K; k0 += 32) {
    *(u16x8*)&As[sr * LSTR + sc] = va0;
    *(u16x8*)&Bs[sr * LSTR + sc] = vb0;
    *(u16x8*)&Bs[(64 + sr) * LSTR + sc] = vb1;
    __syncthreads();
    if (k0 + 32 < K) {
      va0 = *(const u16x8*)(pa0 + k0 + 32);
      vb0 = *(const u16x8*)(pb0 + k0 + 32);
      vb1 = *(const u16x8*)(pb1 + k0 + 32);
    }
    bf16x8 af[2], bf[4];
#pragma unroll
    for (int i = 0; i < 2; i++) af[i] = ld_frag(&As[(wr + i * 16 + lr) * LSTR + lk]);
#pragma unroll
    for (int j = 0; j < 4; j++) bf[j] = ld_frag(&Bs[(wc + j * 16 + lr) * LSTR + lk]);
#pragma unroll
    for (int i = 0; i < 2; i++)
#pragma unroll
      for (int j = 0; j < 4; j++)
        acc[i][j] = __builtin_amdgcn_mfma_f32_16x16x32_bf16(af[i], bf[j], acc[i][j], 0, 0, 0);
    __syncthreads();
  }
#pragma unroll
  for (int i = 0; i < 2; i++)
#pragma unroll
    for (int j = 0; j < 4; j++) {
      int row = m0 + wr + i * 16 + (l >> 4) * 4;
      int col = n0 + wc + j * 16 + lr;
#pragma unroll
      for (int r = 0; r < 4; r++) {
        if (OUT_BF16) ((u16*)Cv)[(size_t)(row + r) * N + col] = f2bf(acc[i][j][r]);
        else          ((float*)Cv)[(size_t)(row + r) * N + col] = acc[i][j][r];
      }
    }
}

// ---------------- GEMM 64x64 tile (for small-N projections; 4x the block parallelism) ----------------
template <int OUT_BF16>
__global__ __launch_bounds__(256) void k_gemm64(const u16* __restrict__ A, const u16* __restrict__ Bt,
                                                void* __restrict__ Cv, int M, int N, int K) {
  constexpr int LSTR = 40;
  __shared__ u16 As[64 * LSTR], Bs[64 * LSTR];
  const int tid = threadIdx.x, l = tid & 63, w = tid >> 6;
  const int nwg = gridDim.x * gridDim.y;
  const int lin = blockIdx.y * gridDim.x + blockIdx.x;
  const int swzb = (lin & 7) * (nwg >> 3) + (lin >> 3);
  const int m0 = (swzb / gridDim.x) * 64, n0 = (swzb % gridDim.x) * 64;
  const int wr = (w >> 1) * 32, wc = (w & 1) * 32;
  const int lr = l & 15, lk = (l >> 4) * 8;
  const int sr = tid >> 2, sc = (tid & 3) * 8;
  f32x4 acc[2][2] = {};
  const u16* pa0 = A + (size_t)(m0 + sr) * K + sc;
  const u16* pb0 = Bt + (size_t)(n0 + sr) * K + sc;
  u16x8 va0 = *(const u16x8*)pa0;
  u16x8 vb0 = *(const u16x8*)pb0;
  for (int k0 = 0; k0 < K; k0 += 32) {
    *(u16x8*)&As[sr * LSTR + sc] = va0;
    *(u16x8*)&Bs[sr * LSTR + sc] = vb0;
    __syncthreads();
    if (k0 + 32 < K) {
      va0 = *(const u16x8*)(pa0 + k0 + 32);
      vb0 = *(const u16x8*)(pb0 + k0 + 32);
    }
    bf16x8 af[2], bf[2];
#pragma unroll
    for (int i = 0; i < 2; i++) af[i] = ld_frag(&As[(wr + i * 16 + lr) * LSTR + lk]);
#pragma unroll
    for (int j = 0; j < 2; j++) bf[j] = ld_frag(&Bs[(wc + j * 16 + lr) * LSTR + lk]);
#pragma unroll
    for (int i = 0; i < 2; i++)
#pragma unroll
      for (int j = 0; j < 2; j++)
        acc[i][j] = __builtin_amdgcn_mfma_f32_16x16x32_bf16(af[i], bf[j], acc[i][j], 0, 0, 0);
    __syncthreads();
  }
#pragma unroll
  for (int i = 0; i < 2; i++)
#pragma unroll
    for (int j = 0; j < 2; j++) {
      int row = m0 + wr + i * 16 + (l >> 4) * 4;
      int col = n0 + wc + j * 16 + lr;
#pragma unroll
      for (int r = 0; r < 4; r++) {
        if (OUT_BF16) ((u16*)Cv)[(size_t)(row + r) * N + col] = f2bf(acc[i][j][r]);
        else          ((float*)Cv)[(size_t)(row + r) * N + col] = acc[i][j][r];
      }
    }
}

// ---------------- kv-down epilogue: rms_norm(16) + rope(64). one wave per row ----------------
__global__ __launch_bounds__(64) void k_kvnorm(const float* __restrict__ ckvf, const float* __restrict__ nw,
                                               const int* __restrict__ pos, u16* __restrict__ ckvn,
                                               u16* __restrict__ kropeb) {
  int row = blockIdx.x, l = threadIdx.x;
  const float* x = ckvf + (size_t)row * 128;
  float v = (l < 16) ? x[l] : 0.f;
  float ss = v * v;
  ss += __shfl_xor(ss, 1); ss += __shfl_xor(ss, 2); ss += __shfl_xor(ss, 4); ss += __shfl_xor(ss, 8);
  if (l < 16) ckvn[(size_t)row * 32 + l] = f2bf(v * rsqrtf(ss * (1.f / 16.f) + 1e-7f) * nw[l]);
  if (l >= 16 && l < 32) ckvn[(size_t)row * 32 + l] = 0;
  if (l < 32) {
    float invf = __expf(-(LOG10000 / 32.f) * (float)l);
    float ang = (float)pos[row] * invf;
    float c = cosf(ang), s = sinf(ang);
    float e = x[16 + 2 * l], o = x[17 + 2 * l];
    kropeb[(size_t)row * 64 + l]      = f2bf(e * c - o * s);
    kropeb[(size_t)row * 64 + l + 32] = f2bf(o * c + e * s);
  }
}

// ---------------- q rms_norm over 256 (scale = 1/sqrt(192) folded in). wave per row ----------------
__global__ __launch_bounds__(256) void k_rms256(const float* __restrict__ in, const float* __restrict__ w,
                                                u16* __restrict__ out, float scale) {
  int row = blockIdx.x * 4 + (threadIdx.x >> 6);
  int l = threadIdx.x & 63;
  const float* x = in + (size_t)row * 256;
  f32x4 v = *(const f32x4*)(x + l * 4);
  float ss = v[0] * v[0] + v[1] * v[1] + v[2] * v[2] + v[3] * v[3];
#pragma unroll
  for (int m = 1; m < 64; m <<= 1) ss += __shfl_xor(ss, m);
  float rinv = rsqrtf(ss * (1.f / 256.f) + 1e-7f) * scale;
  const f32x4 wv = *(const f32x4*)(w + l * 4);
  u16x4 o = { f2bf(v[0] * rinv * wv[0]), f2bf(v[1] * rinv * wv[1]),
              f2bf(v[2] * rinv * wv[2]), f2bf(v[3] * rinv * wv[3]) };
  *(u16x4*)(out + (size_t)row * 256 + l * 4) = o;
}

// ---------------- in-place rope on qproj (B,SQ,H,192): dims 128..191 per head ----------------
__global__ __launch_bounds__(256) void k_qrope(u16* __restrict__ q, const int* __restrict__ pos) {
  __shared__ float cs[32], sn[32];
  int bs = blockIdx.x, tid = threadIdx.x;
  if (tid < 32) {
    float invf = __expf(-(LOG10000 / 32.f) * (float)tid);
    float ang = (float)pos[bs] * invf;
    cs[tid] = cosf(ang); sn[tid] = sinf(ang);
  }
  __syncthreads();
  u16* base = q + (size_t)bs * 3072;
  int h0 = tid >> 5, p0 = tid & 31;
  int h1 = h0 + 8, p1 = p0;
  u16* r0p = base + h0 * 192 + 128;
  u16* r1p = base + h1 * 192 + 128;
  float e0 = bf2f(r0p[2 * p0]), o0 = bf2f(r0p[2 * p0 + 1]);
  float e1 = bf2f(r1p[2 * p1]), o1 = bf2f(r1p[2 * p1 + 1]);
  __syncthreads();
  r0p[p0]      = f2bf(e0 * cs[p0] - o0 * sn[p0]);
  r0p[p0 + 32] = f2bf(o0 * cs[p0] + e0 * sn[p0]);
  r1p[p1]      = f2bf(e1 * cs[p1] - o1 * sn[p1]);
  r1p[p1 + 32] = f2bf(o1 * cs[p1] + e1 * sn[p1]);
}

// ---------------- V^T extraction: Ckv(B*SKV, H*256)[.,h*256+128..] -> VT(BH,128,SKV) ----------------
__global__ void k_vt(const u16* __restrict__ Ckv, u16* __restrict__ VT) {
  __shared__ u16 tile[32][40];
  int bh = blockIdx.z, b = bh >> 4, h = bh & 15;
  int d0 = blockIdx.x * 32, s0 = blockIdx.y * 32;
  int tx = threadIdx.x, ty = threadIdx.y;
  const u16* src = Ckv + ((size_t)(b * 2048 + s0)) * 4096 + h * 256 + 128 + d0;
#pragma unroll
  for (int p = 0; p < 4; p++) tile[ty + p * 8][tx] = src[(size_t)(ty + p * 8) * 4096 + tx];
  __syncthreads();
  u16* dst = VT + ((size_t)bh * 128 + d0) * 2048 + s0;
#pragma unroll
  for (int p = 0; p < 4; p++) dst[(size_t)(ty + p * 8) * 2048 + tx] = tile[tx][ty + p * 8];
}

// ---- fused attention v9 (= v5 structure, best measured): 128 q-rows/block, 8 waves x 16 rows ----
// 96 VGPR -> 4 waves/SIMD; 2 blocks/CU x 8 waves = 16 waves/CU. __expf (native v_exp).
__global__ __launch_bounds__(512, 2) void k_attn(const u16* __restrict__ Qp, const u16* __restrict__ Ckv,
                                                 const u16* __restrict__ kropeb, const u16* __restrict__ VT,
                                                 u16* __restrict__ AO) {
  __shared__ u16 Ks[64 * 192];   // 24KB, XOR-swizzled
  __shared__ u16 Vs[128 * 64];   // 16KB, d-major, XOR-swizzled
  __shared__ u16 Ps[128 * 64];   // 16KB: per-wave 16-row strip (same-wave write->read)
  const int tid = threadIdx.x, l = tid & 63, w = tid >> 6;
  const int lr = l & 15, h4 = l >> 4, lk = h4 * 8;
  const int bid = blockIdx.x, bh = bid & 31, qt = bid >> 5;  // bh%8 fixes XCD for K/V L2 reuse
  const int b = bh >> 4, hh = bh & 15;
  const int m0 = qt * 128;
  const u32 swz = (u32)(lr & 7) << 3;  // read-side swizzle (row&7 == lr&7 for all frag reads)

  // Q fragments: wave w owns q-rows m0 + w*16 .. +15
  bf16x8 qa[6];
  {
    const u16* qrow = Qp + (size_t)(b * 2048 + m0 + w * 16 + lr) * 3072 + hh * 192;
#pragma unroll
    for (int kk = 0; kk < 6; kk++) qa[kk] = ld_frag(qrow + kk * 32 + lk);
  }

  // staging: K = 64x192 (3 chunks/thread @512), V = 128x64 d-major (2 chunks/thread)
  const u16* kptr[3]; int kstep[3]; u32 klds[3];
#pragma unroll
  for (int p = 0; p < 3; p++) {
    int c2 = tid + p * 512;
    int r = c2 / 24, cc = c2 - r * 24;
    klds[p] = (u32)(r * 192 + cc * 8) ^ ((u32)(r & 7) << 3);
    if (cc < 16) { kptr[p] = Ckv + ((size_t)(b * 2048 + r)) * 4096 + hh * 256 + cc * 8; kstep[p] = 64 * 4096; }
    else         { kptr[p] = kropeb + ((size_t)(b * 2048 + r)) * 64 + (cc - 16) * 8;    kstep[p] = 64 * 64; }
  }
  const u16* vptr[2]; u32 vlds[2];
#pragma unroll
  for (int p = 0; p < 2; p++) {
    int c2 = tid + p * 512;
    int d = c2 >> 3, cc = c2 & 7;
    vlds[p] = (u32)(d * 64 + cc * 8) ^ ((u32)(d & 7) << 3);
    vptr[p] = VT + ((size_t)bh * 128 + d) * 2048 + cc * 8;
  }
  u16x8 kreg[3], vreg[2];
#pragma unroll
  for (int p = 0; p < 3; p++) { kreg[p] = *(const u16x8*)kptr[p]; kptr[p] += kstep[p]; }
#pragma unroll
  for (int p = 0; p < 2; p++) { vreg[p] = *(const u16x8*)vptr[p]; vptr[p] += 64; }

  f32x4 oacc[8] = {};
  float lsum[4] = {};
  const int odd = l & 1;

  for (int t = 0; t < 32; t++) {
    // write staged regs -> LDS (vmcnt wait auto-inserted for in-flight prefetch)
#pragma unroll
    for (int p = 0; p < 3; p++) *(u16x8*)&Ks[klds[p]] = kreg[p];
#pragma unroll
    for (int p = 0; p < 2; p++) *(u16x8*)&Vs[vlds[p]] = vreg[p];
    __syncthreads();
    if (t + 1 < 32) {  // issue next-tile loads; latency hides under compute below
#pragma unroll
      for (int p = 0; p < 3; p++) { kreg[p] = *(const u16x8*)kptr[p]; kptr[p] += kstep[p]; }
#pragma unroll
      for (int p = 0; p < 2; p++) { vreg[p] = *(const u16x8*)vptr[p]; vptr[p] += 64; }
    }
    // S = Q * K^T (scale pre-folded into Q)
    f32x4 sacc[4] = {};
    __builtin_amdgcn_s_setprio(1);
#pragma unroll
    for (int n = 0; n < 4; n++)
#pragma unroll
      for (int kk = 0; kk < 6; kk++)
        sacc[n] = __builtin_amdgcn_mfma_f32_16x16x32_bf16(
            qa[kk], ld_frag(&Ks[(u32)((n * 16 + lr) * 192 + kk * 32 + lk) ^ swz]), sacc[n], 0, 0, 0);
    __builtin_amdgcn_s_setprio(0);
    // P = exp(S): packed u32 writes, adjacent cols paired via one shfl_xor
    const int prow = w * 16 + 4 * h4;
#pragma unroll
    for (int n = 0; n < 4; n++) {
      float o0 = __expf(sacc[n][0]), o1 = __expf(sacc[n][1]),
            o2 = __expf(sacc[n][2]), o3 = __expf(sacc[n][3]);
      lsum[0] += o0; lsum[1] += o1; lsum[2] += o2; lsum[3] += o3;
      float p0 = __shfl_xor(o0, 1), p1 = __shfl_xor(o1, 1),
            p2 = __shfl_xor(o2, 1), p3 = __shfl_xor(o3, 1);
      float lo0 = odd ? p2 : o0, hi0 = odd ? o2 : p0;
      float lo1 = odd ? p3 : o1, hi1 = odd ? o3 : p1;
      int r0 = odd ? 2 : 0;
      u32 w0 = (u32)f2bf(lo0) | ((u32)f2bf(hi0) << 16);
      u32 w1 = (u32)f2bf(lo1) | ((u32)f2bf(hi1) << 16);
      int col = n * 16 + (lr & ~1);
      int row0 = prow + r0, row1 = prow + r0 + 1;
      *(u32*)&Ps[(u32)(row0 * 64 + col) ^ ((u32)(row0 & 7) << 3)] = w0;
      *(u32*)&Ps[(u32)(row1 * 64 + col) ^ ((u32)(row1 & 7) << 3)] = w1;
    }
    // O += P * V   (same-wave P write->read: DS ops are in-order per wave; compiler adds lgkmcnt)
    __builtin_amdgcn_s_setprio(1);
#pragma unroll
    for (int kk = 0; kk < 2; kk++) {
      bf16x8 pa = ld_frag(&Ps[(u32)((w * 16 + lr) * 64 + kk * 32 + lk) ^ swz]);
#pragma unroll
      for (int n2 = 0; n2 < 8; n2++)
        oacc[n2] = __builtin_amdgcn_mfma_f32_16x16x32_bf16(
            pa, ld_frag(&Vs[(u32)((n2 * 16 + lr) * 64 + kk * 32 + lk) ^ swz]), oacc[n2], 0, 0, 0);
    }
    __builtin_amdgcn_s_setprio(0);
    __syncthreads();
  }
  // epilogue: deferred row-sum reduce (over the 16 lr lanes), then normalize + store
  float rl[4];
#pragma unroll
  for (int r = 0; r < 4; r++) {
    float s = lsum[r];
    s += __shfl_xor(s, 1); s += __shfl_xor(s, 2); s += __shfl_xor(s, 4); s += __shfl_xor(s, 8);
    rl[r] = 1.f / s;
  }
#pragma unroll
  for (int n2 = 0; n2 < 8; n2++)
#pragma unroll
    for (int r = 0; r < 4; r++) {
      int row = m0 + w * 16 + h4 * 4 + r;
      AO[((size_t)(b * 2048 + row) * 16 + hh) * 128 + n2 * 16 + lr] = f2bf(oacc[n2][r] * rl[r]);
    }
}

extern "C" void kernel_launch(void* const* d_in, const int* in_sizes, int n_in,
                              void* d_out, int out_size, void* d_ws, size_t ws_size,
                              hipStream_t stream) {
  const float* q_in  = (const float*)d_in[0];
  const float* kv_in = (const float*)d_in[1];
  const int*   qpos  = (const int*)d_in[2];
  const int*   kpos  = (const int*)d_in[3];
  const float* Wqd   = (const float*)d_in[4];
  const float* qnw   = (const float*)d_in[5];
  const float* Wqu   = (const float*)d_in[6];
  const float* Wkvd  = (const float*)d_in[7];
  const float* kvnw  = (const float*)d_in[8];
  const float* Wkvu  = (const float*)d_in[9];
  const float* Wo    = (const float*)d_in[10];
  float* out = (float*)d_out;
  char* ws = (char*)d_ws;
  size_t off = 0;
  auto alloc = [&](size_t bytes) -> void* {
    void* p = ws + off; off += (bytes + 255) & ~(size_t)255; return p;
  };
  u16*   Aq     = (u16*)alloc(4096ull * 1024 * 2);
  u16*   Akv    = (u16*)alloc(4096ull * 1024 * 2);
  u16*   WqdT   = (u16*)alloc(256ull * 1024 * 2);
  u16*   WquT   = (u16*)alloc(3072ull * 256 * 2);
  u16*   WkvdT  = (u16*)alloc(128ull * 1024 * 2);
  u16*   WkvuT  = (u16*)alloc(4096ull * 32 * 2);
  u16*   WoT    = (u16*)alloc(1024ull * 2048 * 2);
  float* ckvf   = (float*)alloc(4096ull * 128 * 4);
  u16*   ckvn   = (u16*)alloc(4096ull * 32 * 2);
  u16*   kropeb = (u16*)alloc(4096ull * 64 * 2);
  u16*   Ckv    = (u16*)alloc(4096ull * 4096 * 2);
  u16*   VTb    = (u16*)alloc(32ull * 128 * 2048 * 2);
  float* cq     = (float*)alloc(4096ull * 256 * 4);
  u16*   cqn    = (u16*)alloc(4096ull * 256 * 2);
  u16*   qproj  = (u16*)alloc(4096ull * 3072 * 2);
  u16*   AOb    = (u16*)alloc(4096ull * 2048 * 2);
  (void)in_sizes; (void)n_in; (void)out_size; (void)ws_size;

  k_cvt<<<2048, 256, 0, stream>>>(q_in, Aq);
  k_cvt<<<2048, 256, 0, stream>>>(kv_in, Akv);
  k_wtrans<<<dim3(8, 32), 256, 0, stream>>>(Wqd, WqdT, 1024, 256, 1024);
  k_wtrans<<<dim3(96, 8), 256, 0, stream>>>(Wqu, WquT, 256, 3072, 256);
  k_wtrans<<<dim3(4, 32), 256, 0, stream>>>(Wkvd, WkvdT, 1024, 80, 1024);
  k_wtrans<<<dim3(128, 1), 256, 0, stream>>>(Wkvu, WkvuT, 16, 4096, 32);
  k_wtrans<<<dim3(32, 64), 256, 0, stream>>>(Wo, WoT, 2048, 1024, 2048);
  // kv path (64x64-tile GEMM: 128 blocks instead of 32)
  k_gemm64<0><<<dim3(2, 64), 256, 0, stream>>>(Akv, WkvdT, ckvf, 4096, 128, 1024);
  k_kvnorm<<<4096, 64, 0, stream>>>(ckvf, kvnw, kpos, ckvn, kropeb);
  k_gemm<1><<<dim3(32, 32), 256, 0, stream>>>(ckvn, WkvuT, Ckv, 4096, 4096, 32);
  k_vt<<<dim3(4, 64, 32), dim3(32, 8), 0, stream>>>(Ckv, VTb);
  // q path (64x64-tile GEMM: 256 blocks instead of 64)
  k_gemm64<0><<<dim3(4, 64), 256, 0, stream>>>(Aq, WqdT, cq, 4096, 256, 1024);
  k_rms256<<<1024, 256, 0, stream>>>(cq, qnw, cqn, 0.07216878364870322f);
  k_gemm<1><<<dim3(24, 32), 256, 0, stream>>>(cqn, WquT, qproj, 4096, 3072, 256);
  k_qrope<<<4096, 256, 0, stream>>>(qproj, qpos);
  // attention (512-thread blocks: 8 waves x 16 q-rows)
  k_attn<<<512, 512, 0, stream>>>(qproj, Ckv, kropeb, VTb, AOb);
  // output projection: 64x128 tile -> 512 blocks = 2/CU (was 256 = 1/CU)
  k_gemmh<0><<<dim3(8, 64), 256, 0, stream>>>(AOb, WoT, out, 4096, 1024, 2048);
}

// Round 10
// 259.302 us; speedup vs baseline: 1.6644x; 1.0007x over previous
//
#include <hip/hip_runtime.h>

typedef unsigned short u16;
typedef unsigned int u32;
typedef u16 u16x4 __attribute__((ext_vector_type(4)));
typedef u16 u16x8 __attribute__((ext_vector_type(8)));
typedef u32 u32x4 __attribute__((ext_vector_type(4)));
typedef float f32x4 __attribute__((ext_vector_type(4)));
typedef __bf16 bf16x8 __attribute__((ext_vector_type(8)));

#define DEV static __device__ __forceinline__

DEV float bf2f(u16 u) { u32 v = ((u32)u) << 16; float f; __builtin_memcpy(&f, &v, 4); return f; }
DEV u16 f2bf(float f) { u32 v; __builtin_memcpy(&v, &f, 4); v += 0x7fffu + ((v >> 16) & 1u); return (u16)(v >> 16); }
DEV bf16x8 ld_frag(const u16* p) { u16x8 v = *(const u16x8*)p; return __builtin_bit_cast(bf16x8, v); }

#define LOG10000 9.210340372f

// ------- transpose f32 (R,C) -> bf16 (Cp,Rp), zero-padded. grid(Cp/32,Rp/32), block 256 -------
__global__ __launch_bounds__(256) void k_wtrans(const float* __restrict__ in, u16* __restrict__ out,
                                                int R, int C, int Rp) {
  __shared__ float tile[32][33];
  int c0 = blockIdx.x * 32, r0 = blockIdx.y * 32;
  int tx = threadIdx.x & 31, ty = threadIdx.x >> 5;
#pragma unroll
  for (int p = 0; p < 4; p++) {
    int r = r0 + ty + p * 8, c = c0 + tx;
    tile[ty + p * 8][tx] = (r < R && c < C) ? in[(size_t)r * C + c] : 0.f;
  }
  __syncthreads();
#pragma unroll
  for (int p = 0; p < 4; p++)
    out[(size_t)(c0 + ty + p * 8) * Rp + r0 + tx] = f2bf(tile[tx][ty + p * 8]);
}

// ---------------- GEMM: C(M,N) = A(M,K)bf16 * Bt(N,K)bf16, 128x128 tile, 4 waves ----------------
template <int OUT_BF16>
__global__ __launch_bounds__(256) void k_gemm(const u16* __restrict__ A, const u16* __restrict__ Bt,
                                              void* __restrict__ Cv, int M, int N, int K) {
  constexpr int LSTR = 40;
  __shared__ u16 As[128 * LSTR], Bs[128 * LSTR];
  const int tid = threadIdx.x, l = tid & 63, w = tid >> 6;
  const int nwg = gridDim.x * gridDim.y;
  const int lin = blockIdx.y * gridDim.x + blockIdx.x;
  const int swzb = (lin & 7) * (nwg >> 3) + (lin >> 3);
  const int m0 = (swzb / gridDim.x) * 128, n0 = (swzb % gridDim.x) * 128;
  const int wr = (w >> 1) * 64, wc = (w & 1) * 64;
  const int lr = l & 15, lk = (l >> 4) * 8;
  const int sr = tid >> 2, sc = (tid & 3) * 8;
  f32x4 acc[4][4] = {};
  const u16* pa0 = A + (size_t)(m0 + sr) * K + sc;
  const u16* pa1 = A + (size_t)(m0 + 64 + sr) * K + sc;
  const u16* pb0 = Bt + (size_t)(n0 + sr) * K + sc;
  const u16* pb1 = Bt + (size_t)(n0 + 64 + sr) * K + sc;
  u16x8 va0 = *(const u16x8*)pa0, va1 = *(const u16x8*)pa1;
  u16x8 vb0 = *(const u16x8*)pb0, vb1 = *(const u16x8*)pb1;
  for (int k0 = 0; k0 < K; k0 += 32) {
    *(u16x8*)&As[sr * LSTR + sc] = va0;
    *(u16x8*)&As[(64 + sr) * LSTR + sc] = va1;
    *(u16x8*)&Bs[sr * LSTR + sc] = vb0;
    *(u16x8*)&Bs[(64 + sr) * LSTR + sc] = vb1;
    __syncthreads();
    if (k0 + 32 < K) {
      va0 = *(const u16x8*)(pa0 + k0 + 32);
      va1 = *(const u16x8*)(pa1 + k0 + 32);
      vb0 = *(const u16x8*)(pb0 + k0 + 32);
      vb1 = *(const u16x8*)(pb1 + k0 + 32);
    }
    bf16x8 af[4], bf[4];
#pragma unroll
    for (int i = 0; i < 4; i++) af[i] = ld_frag(&As[(wr + i * 16 + lr) * LSTR + lk]);
#pragma unroll
    for (int j = 0; j < 4; j++) bf[j] = ld_frag(&Bs[(wc + j * 16 + lr) * LSTR + lk]);
#pragma unroll
    for (int i = 0; i < 4; i++)
#pragma unroll
      for (int j = 0; j < 4; j++)
        acc[i][j] = __builtin_amdgcn_mfma_f32_16x16x32_bf16(af[i], bf[j], acc[i][j], 0, 0, 0);
    __syncthreads();
  }
#pragma unroll
  for (int i = 0; i < 4; i++)
#pragma unroll
    for (int j = 0; j < 4; j++) {
      int row = m0 + wr + i * 16 + (l >> 4) * 4;
      int col = n0 + wc + j * 16 + lr;
#pragma unroll
      for (int r = 0; r < 4; r++) {
        if (OUT_BF16) ((u16*)Cv)[(size_t)(row + r) * N + col] = f2bf(acc[i][j][r]);
        else          ((float*)Cv)[(size_t)(row + r) * N + col] = acc[i][j][r];
      }
    }
}

// ---------------- GEMM 64(M)x128(N) tile, 4 waves (2M x 2N) ----------------
template <int OUT_BF16>
__global__ __launch_bounds__(256) void k_gemmh(const u16* __restrict__ A, const u16* __restrict__ Bt,
                                               void* __restrict__ Cv, int M, int N, int K) {
  constexpr int LSTR = 40;
  __shared__ u16 As[64 * LSTR], Bs[128 * LSTR];
  const int tid = threadIdx.x, l = tid & 63, w = tid >> 6;
  const int nwg = gridDim.x * gridDim.y;
  const int lin = blockIdx.y * gridDim.x + blockIdx.x;
  const int swzb = (lin & 7) * (nwg >> 3) + (lin >> 3);
  const int m0 = (swzb / gridDim.x) * 64, n0 = (swzb % gridDim.x) * 128;
  const int wr = (w >> 1) * 32, wc = (w & 1) * 64;
  const int lr = l & 15, lk = (l >> 4) * 8;
  const int sr = tid >> 2, sc = (tid & 3) * 8;
  f32x4 acc[2][4] = {};
  const u16* pa0 = A + (size_t)(m0 + sr) * K + sc;
  const u16* pb0 = Bt + (size_t)(n0 + sr) * K + sc;
  const u16* pb1 = Bt + (size_t)(n0 + 64 + sr) * K + sc;
  u16x8 va0 = *(const u16x8*)pa0;
  u16x8 vb0 = *(const u16x8*)pb0, vb1 = *(const u16x8*)pb1;
  for (int k0 = 0; k0 < K; k0 += 32) {
    *(u16x8*)&As[sr * LSTR + sc] = va0;
    *(u16x8*)&Bs[sr * LSTR + sc] = vb0;
    *(u16x8*)&Bs[(64 + sr) * LSTR + sc] = vb1;
    __syncthreads();
    if (k0 + 32 < K) {
      va0 = *(const u16x8*)(pa0 + k0 + 32);
      vb0 = *(const u16x8*)(pb0 + k0 + 32);
      vb1 = *(const u16x8*)(pb1 + k0 + 32);
    }
    bf16x8 af[2], bf[4];
#pragma unroll
    for (int i = 0; i < 2; i++) af[i] = ld_frag(&As[(wr + i * 16 + lr) * LSTR + lk]);
#pragma unroll
    for (int j = 0; j < 4; j++) bf[j] = ld_frag(&Bs[(wc + j * 16 + lr) * LSTR + lk]);
#pragma unroll
    for (int i = 0; i < 2; i++)
#pragma unroll
      for (int j = 0; j < 4; j++)
        acc[i][j] = __builtin_amdgcn_mfma_f32_16x16x32_bf16(af[i], bf[j], acc[i][j], 0, 0, 0);
    __syncthreads();
  }
#pragma unroll
  for (int i = 0; i < 2; i++)
#pragma unroll
    for (int j = 0; j < 4; j++) {
      int row = m0 + wr + i * 16 + (l >> 4) * 4;
      int col = n0 + wc + j * 16 + lr;
#pragma unroll
      for (int r = 0; r < 4; r++) {
        if (OUT_BF16) ((u16*)Cv)[(size_t)(row + r) * N + col] = f2bf(acc[i][j][r]);
        else          ((float*)Cv)[(size_t)(row + r) * N + col] = acc[i][j][r];
      }
    }
}

// ------- GEMM 64x64 tile, A in f32 (fused cvt in staging): C = A(M,K)f32 * Bt(N,K)bf16 -------
template <int OUT_BF16>
__global__ __launch_bounds__(256) void k_gemm64f(const float* __restrict__ A, const u16* __restrict__ Bt,
                                                 void* __restrict__ Cv, int M, int N, int K) {
  constexpr int LSTR = 40;
  __shared__ u16 As[64 * LSTR], Bs[64 * LSTR];
  const int tid = threadIdx.x, l = tid & 63, w = tid >> 6;
  const int nwg = gridDim.x * gridDim.y;
  const int lin = blockIdx.y * gridDim.x + blockIdx.x;
  const int swzb = (lin & 7) * (nwg >> 3) + (lin >> 3);
  const int m0 = (swzb / gridDim.x) * 64, n0 = (swzb % gridDim.x) * 64;
  const int wr = (w >> 1) * 32, wc = (w & 1) * 32;
  const int lr = l & 15, lk = (l >> 4) * 8;
  const int sr = tid >> 2, sc = (tid & 3) * 8;
  f32x4 acc[2][2] = {};
  const float* pa0 = A + (size_t)(m0 + sr) * K + sc;
  const u16* pb0 = Bt + (size_t)(n0 + sr) * K + sc;
  f32x4 vaa = *(const f32x4*)pa0, vab = *(const f32x4*)(pa0 + 4);
  u16x8 vb0 = *(const u16x8*)pb0;
  for (int k0 = 0; k0 < K; k0 += 32) {
    u16x8 va0 = { f2bf(vaa[0]), f2bf(vaa[1]), f2bf(vaa[2]), f2bf(vaa[3]),
                  f2bf(vab[0]), f2bf(vab[1]), f2bf(vab[2]), f2bf(vab[3]) };
    *(u16x8*)&As[sr * LSTR + sc] = va0;
    *(u16x8*)&Bs[sr * LSTR + sc] = vb0;
    __syncthreads();
    if (k0 + 32 < K) {
      vaa = *(const f32x4*)(pa0 + k0 + 32);
      vab = *(const f32x4*)(pa0 + k0 + 36);
      vb0 = *(const u16x8*)(pb0 + k0 + 32);
    }
    bf16x8 af[2], bf[2];
#pragma unroll
    for (int i = 0; i < 2; i++) af[i] = ld_frag(&As[(wr + i * 16 + lr) * LSTR + lk]);
#pragma unroll
    for (int j = 0; j < 2; j++) bf[j] = ld_frag(&Bs[(wc + j * 16 + lr) * LSTR + lk]);
#pragma unroll
    for (int i = 0; i < 2; i++)
#pragma unroll
      for (int j = 0; j < 2; j++)
        acc[i][j] = __builtin_amdgcn_mfma_f32_16x16x32_bf16(af[i], bf[j], acc[i][j], 0, 0, 0);
    __syncthreads();
  }
#pragma unroll
  for (int i = 0; i < 2; i++)
#pragma unroll
    for (int j = 0; j < 2; j++) {
      int row = m0 + wr + i * 16 + (l >> 4) * 4;
      int col = n0 + wc + j * 16 + lr;
#pragma unroll
      for (int r = 0; r < 4; r++) {
        if (OUT_BF16) ((u16*)Cv)[(size_t)(row + r) * N + col] = f2bf(acc[i][j][r]);
        else          ((float*)Cv)[(size_t)(row + r) * N + col] = acc[i][j][r];
      }
    }
}

// ---------------- kv-down epilogue: rms_norm(16) + rope(64). one wave per row ----------------
__global__ __launch_bounds__(64) void k_kvnorm(const float* __restrict__ ckvf, const float* __restrict__ nw,
                                               const int* __restrict__ pos, u16* __restrict__ ckvn,
                                               u16* __restrict__ kropeb) {
  int row = blockIdx.x, l = threadIdx.x;
  const float* x = ckvf + (size_t)row * 128;
  float v = (l < 16) ? x[l] : 0.f;
  float ss = v * v;
  ss += __shfl_xor(ss, 1); ss += __shfl_xor(ss, 2); ss += __shfl_xor(ss, 4); ss += __shfl_xor(ss, 8);
  if (l < 16) ckvn[(size_t)row * 32 + l] = f2bf(v * rsqrtf(ss * (1.f / 16.f) + 1e-7f) * nw[l]);
  if (l >= 16 && l < 32) ckvn[(size_t)row * 32 + l] = 0;
  if (l < 32) {
    float invf = __expf(-(LOG10000 / 32.f) * (float)l);
    float ang = (float)pos[row] * invf;
    float c = cosf(ang), s = sinf(ang);
    float e = x[16 + 2 * l], o = x[17 + 2 * l];
    kropeb[(size_t)row * 64 + l]      = f2bf(e * c - o * s);
    kropeb[(size_t)row * 64 + l + 32] = f2bf(o * c + e * s);
  }
}

// ---------------- q rms_norm over 256 (scale = 1/sqrt(192) folded in). wave per row ----------------
__global__ __launch_bounds__(256) void k_rms256(const float* __restrict__ in, const float* __restrict__ w,
                                                u16* __restrict__ out, float scale) {
  int row = blockIdx.x * 4 + (threadIdx.x >> 6);
  int l = threadIdx.x & 63;
  const float* x = in + (size_t)row * 256;
  f32x4 v = *(const f32x4*)(x + l * 4);
  float ss = v[0] * v[0] + v[1] * v[1] + v[2] * v[2] + v[3] * v[3];
#pragma unroll
  for (int m = 1; m < 64; m <<= 1) ss += __shfl_xor(ss, m);
  float rinv = rsqrtf(ss * (1.f / 256.f) + 1e-7f) * scale;
  const f32x4 wv = *(const f32x4*)(w + l * 4);
  u16x4 o = { f2bf(v[0] * rinv * wv[0]), f2bf(v[1] * rinv * wv[1]),
              f2bf(v[2] * rinv * wv[2]), f2bf(v[3] * rinv * wv[3]) };
  *(u16x4*)(out + (size_t)row * 256 + l * 4) = o;
}

// ---------------- in-place rope on qproj (B,SQ,H,192): dims 128..191 per head ----------------
__global__ __launch_bounds__(256) void k_qrope(u16* __restrict__ q, const int* __restrict__ pos) {
  __shared__ float cs[32], sn[32];
  int bs = blockIdx.x, tid = threadIdx.x;
  if (tid < 32) {
    float invf = __expf(-(LOG10000 / 32.f) * (float)tid);
    float ang = (float)pos[bs] * invf;
    cs[tid] = cosf(ang); sn[tid] = sinf(ang);
  }
  __syncthreads();
  u16* base = q + (size_t)bs * 3072;
  int h0 = tid >> 5, p0 = tid & 31;
  int h1 = h0 + 8, p1 = p0;
  u16* r0p = base + h0 * 192 + 128;
  u16* r1p = base + h1 * 192 + 128;
  float e0 = bf2f(r0p[2 * p0]), o0 = bf2f(r0p[2 * p0 + 1]);
  float e1 = bf2f(r1p[2 * p1]), o1 = bf2f(r1p[2 * p1 + 1]);
  __syncthreads();
  r0p[p0]      = f2bf(e0 * cs[p0] - o0 * sn[p0]);
  r0p[p0 + 32] = f2bf(o0 * cs[p0] + e0 * sn[p0]);
  r1p[p1]      = f2bf(e1 * cs[p1] - o1 * sn[p1]);
  r1p[p1 + 32] = f2bf(o1 * cs[p1] + e1 * sn[p1]);
}

// -------- V^T extraction (vectorized): Ckv -> VT(BH,128,SKV). 64x64 tiles, u16x8 both sides --------
__global__ __launch_bounds__(256) void k_vt(const u16* __restrict__ Ckv, u16* __restrict__ VT) {
  __shared__ u16 tile[64][72];
  int bh = blockIdx.z, b = bh >> 4, h = bh & 15;
  int d0 = blockIdx.x * 64, s0 = blockIdx.y * 64;
  int tid = threadIdx.x;
#pragma unroll
  for (int p = 0; p < 2; p++) {
    int c = tid + p * 256;
    int r = c >> 3, cc = (c & 7) * 8;
    *(u16x8*)&tile[r][cc] =
        *(const u16x8*)&Ckv[((size_t)(b * 2048 + s0 + r)) * 4096 + h * 256 + 128 + d0 + cc];
  }
  __syncthreads();
#pragma unroll
  for (int p = 0; p < 2; p++) {
    int c = tid + p * 256;
    int d = c >> 3, ss = (c & 7) * 8;
    u16x8 v = { tile[ss][d],     tile[ss + 1][d], tile[ss + 2][d], tile[ss + 3][d],
                tile[ss + 4][d], tile[ss + 5][d], tile[ss + 6][d], tile[ss + 7][d] };
    *(u16x8*)&VT[((size_t)bh * 128 + d0 + d) * 2048 + s0 + ss] = v;
  }
}

// ---- fused attention v10: swapped-QK (S^T via mfma(K,Q)) + in-register P redistribution ----
// 8 waves x 16 q-rows, 40KB LDS (no Ps). P lives per-lane (one q-row per lane) -> 16 shfls
// replace the P LDS round-trip; lsum is a single scalar per lane.
__global__ __launch_bounds__(512, 2) void k_attn(const u16* __restrict__ Qp, const u16* __restrict__ Ckv,
                                                 const u16* __restrict__ kropeb, const u16* __restrict__ VT,
                                                 u16* __restrict__ AO) {
  __shared__ u16 Ks[64 * 192];   // 24KB, XOR-swizzled
  __shared__ u16 Vs[128 * 64];   // 16KB, d-major, XOR-swizzled
  const int tid = threadIdx.x, l = tid & 63, w = tid >> 6;
  const int lr = l & 15, g = l >> 4, lk = g * 8;
  const int bid = blockIdx.x, bh = bid & 31, qt = bid >> 5;  // bh%8 fixes XCD for K/V L2 reuse
  const int b = bh >> 4, hh = bh & 15;
  const int m0 = qt * 128;
  const u32 swz = (u32)(lr & 7) << 3;

  // Q fragments (B-operand): wave w owns q-rows m0 + w*16 .. +15
  bf16x8 qa[6];
  {
    const u16* qrow = Qp + (size_t)(b * 2048 + m0 + w * 16 + lr) * 3072 + hh * 192;
#pragma unroll
    for (int kk = 0; kk < 6; kk++) qa[kk] = ld_frag(qrow + kk * 32 + lk);
  }

  // staging: K = 64x192 (3 chunks/thread @512), V = 128x64 d-major (2 chunks/thread)
  const u16* kptr[3]; int kstep[3]; u32 klds[3];
#pragma unroll
  for (int p = 0; p < 3; p++) {
    int c2 = tid + p * 512;
    int r = c2 / 24, cc = c2 - r * 24;
    klds[p] = (u32)(r * 192 + cc * 8) ^ ((u32)(r & 7) << 3);
    if (cc < 16) { kptr[p] = Ckv + ((size_t)(b * 2048 + r)) * 4096 + hh * 256 + cc * 8; kstep[p] = 64 * 4096; }
    else         { kptr[p] = kropeb + ((size_t)(b * 2048 + r)) * 64 + (cc - 16) * 8;    kstep[p] = 64 * 64; }
  }
  const u16* vptr[2]; u32 vlds[2];
#pragma unroll
  for (int p = 0; p < 2; p++) {
    int c2 = tid + p * 512;
    int d = c2 >> 3, cc = c2 & 7;
    vlds[p] = (u32)(d * 64 + cc * 8) ^ ((u32)(d & 7) << 3);
    vptr[p] = VT + ((size_t)bh * 128 + d) * 2048 + cc * 8;
  }
  u16x8 kreg[3], vreg[2];
#pragma unroll
  for (int p = 0; p < 3; p++) { kreg[p] = *(const u16x8*)kptr[p]; kptr[p] += kstep[p]; }
#pragma unroll
  for (int p = 0; p < 2; p++) { vreg[p] = *(const u16x8*)vptr[p]; vptr[p] += 64; }

  f32x4 oacc[8] = {};
  float lsum = 0.f;
  const int srcA = lr + ((l & 16) << 1);  // q + 16 * (2*(g&1))
  const int srcB = srcA + 16;
  const bool hi = (l & 32) != 0;          // g>>1

  for (int t = 0; t < 32; t++) {
#pragma unroll
    for (int p = 0; p < 3; p++) *(u16x8*)&Ks[klds[p]] = kreg[p];
#pragma unroll
    for (int p = 0; p < 2; p++) *(u16x8*)&Vs[vlds[p]] = vreg[p];
    __syncthreads();
    if (t + 1 < 32) {
#pragma unroll
      for (int p = 0; p < 3; p++) { kreg[p] = *(const u16x8*)kptr[p]; kptr[p] += kstep[p]; }
#pragma unroll
      for (int p = 0; p < 2; p++) { vreg[p] = *(const u16x8*)vptr[p]; vptr[p] += 64; }
    }
    // S^T = K * Q^T: sacc[n] = D[kv rows 16n..][q cols]; lane: q=lr, kv=16n+4g+r
    f32x4 sacc[4] = {};
    __builtin_amdgcn_s_setprio(1);
#pragma unroll
    for (int n = 0; n < 4; n++)
#pragma unroll
      for (int kk = 0; kk < 6; kk++)
        sacc[n] = __builtin_amdgcn_mfma_f32_16x16x32_bf16(
            ld_frag(&Ks[(u32)((n * 16 + lr) * 192 + kk * 32 + lk) ^ swz]), qa[kk], sacc[n], 0, 0, 0);
    __builtin_amdgcn_s_setprio(0);
    // P = exp(S): per-lane (one q-row); pack bf16 pairs
    u32 pw[4][2];
#pragma unroll
    for (int n = 0; n < 4; n++) {
      float p0 = __expf(sacc[n][0]), p1 = __expf(sacc[n][1]),
            p2 = __expf(sacc[n][2]), p3 = __expf(sacc[n][3]);
      lsum += (p0 + p1) + (p2 + p3);
      pw[n][0] = (u32)f2bf(p0) | ((u32)f2bf(p1) << 16);
      pw[n][1] = (u32)f2bf(p2) | ((u32)f2bf(p3) << 16);
    }
    // redistribute: pa[kk2] elem-pair i of lane(q=lr,g) = pw[2kk2+(g>>1)][i'] from lane q+16*(2(g&1)+b)
    u32 pa32[2][4];
#pragma unroll
    for (int kk2 = 0; kk2 < 2; kk2++) {
      u32 t0a = __shfl(pw[2 * kk2][0], srcA), t1a = __shfl(pw[2 * kk2 + 1][0], srcA);
      u32 t0b = __shfl(pw[2 * kk2][1], srcA), t1b = __shfl(pw[2 * kk2 + 1][1], srcA);
      u32 t0c = __shfl(pw[2 * kk2][0], srcB), t1c = __shfl(pw[2 * kk2 + 1][0], srcB);
      u32 t0d = __shfl(pw[2 * kk2][1], srcB), t1d = __shfl(pw[2 * kk2 + 1][1], srcB);
      pa32[kk2][0] = hi ? t1a : t0a;
      pa32[kk2][1] = hi ? t1b : t0b;
      pa32[kk2][2] = hi ? t1c : t0c;
      pa32[kk2][3] = hi ? t1d : t0d;
    }
    // O += P * V
    __builtin_amdgcn_s_setprio(1);
#pragma unroll
    for (int kk2 = 0; kk2 < 2; kk2++) {
      u32x4 pv = { pa32[kk2][0], pa32[kk2][1], pa32[kk2][2], pa32[kk2][3] };
      bf16x8 paf = __builtin_bit_cast(bf16x8, pv);
#pragma unroll
      for (int n2 = 0; n2 < 8; n2++)
        oacc[n2] = __builtin_amdgcn_mfma_f32_16x16x32_bf16(
            paf, ld_frag(&Vs[(u32)((n2 * 16 + lr) * 64 + kk2 * 32 + lk) ^ swz]), oacc[n2], 0, 0, 0);
    }
    __builtin_amdgcn_s_setprio(0);
    __syncthreads();
  }
  // epilogue: lsum held per q=lr; sum across the 4 g-groups, then redistribute to rows 4g+r
  float s = lsum;
  s += __shfl_xor(s, 16);
  s += __shfl_xor(s, 32);
  float rl = 1.f / s;
  float rlv[4];
#pragma unroll
  for (int r = 0; r < 4; r++) rlv[r] = __shfl(rl, g * 4 + r);
#pragma unroll
  for (int n2 = 0; n2 < 8; n2++)
#pragma unroll
    for (int r = 0; r < 4; r++) {
      int row = m0 + w * 16 + g * 4 + r;
      AO[((size_t)(b * 2048 + row) * 16 + hh) * 128 + n2 * 16 + lr] = f2bf(oacc[n2][r] * rlv[r]);
    }
}

extern "C" void kernel_launch(void* const* d_in, const int* in_sizes, int n_in,
                              void* d_out, int out_size, void* d_ws, size_t ws_size,
                              hipStream_t stream) {
  const float* q_in  = (const float*)d_in[0];
  const float* kv_in = (const float*)d_in[1];
  const int*   qpos  = (const int*)d_in[2];
  const int*   kpos  = (const int*)d_in[3];
  const float* Wqd   = (const float*)d_in[4];
  const float* qnw   = (const float*)d_in[5];
  const float* Wqu   = (const float*)d_in[6];
  const float* Wkvd  = (const float*)d_in[7];
  const float* kvnw  = (const float*)d_in[8];
  const float* Wkvu  = (const float*)d_in[9];
  const float* Wo    = (const float*)d_in[10];
  float* out = (float*)d_out;
  char* ws = (char*)d_ws;
  size_t off = 0;
  auto alloc = [&](size_t bytes) -> void* {
    void* p = ws + off; off += (bytes + 255) & ~(size_t)255; return p;
  };
  u16*   WqdT   = (u16*)alloc(256ull * 1024 * 2);
  u16*   WquT   = (u16*)alloc(3072ull * 256 * 2);
  u16*   WkvdT  = (u16*)alloc(128ull * 1024 * 2);
  u16*   WkvuT  = (u16*)alloc(4096ull * 32 * 2);
  u16*   WoT    = (u16*)alloc(1024ull * 2048 * 2);
  float* ckvf   = (float*)alloc(4096ull * 128 * 4);
  u16*   ckvn   = (u16*)alloc(4096ull * 32 * 2);
  u16*   kropeb = (u16*)alloc(4096ull * 64 * 2);
  u16*   Ckv    = (u16*)alloc(4096ull * 4096 * 2);
  u16*   VTb    = (u16*)alloc(32ull * 128 * 2048 * 2);
  float* cq     = (float*)alloc(4096ull * 256 * 4);
  u16*   cqn    = (u16*)alloc(4096ull * 256 * 2);
  u16*   qproj  = (u16*)alloc(4096ull * 3072 * 2);
  u16*   AOb    = (u16*)alloc(4096ull * 2048 * 2);
  (void)in_sizes; (void)n_in; (void)out_size; (void)ws_size;

  // weight transposes (to bf16 (N,K), zero-padded)
  k_wtrans<<<dim3(8, 32), 256, 0, stream>>>(Wqd, WqdT, 1024, 256, 1024);
  k_wtrans<<<dim3(96, 8), 256, 0, stream>>>(Wqu, WquT, 256, 3072, 256);
  k_wtrans<<<dim3(4, 32), 256, 0, stream>>>(Wkvd, WkvdT, 1024, 80, 1024);
  k_wtrans<<<dim3(128, 1), 256, 0, stream>>>(Wkvu, WkvuT, 16, 4096, 32);
  k_wtrans<<<dim3(32, 64), 256, 0, stream>>>(Wo, WoT, 2048, 1024, 2048);
  // kv path (f32-A down-GEMM: cvt fused into staging)
  k_gemm64f<0><<<dim3(2, 64), 256, 0, stream>>>(kv_in, WkvdT, ckvf, 4096, 128, 1024);
  k_kvnorm<<<4096, 64, 0, stream>>>(ckvf, kvnw, kpos, ckvn, kropeb);
  k_gemm<1><<<dim3(32, 32), 256, 0, stream>>>(ckvn, WkvuT, Ckv, 4096, 4096, 32);
  k_vt<<<dim3(2, 32, 32), 256, 0, stream>>>(Ckv, VTb);
  // q path
  k_gemm64f<0><<<dim3(4, 64), 256, 0, stream>>>(q_in, WqdT, cq, 4096, 256, 1024);
  k_rms256<<<1024, 256, 0, stream>>>(cq, qnw, cqn, 0.07216878364870322f);
  k_gemm<1><<<dim3(24, 32), 256, 0, stream>>>(cqn, WquT, qproj, 4096, 3072, 256);
  k_qrope<<<4096, 256, 0, stream>>>(qproj, qpos);
  // attention (512-thread blocks: 8 waves x 16 q-rows, no P LDS)
  k_attn<<<512, 512, 0, stream>>>(qproj, Ckv, kropeb, VTb, AOb);
  // output projection
  k_gemmh<0><<<dim3(8, 64), 256, 0, stream>>>(AOb, WoT, out, 4096, 1024, 2048);
}

// Round 11
// 258.416 us; speedup vs baseline: 1.6701x; 1.0034x over previous
//
#include <hip/hip_runtime.h>

typedef unsigned short u16;
typedef unsigned int u32;
typedef u16 u16x4 __attribute__((ext_vector_type(4)));
typedef u16 u16x8 __attribute__((ext_vector_type(8)));
typedef u32 u32x4 __attribute__((ext_vector_type(4)));
typedef float f32x4 __attribute__((ext_vector_type(4)));
typedef __bf16 bf16x8 __attribute__((ext_vector_type(8)));

#define DEV static __device__ __forceinline__

DEV float bf2f(u16 u) { u32 v = ((u32)u) << 16; float f; __builtin_memcpy(&f, &v, 4); return f; }
DEV u16 f2bf(float f) { u32 v; __builtin_memcpy(&v, &f, 4); v += 0x7fffu + ((v >> 16) & 1u); return (u16)(v >> 16); }
DEV bf16x8 ld_frag(const u16* p) { u16x8 v = *(const u16x8*)p; return __builtin_bit_cast(bf16x8, v); }

#define LOG10000 9.210340372f

// ------- transpose f32 (R,C) -> bf16 (Cp,Rp), zero-padded. grid(Cp/32,Rp/32), block 256 -------
__global__ __launch_bounds__(256) void k_wtrans(const float* __restrict__ in, u16* __restrict__ out,
                                                int R, int C, int Rp) {
  __shared__ float tile[32][33];
  int c0 = blockIdx.x * 32, r0 = blockIdx.y * 32;
  int tx = threadIdx.x & 31, ty = threadIdx.x >> 5;
#pragma unroll
  for (int p = 0; p < 4; p++) {
    int r = r0 + ty + p * 8, c = c0 + tx;
    tile[ty + p * 8][tx] = (r < R && c < C) ? in[(size_t)r * C + c] : 0.f;
  }
  __syncthreads();
#pragma unroll
  for (int p = 0; p < 4; p++)
    out[(size_t)(c0 + ty + p * 8) * Rp + r0 + tx] = f2bf(tile[tx][ty + p * 8]);
}

// ---------------- GEMM: C(M,N) = A(M,K)bf16 * Bt(N,K)bf16, 128x128 tile, 4 waves ----------------
template <int OUT_BF16>
__global__ __launch_bounds__(256) void k_gemm(const u16* __restrict__ A, const u16* __restrict__ Bt,
                                              void* __restrict__ Cv, int M, int N, int K) {
  constexpr int LSTR = 40;
  __shared__ u16 As[128 * LSTR], Bs[128 * LSTR];
  const int tid = threadIdx.x, l = tid & 63, w = tid >> 6;
  const int nwg = gridDim.x * gridDim.y;
  const int lin = blockIdx.y * gridDim.x + blockIdx.x;
  const int swzb = (lin & 7) * (nwg >> 3) + (lin >> 3);
  const int m0 = (swzb / gridDim.x) * 128, n0 = (swzb % gridDim.x) * 128;
  const int wr = (w >> 1) * 64, wc = (w & 1) * 64;
  const int lr = l & 15, lk = (l >> 4) * 8;
  const int sr = tid >> 2, sc = (tid & 3) * 8;
  f32x4 acc[4][4] = {};
  const u16* pa0 = A + (size_t)(m0 + sr) * K + sc;
  const u16* pa1 = A + (size_t)(m0 + 64 + sr) * K + sc;
  const u16* pb0 = Bt + (size_t)(n0 + sr) * K + sc;
  const u16* pb1 = Bt + (size_t)(n0 + 64 + sr) * K + sc;
  u16x8 va0 = *(const u16x8*)pa0, va1 = *(const u16x8*)pa1;
  u16x8 vb0 = *(const u16x8*)pb0, vb1 = *(const u16x8*)pb1;
  for (int k0 = 0; k0 < K; k0 += 32) {
    *(u16x8*)&As[sr * LSTR + sc] = va0;
    *(u16x8*)&As[(64 + sr) * LSTR + sc] = va1;
    *(u16x8*)&Bs[sr * LSTR + sc] = vb0;
    *(u16x8*)&Bs[(64 + sr) * LSTR + sc] = vb1;
    __syncthreads();
    if (k0 + 32 < K) {
      va0 = *(const u16x8*)(pa0 + k0 + 32);
      va1 = *(const u16x8*)(pa1 + k0 + 32);
      vb0 = *(const u16x8*)(pb0 + k0 + 32);
      vb1 = *(const u16x8*)(pb1 + k0 + 32);
    }
    bf16x8 af[4], bf[4];
#pragma unroll
    for (int i = 0; i < 4; i++) af[i] = ld_frag(&As[(wr + i * 16 + lr) * LSTR + lk]);
#pragma unroll
    for (int j = 0; j < 4; j++) bf[j] = ld_frag(&Bs[(wc + j * 16 + lr) * LSTR + lk]);
#pragma unroll
    for (int i = 0; i < 4; i++)
#pragma unroll
      for (int j = 0; j < 4; j++)
        acc[i][j] = __builtin_amdgcn_mfma_f32_16x16x32_bf16(af[i], bf[j], acc[i][j], 0, 0, 0);
    __syncthreads();
  }
#pragma unroll
  for (int i = 0; i < 4; i++)
#pragma unroll
    for (int j = 0; j < 4; j++) {
      int row = m0 + wr + i * 16 + (l >> 4) * 4;
      int col = n0 + wc + j * 16 + lr;
#pragma unroll
      for (int r = 0; r < 4; r++) {
        if (OUT_BF16) ((u16*)Cv)[(size_t)(row + r) * N + col] = f2bf(acc[i][j][r]);
        else          ((float*)Cv)[(size_t)(row + r) * N + col] = acc[i][j][r];
      }
    }
}

// ---- kv_up GEMM: K-part tiles -> Ckv (row-major), V-part tiles -> VT (transposed direct) ----
// N=4096, 128-wide tiles: (n0&255)==0 -> K-part, ==128 -> V-part. Kills the separate k_vt pass.
__global__ __launch_bounds__(256) void k_gemm_kv(const u16* __restrict__ A, const u16* __restrict__ Bt,
                                                 u16* __restrict__ Ckv, u16* __restrict__ VT,
                                                 int M, int N, int K) {
  constexpr int LSTR = 40;
  __shared__ u16 As[128 * LSTR], Bs[128 * LSTR];
  const int tid = threadIdx.x, l = tid & 63, w = tid >> 6;
  const int nwg = gridDim.x * gridDim.y;
  const int lin = blockIdx.y * gridDim.x + blockIdx.x;
  const int swzb = (lin & 7) * (nwg >> 3) + (lin >> 3);
  const int m0 = (swzb / gridDim.x) * 128, n0 = (swzb % gridDim.x) * 128;
  const int wr = (w >> 1) * 64, wc = (w & 1) * 64;
  const int lr = l & 15, lk = (l >> 4) * 8;
  const int sr = tid >> 2, sc = (tid & 3) * 8;
  f32x4 acc[4][4] = {};
  const u16* pa0 = A + (size_t)(m0 + sr) * K + sc;
  const u16* pa1 = A + (size_t)(m0 + 64 + sr) * K + sc;
  const u16* pb0 = Bt + (size_t)(n0 + sr) * K + sc;
  const u16* pb1 = Bt + (size_t)(n0 + 64 + sr) * K + sc;
  u16x8 va0 = *(const u16x8*)pa0, va1 = *(const u16x8*)pa1;
  u16x8 vb0 = *(const u16x8*)pb0, vb1 = *(const u16x8*)pb1;
  for (int k0 = 0; k0 < K; k0 += 32) {
    *(u16x8*)&As[sr * LSTR + sc] = va0;
    *(u16x8*)&As[(64 + sr) * LSTR + sc] = va1;
    *(u16x8*)&Bs[sr * LSTR + sc] = vb0;
    *(u16x8*)&Bs[(64 + sr) * LSTR + sc] = vb1;
    __syncthreads();
    if (k0 + 32 < K) {
      va0 = *(const u16x8*)(pa0 + k0 + 32);
      va1 = *(const u16x8*)(pa1 + k0 + 32);
      vb0 = *(const u16x8*)(pb0 + k0 + 32);
      vb1 = *(const u16x8*)(pb1 + k0 + 32);
    }
    bf16x8 af[4], bf[4];
#pragma unroll
    for (int i = 0; i < 4; i++) af[i] = ld_frag(&As[(wr + i * 16 + lr) * LSTR + lk]);
#pragma unroll
    for (int j = 0; j < 4; j++) bf[j] = ld_frag(&Bs[(wc + j * 16 + lr) * LSTR + lk]);
#pragma unroll
    for (int i = 0; i < 4; i++)
#pragma unroll
      for (int j = 0; j < 4; j++)
        acc[i][j] = __builtin_amdgcn_mfma_f32_16x16x32_bf16(af[i], bf[j], acc[i][j], 0, 0, 0);
    __syncthreads();
  }
  if ((n0 & 255) < 128) {  // K-part -> Ckv row-major
#pragma unroll
    for (int i = 0; i < 4; i++)
#pragma unroll
      for (int j = 0; j < 4; j++) {
        int row = m0 + wr + i * 16 + (l >> 4) * 4;
        int col = n0 + wc + j * 16 + lr;
#pragma unroll
        for (int r = 0; r < 4; r++)
          Ckv[(size_t)(row + r) * N + col] = f2bf(acc[i][j][r]);
      }
  } else {  // V-part -> VT(BH,128,SKV), s-contiguous u16x4 stores
#pragma unroll
    for (int i = 0; i < 4; i++)
#pragma unroll
      for (int j = 0; j < 4; j++) {
        int row = m0 + wr + i * 16 + (l >> 4) * 4;
        int col = n0 + wc + j * 16 + lr;
        int bb = row >> 11, srow = row & 2047;
        int hh2 = col >> 8, d = col & 127;
        u16x4 pk = { f2bf(acc[i][j][0]), f2bf(acc[i][j][1]),
                     f2bf(acc[i][j][2]), f2bf(acc[i][j][3]) };
        *(u16x4*)&VT[((size_t)(bb * 16 + hh2) * 128 + d) * 2048 + srow] = pk;
      }
  }
}

// ---------------- GEMM 64(M)x128(N) tile, 4 waves (2M x 2N) ----------------
template <int OUT_BF16>
__global__ __launch_bounds__(256) void k_gemmh(const u16* __restrict__ A, const u16* __restrict__ Bt,
                                               void* __restrict__ Cv, int M, int N, int K) {
  constexpr int LSTR = 40;
  __shared__ u16 As[64 * LSTR], Bs[128 * LSTR];
  const int tid = threadIdx.x, l = tid & 63, w = tid >> 6;
  const int nwg = gridDim.x * gridDim.y;
  const int lin = blockIdx.y * gridDim.x + blockIdx.x;
  const int swzb = (lin & 7) * (nwg >> 3) + (lin >> 3);
  const int m0 = (swzb / gridDim.x) * 64, n0 = (swzb % gridDim.x) * 128;
  const int wr = (w >> 1) * 32, wc = (w & 1) * 64;
  const int lr = l & 15, lk = (l >> 4) * 8;
  const int sr = tid >> 2, sc = (tid & 3) * 8;
  f32x4 acc[2][4] = {};
  const u16* pa0 = A + (size_t)(m0 + sr) * K + sc;
  const u16* pb0 = Bt + (size_t)(n0 + sr) * K + sc;
  const u16* pb1 = Bt + (size_t)(n0 + 64 + sr) * K + sc;
  u16x8 va0 = *(const u16x8*)pa0;
  u16x8 vb0 = *(const u16x8*)pb0, vb1 = *(const u16x8*)pb1;
  for (int k0 = 0; k0 < K; k0 += 32) {
    *(u16x8*)&As[sr * LSTR + sc] = va0;
    *(u16x8*)&Bs[sr * LSTR + sc] = vb0;
    *(u16x8*)&Bs[(64 + sr) * LSTR + sc] = vb1;
    __syncthreads();
    if (k0 + 32 < K) {
      va0 = *(const u16x8*)(pa0 + k0 + 32);
      vb0 = *(const u16x8*)(pb0 + k0 + 32);
      vb1 = *(const u16x8*)(pb1 + k0 + 32);
    }
    bf16x8 af[2], bf[4];
#pragma unroll
    for (int i = 0; i < 2; i++) af[i] = ld_frag(&As[(wr + i * 16 + lr) * LSTR + lk]);
#pragma unroll
    for (int j = 0; j < 4; j++) bf[j] = ld_frag(&Bs[(wc + j * 16 + lr) * LSTR + lk]);
#pragma unroll
    for (int i = 0; i < 2; i++)
#pragma unroll
      for (int j = 0; j < 4; j++)
        acc[i][j] = __builtin_amdgcn_mfma_f32_16x16x32_bf16(af[i], bf[j], acc[i][j], 0, 0, 0);
    __syncthreads();
  }
#pragma unroll
  for (int i = 0; i < 2; i++)
#pragma unroll
    for (int j = 0; j < 4; j++) {
      int row = m0 + wr + i * 16 + (l >> 4) * 4;
      int col = n0 + wc + j * 16 + lr;
#pragma unroll
      for (int r = 0; r < 4; r++) {
        if (OUT_BF16) ((u16*)Cv)[(size_t)(row + r) * N + col] = f2bf(acc[i][j][r]);
        else          ((float*)Cv)[(size_t)(row + r) * N + col] = acc[i][j][r];
      }
    }
}

// ------- GEMM 64x64 tile, A in f32 (fused cvt in staging): C = A(M,K)f32 * Bt(N,K)bf16 -------
template <int OUT_BF16>
__global__ __launch_bounds__(256) void k_gemm64f(const float* __restrict__ A, const u16* __restrict__ Bt,
                                                 void* __restrict__ Cv, int M, int N, int K) {
  constexpr int LSTR = 40;
  __shared__ u16 As[64 * LSTR], Bs[64 * LSTR];
  const int tid = threadIdx.x, l = tid & 63, w = tid >> 6;
  const int nwg = gridDim.x * gridDim.y;
  const int lin = blockIdx.y * gridDim.x + blockIdx.x;
  const int swzb = (lin & 7) * (nwg >> 3) + (lin >> 3);
  const int m0 = (swzb / gridDim.x) * 64, n0 = (swzb % gridDim.x) * 64;
  const int wr = (w >> 1) * 32, wc = (w & 1) * 32;
  const int lr = l & 15, lk = (l >> 4) * 8;
  const int sr = tid >> 2, sc = (tid & 3) * 8;
  f32x4 acc[2][2] = {};
  const float* pa0 = A + (size_t)(m0 + sr) * K + sc;
  const u16* pb0 = Bt + (size_t)(n0 + sr) * K + sc;
  f32x4 vaa = *(const f32x4*)pa0, vab = *(const f32x4*)(pa0 + 4);
  u16x8 vb0 = *(const u16x8*)pb0;
  for (int k0 = 0; k0 < K; k0 += 32) {
    u16x8 va0 = { f2bf(vaa[0]), f2bf(vaa[1]), f2bf(vaa[2]), f2bf(vaa[3]),
                  f2bf(vab[0]), f2bf(vab[1]), f2bf(vab[2]), f2bf(vab[3]) };
    *(u16x8*)&As[sr * LSTR + sc] = va0;
    *(u16x8*)&Bs[sr * LSTR + sc] = vb0;
    __syncthreads();
    if (k0 + 32 < K) {
      vaa = *(const f32x4*)(pa0 + k0 + 32);
      vab = *(const f32x4*)(pa0 + k0 + 36);
      vb0 = *(const u16x8*)(pb0 + k0 + 32);
    }
    bf16x8 af[2], bf[2];
#pragma unroll
    for (int i = 0; i < 2; i++) af[i] = ld_frag(&As[(wr + i * 16 + lr) * LSTR + lk]);
#pragma unroll
    for (int j = 0; j < 2; j++) bf[j] = ld_frag(&Bs[(wc + j * 16 + lr) * LSTR + lk]);
#pragma unroll
    for (int i = 0; i < 2; i++)
#pragma unroll
      for (int j = 0; j < 2; j++)
        acc[i][j] = __builtin_amdgcn_mfma_f32_16x16x32_bf16(af[i], bf[j], acc[i][j], 0, 0, 0);
    __syncthreads();
  }
#pragma unroll
  for (int i = 0; i < 2; i++)
#pragma unroll
    for (int j = 0; j < 2; j++) {
      int row = m0 + wr + i * 16 + (l >> 4) * 4;
      int col = n0 + wc + j * 16 + lr;
#pragma unroll
      for (int r = 0; r < 4; r++) {
        if (OUT_BF16) ((u16*)Cv)[(size_t)(row + r) * N + col] = f2bf(acc[i][j][r]);
        else          ((float*)Cv)[(size_t)(row + r) * N + col] = acc[i][j][r];
      }
    }
}

// ---------------- kv-down epilogue: rms_norm(16) + rope(64). one wave per row ----------------
__global__ __launch_bounds__(64) void k_kvnorm(const float* __restrict__ ckvf, const float* __restrict__ nw,
                                               const int* __restrict__ pos, u16* __restrict__ ckvn,
                                               u16* __restrict__ kropeb) {
  int row = blockIdx.x, l = threadIdx.x;
  const float* x = ckvf + (size_t)row * 128;
  float v = (l < 16) ? x[l] : 0.f;
  float ss = v * v;
  ss += __shfl_xor(ss, 1); ss += __shfl_xor(ss, 2); ss += __shfl_xor(ss, 4); ss += __shfl_xor(ss, 8);
  if (l < 16) ckvn[(size_t)row * 32 + l] = f2bf(v * rsqrtf(ss * (1.f / 16.f) + 1e-7f) * nw[l]);
  if (l >= 16 && l < 32) ckvn[(size_t)row * 32 + l] = 0;
  if (l < 32) {
    float invf = __expf(-(LOG10000 / 32.f) * (float)l);
    float ang = (float)pos[row] * invf;
    float c = cosf(ang), s = sinf(ang);
    float e = x[16 + 2 * l], o = x[17 + 2 * l];
    kropeb[(size_t)row * 64 + l]      = f2bf(e * c - o * s);
    kropeb[(size_t)row * 64 + l + 32] = f2bf(o * c + e * s);
  }
}

// ---------------- q rms_norm over 256 (scale = 1/sqrt(192) folded in). wave per row ----------------
__global__ __launch_bounds__(256) void k_rms256(const float* __restrict__ in, const float* __restrict__ w,
                                                u16* __restrict__ out, float scale) {
  int row = blockIdx.x * 4 + (threadIdx.x >> 6);
  int l = threadIdx.x & 63;
  const float* x = in + (size_t)row * 256;
  f32x4 v = *(const f32x4*)(x + l * 4);
  float ss = v[0] * v[0] + v[1] * v[1] + v[2] * v[2] + v[3] * v[3];
#pragma unroll
  for (int m = 1; m < 64; m <<= 1) ss += __shfl_xor(ss, m);
  float rinv = rsqrtf(ss * (1.f / 256.f) + 1e-7f) * scale;
  const f32x4 wv = *(const f32x4*)(w + l * 4);
  u16x4 o = { f2bf(v[0] * rinv * wv[0]), f2bf(v[1] * rinv * wv[1]),
              f2bf(v[2] * rinv * wv[2]), f2bf(v[3] * rinv * wv[3]) };
  *(u16x4*)(out + (size_t)row * 256 + l * 4) = o;
}

// ---------------- in-place rope on qproj (B,SQ,H,192): dims 128..191 per head ----------------
__global__ __launch_bounds__(256) void k_qrope(u16* __restrict__ q, const int* __restrict__ pos) {
  __shared__ float cs[32], sn[32];
  int bs = blockIdx.x, tid = threadIdx.x;
  if (tid < 32) {
    float invf = __expf(-(LOG10000 / 32.f) * (float)tid);
    float ang = (float)pos[bs] * invf;
    cs[tid] = cosf(ang); sn[tid] = sinf(ang);
  }
  __syncthreads();
  u16* base = q + (size_t)bs * 3072;
  int h0 = tid >> 5, p0 = tid & 31;
  int h1 = h0 + 8, p1 = p0;
  u16* r0p = base + h0 * 192 + 128;
  u16* r1p = base + h1 * 192 + 128;
  float e0 = bf2f(r0p[2 * p0]), o0 = bf2f(r0p[2 * p0 + 1]);
  float e1 = bf2f(r1p[2 * p1]), o1 = bf2f(r1p[2 * p1 + 1]);
  __syncthreads();
  r0p[p0]      = f2bf(e0 * cs[p0] - o0 * sn[p0]);
  r0p[p0 + 32] = f2bf(o0 * cs[p0] + e0 * sn[p0]);
  r1p[p1]      = f2bf(e1 * cs[p1] - o1 * sn[p1]);
  r1p[p1 + 32] = f2bf(o1 * cs[p1] + e1 * sn[p1]);
}

// ---- fused attention v11: swapped-QK + in-register P, double-buffered K/V LDS (1 barrier/tile) ----
__global__ __launch_bounds__(512, 2) void k_attn(const u16* __restrict__ Qp, const u16* __restrict__ Ckv,
                                                 const u16* __restrict__ kropeb, const u16* __restrict__ VT,
                                                 u16* __restrict__ AO) {
  constexpr u32 KSZ = 64 * 192, VSZ = 128 * 64;
  __shared__ u16 Ks[2 * KSZ];   // 48KB
  __shared__ u16 Vs[2 * VSZ];   // 32KB  -> 80KB/block, 2 blocks = 160KB (exact fit)
  const int tid = threadIdx.x, l = tid & 63, w = tid >> 6;
  const int lr = l & 15, g = l >> 4, lk = g * 8;
  const int bid = blockIdx.x, bh = bid & 31, qt = bid >> 5;  // bh%8 fixes XCD for K/V L2 reuse
  const int b = bh >> 4, hh = bh & 15;
  const int m0 = qt * 128;
  const u32 swz = (u32)(lr & 7) << 3;

  // Q fragments (B-operand): wave w owns q-rows m0 + w*16 .. +15
  bf16x8 qa[6];
  {
    const u16* qrow = Qp + (size_t)(b * 2048 + m0 + w * 16 + lr) * 3072 + hh * 192;
#pragma unroll
    for (int kk = 0; kk < 6; kk++) qa[kk] = ld_frag(qrow + kk * 32 + lk);
  }

  // staging: K = 64x192 (3 chunks/thread @512), V = 128x64 d-major (2 chunks/thread)
  const u16* kptr[3]; int kstep[3]; u32 klds[3];
#pragma unroll
  for (int p = 0; p < 3; p++) {
    int c2 = tid + p * 512;
    int r = c2 / 24, cc = c2 - r * 24;
    klds[p] = (u32)(r * 192 + cc * 8) ^ ((u32)(r & 7) << 3);
    if (cc < 16) { kptr[p] = Ckv + ((size_t)(b * 2048 + r)) * 4096 + hh * 256 + cc * 8; kstep[p] = 64 * 4096; }
    else         { kptr[p] = kropeb + ((size_t)(b * 2048 + r)) * 64 + (cc - 16) * 8;    kstep[p] = 64 * 64; }
  }
  const u16* vptr[2]; u32 vlds[2];
#pragma unroll
  for (int p = 0; p < 2; p++) {
    int c2 = tid + p * 512;
    int d = c2 >> 3, cc = c2 & 7;
    vlds[p] = (u32)(d * 64 + cc * 8) ^ ((u32)(d & 7) << 3);
    vptr[p] = VT + ((size_t)bh * 128 + d) * 2048 + cc * 8;
  }
  u16x8 kreg[3], vreg[2];
  // prologue: tile 0 -> buf0; issue tile 1 loads
#pragma unroll
  for (int p = 0; p < 3; p++) { kreg[p] = *(const u16x8*)kptr[p]; kptr[p] += kstep[p]; }
#pragma unroll
  for (int p = 0; p < 2; p++) { vreg[p] = *(const u16x8*)vptr[p]; vptr[p] += 64; }
#pragma unroll
  for (int p = 0; p < 3; p++) *(u16x8*)&Ks[klds[p]] = kreg[p];
#pragma unroll
  for (int p = 0; p < 2; p++) *(u16x8*)&Vs[vlds[p]] = vreg[p];
#pragma unroll
  for (int p = 0; p < 3; p++) { kreg[p] = *(const u16x8*)kptr[p]; kptr[p] += kstep[p]; }
#pragma unroll
  for (int p = 0; p < 2; p++) { vreg[p] = *(const u16x8*)vptr[p]; vptr[p] += 64; }
  __syncthreads();

  f32x4 oacc[8] = {};
  float lsum = 0.f;
  const int srcA = lr + ((l & 16) << 1);
  const int srcB = srcA + 16;
  const bool hi = (l & 32) != 0;

  for (int t = 0; t < 32; t++) {
    const u32 curK = (u32)(t & 1) * KSZ, curV = (u32)(t & 1) * VSZ;
    const u32 nxtK = curK ^ KSZ, nxtV = curV ^ VSZ;
    if (t + 1 < 32) {  // write staged tile t+1 (vmcnt wait: issuing wave only)
#pragma unroll
      for (int p = 0; p < 3; p++) *(u16x8*)&Ks[nxtK + klds[p]] = kreg[p];
#pragma unroll
      for (int p = 0; p < 2; p++) *(u16x8*)&Vs[nxtV + vlds[p]] = vreg[p];
    }
    if (t + 2 < 32) {  // issue loads for tile t+2
#pragma unroll
      for (int p = 0; p < 3; p++) { kreg[p] = *(const u16x8*)kptr[p]; kptr[p] += kstep[p]; }
#pragma unroll
      for (int p = 0; p < 2; p++) { vreg[p] = *(const u16x8*)vptr[p]; vptr[p] += 64; }
    }
    // S^T = K * Q^T: lane holds q=lr, kv=16n+4g+r
    f32x4 sacc[4] = {};
    __builtin_amdgcn_s_setprio(1);
#pragma unroll
    for (int n = 0; n < 4; n++)
#pragma unroll
      for (int kk = 0; kk < 6; kk++)
        sacc[n] = __builtin_amdgcn_mfma_f32_16x16x32_bf16(
            ld_frag(&Ks[curK + ((u32)((n * 16 + lr) * 192 + kk * 32 + lk) ^ swz)]), qa[kk], sacc[n], 0, 0, 0);
    __builtin_amdgcn_s_setprio(0);
    // P = exp(S): per-lane (one q-row); pack bf16 pairs
    u32 pw[4][2];
#pragma unroll
    for (int n = 0; n < 4; n++) {
      float p0 = __expf(sacc[n][0]), p1 = __expf(sacc[n][1]),
            p2 = __expf(sacc[n][2]), p3 = __expf(sacc[n][3]);
      lsum += (p0 + p1) + (p2 + p3);
      pw[n][0] = (u32)f2bf(p0) | ((u32)f2bf(p1) << 16);
      pw[n][1] = (u32)f2bf(p2) | ((u32)f2bf(p3) << 16);
    }
    // redistribute P to PV A-fragment layout (16 bpermutes, no LDS buffer)
    u32 pa32[2][4];
#pragma unroll
    for (int kk2 = 0; kk2 < 2; kk2++) {
      u32 t0a = __shfl(pw[2 * kk2][0], srcA), t1a = __shfl(pw[2 * kk2 + 1][0], srcA);
      u32 t0b = __shfl(pw[2 * kk2][1], srcA), t1b = __shfl(pw[2 * kk2 + 1][1], srcA);
      u32 t0c = __shfl(pw[2 * kk2][0], srcB), t1c = __shfl(pw[2 * kk2 + 1][0], srcB);
      u32 t0d = __shfl(pw[2 * kk2][1], srcB), t1d = __shfl(pw[2 * kk2 + 1][1], srcB);
      pa32[kk2][0] = hi ? t1a : t0a;
      pa32[kk2][1] = hi ? t1b : t0b;
      pa32[kk2][2] = hi ? t1c : t0c;
      pa32[kk2][3] = hi ? t1d : t0d;
    }
    // O += P * V
    __builtin_amdgcn_s_setprio(1);
#pragma unroll
    for (int kk2 = 0; kk2 < 2; kk2++) {
      u32x4 pv = { pa32[kk2][0], pa32[kk2][1], pa32[kk2][2], pa32[kk2][3] };
      bf16x8 paf = __builtin_bit_cast(bf16x8, pv);
#pragma unroll
      for (int n2 = 0; n2 < 8; n2++)
        oacc[n2] = __builtin_amdgcn_mfma_f32_16x16x32_bf16(
            paf, ld_frag(&Vs[curV + ((u32)((n2 * 16 + lr) * 64 + kk2 * 32 + lk) ^ swz)]), oacc[n2], 0, 0, 0);
    }
    __builtin_amdgcn_s_setprio(0);
    __syncthreads();  // single barrier per tile (dbuf)
  }
  // epilogue: lsum per q=lr; sum the 4 g-groups, redistribute to rows 4g+r
  float s = lsum;
  s += __shfl_xor(s, 16);
  s += __shfl_xor(s, 32);
  float rl = 1.f / s;
  float rlv[4];
#pragma unroll
  for (int r = 0; r < 4; r++) rlv[r] = __shfl(rl, g * 4 + r);
#pragma unroll
  for (int n2 = 0; n2 < 8; n2++)
#pragma unroll
    for (int r = 0; r < 4; r++) {
      int row = m0 + w * 16 + g * 4 + r;
      AO[((size_t)(b * 2048 + row) * 16 + hh) * 128 + n2 * 16 + lr] = f2bf(oacc[n2][r] * rlv[r]);
    }
}

extern "C" void kernel_launch(void* const* d_in, const int* in_sizes, int n_in,
                              void* d_out, int out_size, void* d_ws, size_t ws_size,
                              hipStream_t stream) {
  const float* q_in  = (const float*)d_in[0];
  const float* kv_in = (const float*)d_in[1];
  const int*   qpos  = (const int*)d_in[2];
  const int*   kpos  = (const int*)d_in[3];
  const float* Wqd   = (const float*)d_in[4];
  const float* qnw   = (const float*)d_in[5];
  const float* Wqu   = (const float*)d_in[6];
  const float* Wkvd  = (const float*)d_in[7];
  const float* kvnw  = (const float*)d_in[8];
  const float* Wkvu  = (const float*)d_in[9];
  const float* Wo    = (const float*)d_in[10];
  float* out = (float*)d_out;
  char* ws = (char*)d_ws;
  size_t off = 0;
  auto alloc = [&](size_t bytes) -> void* {
    void* p = ws + off; off += (bytes + 255) & ~(size_t)255; return p;
  };
  u16*   WqdT   = (u16*)alloc(256ull * 1024 * 2);
  u16*   WquT   = (u16*)alloc(3072ull * 256 * 2);
  u16*   WkvdT  = (u16*)alloc(128ull * 1024 * 2);
  u16*   WkvuT  = (u16*)alloc(4096ull * 32 * 2);
  u16*   WoT    = (u16*)alloc(1024ull * 2048 * 2);
  float* ckvf   = (float*)alloc(4096ull * 128 * 4);
  u16*   ckvn   = (u16*)alloc(4096ull * 32 * 2);
  u16*   kropeb = (u16*)alloc(4096ull * 64 * 2);
  u16*   Ckv    = (u16*)alloc(4096ull * 4096 * 2);
  u16*   VTb    = (u16*)alloc(32ull * 128 * 2048 * 2);
  float* cq     = (float*)alloc(4096ull * 256 * 4);
  u16*   cqn    = (u16*)alloc(4096ull * 256 * 2);
  u16*   qproj  = (u16*)alloc(4096ull * 3072 * 2);
  u16*   AOb    = (u16*)alloc(4096ull * 2048 * 2);
  (void)in_sizes; (void)n_in; (void)out_size; (void)ws_size;

  // weight transposes (to bf16 (N,K), zero-padded)
  k_wtrans<<<dim3(8, 32), 256, 0, stream>>>(Wqd, WqdT, 1024, 256, 1024);
  k_wtrans<<<dim3(96, 8), 256, 0, stream>>>(Wqu, WquT, 256, 3072, 256);
  k_wtrans<<<dim3(4, 32), 256, 0, stream>>>(Wkvd, WkvdT, 1024, 80, 1024);
  k_wtrans<<<dim3(128, 1), 256, 0, stream>>>(Wkvu, WkvuT, 16, 4096, 32);
  k_wtrans<<<dim3(32, 64), 256, 0, stream>>>(Wo, WoT, 2048, 1024, 2048);
  // kv path (f32-A down-GEMM: cvt fused into staging; kv_up writes K->Ckv + V->VT directly)
  k_gemm64f<0><<<dim3(2, 64), 256, 0, stream>>>(kv_in, WkvdT, ckvf, 4096, 128, 1024);
  k_kvnorm<<<4096, 64, 0, stream>>>(ckvf, kvnw, kpos, ckvn, kropeb);
  k_gemm_kv<<<dim3(32, 32), 256, 0, stream>>>(ckvn, WkvuT, Ckv, VTb, 4096, 4096, 32);
  // q path
  k_gemm64f<0><<<dim3(4, 64), 256, 0, stream>>>(q_in, WqdT, cq, 4096, 256, 1024);
  k_rms256<<<1024, 256, 0, stream>>>(cq, qnw, cqn, 0.07216878364870322f);
  k_gemm<1><<<dim3(24, 32), 256, 0, stream>>>(cqn, WquT, qproj, 4096, 3072, 256);
  k_qrope<<<4096, 256, 0, stream>>>(qproj, qpos);
  // attention (512 threads: 8 waves x 16 q-rows, dbuf K/V, 1 barrier/tile)
  k_attn<<<512, 512, 0, stream>>>(qproj, Ckv, kropeb, VTb, AOb);
  // output projection
  k_gemmh<0><<<dim3(8, 64), 256, 0, stream>>>(AOb, WoT, out, 4096, 1024, 2048);
}

// Round 12
// 213.147 us; speedup vs baseline: 2.0248x; 1.2124x over previous
//
#include <hip/hip_runtime.h>

typedef unsigned short u16;
typedef unsigned int u32;
typedef u16 u16x4 __attribute__((ext_vector_type(4)));
typedef u16 u16x8 __attribute__((ext_vector_type(8)));
typedef u32 u32x4 __attribute__((ext_vector_type(4)));
typedef float f32x4 __attribute__((ext_vector_type(4)));
typedef __bf16 bf16x8 __attribute__((ext_vector_type(8)));
typedef __bf16 bf16x2 __attribute__((ext_vector_type(2)));

#define DEV static __device__ __forceinline__

DEV float bf2f(u16 u) { u32 v = ((u32)u) << 16; float f; __builtin_memcpy(&f, &v, 4); return f; }
DEV u16 f2bf(float f) { u32 v; __builtin_memcpy(&v, &f, 4); v += 0x7fffu + ((v >> 16) & 1u); return (u16)(v >> 16); }
DEV bf16x8 ld_frag(const u16* p) { u16x8 v = *(const u16x8*)p; return __builtin_bit_cast(bf16x8, v); }

#define LOG10000 9.210340372f

// ------- merged weight transposes: 5 matrices in one launch, 3328 blocks -------
__global__ __launch_bounds__(256) void k_wtrans5(
    const float* __restrict__ Wqd, const float* __restrict__ Wqu, const float* __restrict__ Wkvd,
    const float* __restrict__ Wkvu, const float* __restrict__ Wo,
    u16* __restrict__ WqdT, u16* __restrict__ WquT, u16* __restrict__ WkvdT,
    u16* __restrict__ WkvuT, u16* __restrict__ WoT) {
  __shared__ float tile[32][33];
  int id = blockIdx.x;
  const float* in; u16* out; int R, C, Rp, bx, by;
  if (id < 256)       { in = Wqd;  out = WqdT;  R = 1024; C = 256;  Rp = 1024; bx = id & 7;  by = id >> 3; }
  else if (id < 1024) { id -= 256;  in = Wqu;  out = WquT;  R = 256;  C = 3072; Rp = 256;  bx = id % 96; by = id / 96; }
  else if (id < 1152) { id -= 1024; in = Wkvd; out = WkvdT; R = 1024; C = 80;   Rp = 1024; bx = id & 3;  by = id >> 2; }
  else if (id < 1280) { id -= 1152; in = Wkvu; out = WkvuT; R = 16;   C = 4096; Rp = 32;   bx = id;      by = 0; }
  else                { id -= 1280; in = Wo;   out = WoT;   R = 2048; C = 1024; Rp = 2048; bx = id & 31; by = id >> 5; }
  int c0 = bx * 32, r0 = by * 32;
  int tx = threadIdx.x & 31, ty = threadIdx.x >> 5;
#pragma unroll
  for (int p = 0; p < 4; p++) {
    int r = r0 + ty + p * 8, c = c0 + tx;
    tile[ty + p * 8][tx] = (r < R && c < C) ? in[(size_t)r * C + c] : 0.f;
  }
  __syncthreads();
#pragma unroll
  for (int p = 0; p < 4; p++)
    out[(size_t)(c0 + ty + p * 8) * Rp + r0 + tx] = f2bf(tile[tx][ty + p * 8]);
}

// ------- 64x64-tile GEMM body, A in f32 (cvt fused): C(M,N)f32 = A(M,K)f32 * Bt(N,K)bf16 -------
DEV void gemm64f_body(int m0, int n0, const float* __restrict__ A, const u16* __restrict__ Bt,
                      float* __restrict__ C, int N, int K, int tid, u16* As, u16* Bs) {
  constexpr int LSTR = 40;
  const int l = tid & 63, w = tid >> 6;
  const int wr = (w >> 1) * 32, wc = (w & 1) * 32;
  const int lr = l & 15, lk = (l >> 4) * 8;
  const int sr = tid >> 2, sc = (tid & 3) * 8;
  f32x4 acc[2][2] = {};
  const float* pa0 = A + (size_t)(m0 + sr) * K + sc;
  const u16* pb0 = Bt + (size_t)(n0 + sr) * K + sc;
  f32x4 vaa = *(const f32x4*)pa0, vab = *(const f32x4*)(pa0 + 4);
  u16x8 vb0 = *(const u16x8*)pb0;
  for (int k0 = 0; k0 < K; k0 += 32) {
    u16x8 va0 = { f2bf(vaa[0]), f2bf(vaa[1]), f2bf(vaa[2]), f2bf(vaa[3]),
                  f2bf(vab[0]), f2bf(vab[1]), f2bf(vab[2]), f2bf(vab[3]) };
    *(u16x8*)&As[sr * LSTR + sc] = va0;
    *(u16x8*)&Bs[sr * LSTR + sc] = vb0;
    __syncthreads();
    if (k0 + 32 < K) {
      vaa = *(const f32x4*)(pa0 + k0 + 32);
      vab = *(const f32x4*)(pa0 + k0 + 36);
      vb0 = *(const u16x8*)(pb0 + k0 + 32);
    }
    bf16x8 af[2], bf[2];
#pragma unroll
    for (int i = 0; i < 2; i++) af[i] = ld_frag(&As[(wr + i * 16 + lr) * LSTR + lk]);
#pragma unroll
    for (int j = 0; j < 2; j++) bf[j] = ld_frag(&Bs[(wc + j * 16 + lr) * LSTR + lk]);
#pragma unroll
    for (int i = 0; i < 2; i++)
#pragma unroll
      for (int j = 0; j < 2; j++)
        acc[i][j] = __builtin_amdgcn_mfma_f32_16x16x32_bf16(af[i], bf[j], acc[i][j], 0, 0, 0);
    __syncthreads();
  }
#pragma unroll
  for (int i = 0; i < 2; i++)
#pragma unroll
    for (int j = 0; j < 2; j++) {
      int row = m0 + wr + i * 16 + (l >> 4) * 4;
      int col = n0 + wc + j * 16 + lr;
#pragma unroll
      for (int r = 0; r < 4; r++)
        C[(size_t)(row + r) * N + col] = acc[i][j][r];
    }
}

// ------- merged down-projections: kv_down (128 blocks) + q_down (256 blocks) in one launch -------
__global__ __launch_bounds__(256) void k_downs(const float* __restrict__ q_in, const float* __restrict__ kv_in,
                                               const u16* __restrict__ WqdT, const u16* __restrict__ WkvdT,
                                               float* __restrict__ cq, float* __restrict__ ckvf) {
  __shared__ u16 As[64 * 40], Bs[64 * 40];
  int id = blockIdx.x, tid = threadIdx.x;
  if (id < 128) {  // kv: grid (2,64)
    int swzb = (id & 7) * 16 + (id >> 3);
    gemm64f_body((swzb >> 1) * 64, (swzb & 1) * 64, kv_in, WkvdT, ckvf, 128, 1024, tid, As, Bs);
  } else {         // q: grid (4,64)
    int lin = id - 128;
    int swzb = (lin & 7) * 32 + (lin >> 3);
    gemm64f_body((swzb >> 2) * 64, (swzb & 3) * 64, q_in, WqdT, cq, 256, 1024, tid, As, Bs);
  }
}

// ------- merged norms: kv rms_norm(16)+rope (1024 blocks) + q rms_norm(256) (1024 blocks) -------
__global__ __launch_bounds__(256) void k_norms(const float* __restrict__ ckvf, const float* __restrict__ kvnw,
                                               const int* __restrict__ kpos, u16* __restrict__ ckvn,
                                               u16* __restrict__ kropeb,
                                               const float* __restrict__ cq, const float* __restrict__ qnw,
                                               u16* __restrict__ cqn, float scale) {
  int id = blockIdx.x, tid = threadIdx.x;
  int l = tid & 63;
  if (id < 1024) {
    int row = id * 4 + (tid >> 6);
    const float* x = ckvf + (size_t)row * 128;
    float v = (l < 16) ? x[l] : 0.f;
    float ss = v * v;
    ss += __shfl_xor(ss, 1); ss += __shfl_xor(ss, 2); ss += __shfl_xor(ss, 4); ss += __shfl_xor(ss, 8);
    if (l < 16) ckvn[(size_t)row * 32 + l] = f2bf(v * rsqrtf(ss * (1.f / 16.f) + 1e-7f) * kvnw[l]);
    if (l >= 16 && l < 32) ckvn[(size_t)row * 32 + l] = 0;
    if (l < 32) {
      float invf = __expf(-(LOG10000 / 32.f) * (float)l);
      float ang = (float)kpos[row] * invf;
      float c = cosf(ang), s = sinf(ang);
      float e = x[16 + 2 * l], o = x[17 + 2 * l];
      kropeb[(size_t)row * 64 + l]      = f2bf(e * c - o * s);
      kropeb[(size_t)row * 64 + l + 32] = f2bf(o * c + e * s);
    }
  } else {
    int row = (id - 1024) * 4 + (tid >> 6);
    const float* x = cq + (size_t)row * 256;
    f32x4 v = *(const f32x4*)(x + l * 4);
    float ss = v[0] * v[0] + v[1] * v[1] + v[2] * v[2] + v[3] * v[3];
#pragma unroll
    for (int m = 1; m < 64; m <<= 1) ss += __shfl_xor(ss, m);
    float rinv = rsqrtf(ss * (1.f / 256.f) + 1e-7f) * scale;
    const f32x4 wv = *(const f32x4*)(qnw + l * 4);
    u16x4 o = { f2bf(v[0] * rinv * wv[0]), f2bf(v[1] * rinv * wv[1]),
                f2bf(v[2] * rinv * wv[2]), f2bf(v[3] * rinv * wv[3]) };
    *(u16x4*)(cqn + (size_t)row * 256 + l * 4) = o;
  }
}

// ------- 128x128-tile GEMM body; MODE 0: bf16 C row-major, MODE 1: kv-split (Ckv + VT) -------
template <int MODE>
DEV void gemm128_body(int m0, int n0, const u16* __restrict__ A, const u16* __restrict__ Bt,
                      u16* __restrict__ C0, u16* __restrict__ C1, int N, int K, int tid,
                      u16* As, u16* Bs) {
  constexpr int LSTR = 40;
  const int l = tid & 63, w = tid >> 6;
  const int wr = (w >> 1) * 64, wc = (w & 1) * 64;
  const int lr = l & 15, lk = (l >> 4) * 8;
  const int sr = tid >> 2, sc = (tid & 3) * 8;
  f32x4 acc[4][4] = {};
  const u16* pa0 = A + (size_t)(m0 + sr) * K + sc;
  const u16* pa1 = A + (size_t)(m0 + 64 + sr) * K + sc;
  const u16* pb0 = Bt + (size_t)(n0 + sr) * K + sc;
  const u16* pb1 = Bt + (size_t)(n0 + 64 + sr) * K + sc;
  u16x8 va0 = *(const u16x8*)pa0, va1 = *(const u16x8*)pa1;
  u16x8 vb0 = *(const u16x8*)pb0, vb1 = *(const u16x8*)pb1;
  for (int k0 = 0; k0 < K; k0 += 32) {
    *(u16x8*)&As[sr * LSTR + sc] = va0;
    *(u16x8*)&As[(64 + sr) * LSTR + sc] = va1;
    *(u16x8*)&Bs[sr * LSTR + sc] = vb0;
    *(u16x8*)&Bs[(64 + sr) * LSTR + sc] = vb1;
    __syncthreads();
    if (k0 + 32 < K) {
      va0 = *(const u16x8*)(pa0 + k0 + 32);
      va1 = *(const u16x8*)(pa1 + k0 + 32);
      vb0 = *(const u16x8*)(pb0 + k0 + 32);
      vb1 = *(const u16x8*)(pb1 + k0 + 32);
    }
    bf16x8 af[4], bf[4];
#pragma unroll
    for (int i = 0; i < 4; i++) af[i] = ld_frag(&As[(wr + i * 16 + lr) * LSTR + lk]);
#pragma unroll
    for (int j = 0; j < 4; j++) bf[j] = ld_frag(&Bs[(wc + j * 16 + lr) * LSTR + lk]);
#pragma unroll
    for (int i = 0; i < 4; i++)
#pragma unroll
      for (int j = 0; j < 4; j++)
        acc[i][j] = __builtin_amdgcn_mfma_f32_16x16x32_bf16(af[i], bf[j], acc[i][j], 0, 0, 0);
    __syncthreads();
  }
  if (MODE == 0 || (n0 & 255) < 128) {  // plain bf16 C (or kv K-part)
#pragma unroll
    for (int i = 0; i < 4; i++)
#pragma unroll
      for (int j = 0; j < 4; j++) {
        int row = m0 + wr + i * 16 + (l >> 4) * 4;
        int col = n0 + wc + j * 16 + lr;
#pragma unroll
        for (int r = 0; r < 4; r++)
          C0[(size_t)(row + r) * N + col] = f2bf(acc[i][j][r]);
      }
  } else {  // kv V-part -> VT(BH,128,SKV), s-contiguous u16x4 stores
#pragma unroll
    for (int i = 0; i < 4; i++)
#pragma unroll
      for (int j = 0; j < 4; j++) {
        int row = m0 + wr + i * 16 + (l >> 4) * 4;
        int col = n0 + wc + j * 16 + lr;
        int bb = row >> 11, srow = row & 2047;
        int hh2 = col >> 8, d = col & 127;
        u16x4 pk = { f2bf(acc[i][j][0]), f2bf(acc[i][j][1]),
                     f2bf(acc[i][j][2]), f2bf(acc[i][j][3]) };
        *(u16x4*)&C1[((size_t)(bb * 16 + hh2) * 128 + d) * 2048 + srow] = pk;
      }
  }
}

// ------- merged up-projections: kv_up (1024 blocks, K->Ckv V->VT) + q_up (768 blocks) -------
__global__ __launch_bounds__(256) void k_ups(const u16* __restrict__ ckvn, const u16* __restrict__ WkvuT,
                                             u16* __restrict__ Ckv, u16* __restrict__ VTb,
                                             const u16* __restrict__ cqn, const u16* __restrict__ WquT,
                                             u16* __restrict__ qproj) {
  __shared__ u16 As[128 * 40], Bs[128 * 40];
  int id = blockIdx.x, tid = threadIdx.x;
  if (id < 1024) {  // kv_up: grid (32,32), K=32
    int swzb = (id & 7) * 128 + (id >> 3);
    gemm128_body<1>((swzb >> 5) * 128, (swzb & 31) * 128, ckvn, WkvuT, Ckv, VTb, 4096, 32, tid, As, Bs);
  } else {          // q_up: grid (24,32), K=256
    int lin = id - 1024;
    int swzb = (lin & 7) * 96 + (lin >> 3);
    gemm128_body<0>((swzb / 24) * 128, (swzb % 24) * 128, cqn, WquT, qproj, nullptr, 3072, 256, tid, As, Bs);
  }
}

// ---------------- GEMM 64(M)x128(N) tile, f32 out (out-projection) ----------------
__global__ __launch_bounds__(256) void k_gemmh(const u16* __restrict__ A, const u16* __restrict__ Bt,
                                               float* __restrict__ Cv, int M, int N, int K) {
  constexpr int LSTR = 40;
  __shared__ u16 As[64 * LSTR], Bs[128 * LSTR];
  const int tid = threadIdx.x, l = tid & 63, w = tid >> 6;
  const int nwg = gridDim.x * gridDim.y;
  const int lin = blockIdx.y * gridDim.x + blockIdx.x;
  const int swzb = (lin & 7) * (nwg >> 3) + (lin >> 3);
  const int m0 = (swzb / gridDim.x) * 64, n0 = (swzb % gridDim.x) * 128;
  const int wr = (w >> 1) * 32, wc = (w & 1) * 64;
  const int lr = l & 15, lk = (l >> 4) * 8;
  const int sr = tid >> 2, sc = (tid & 3) * 8;
  f32x4 acc[2][4] = {};
  const u16* pa0 = A + (size_t)(m0 + sr) * K + sc;
  const u16* pb0 = Bt + (size_t)(n0 + sr) * K + sc;
  const u16* pb1 = Bt + (size_t)(n0 + 64 + sr) * K + sc;
  u16x8 va0 = *(const u16x8*)pa0;
  u16x8 vb0 = *(const u16x8*)pb0, vb1 = *(const u16x8*)pb1;
  for (int k0 = 0; k0 < K; k0 += 32) {
    *(u16x8*)&As[sr * LSTR + sc] = va0;
    *(u16x8*)&Bs[sr * LSTR + sc] = vb0;
    *(u16x8*)&Bs[(64 + sr) * LSTR + sc] = vb1;
    __syncthreads();
    if (k0 + 32 < K) {
      va0 = *(const u16x8*)(pa0 + k0 + 32);
      vb0 = *(const u16x8*)(pb0 + k0 + 32);
      vb1 = *(const u16x8*)(pb1 + k0 + 32);
    }
    bf16x8 af[2], bf[4];
#pragma unroll
    for (int i = 0; i < 2; i++) af[i] = ld_frag(&As[(wr + i * 16 + lr) * LSTR + lk]);
#pragma unroll
    for (int j = 0; j < 4; j++) bf[j] = ld_frag(&Bs[(wc + j * 16 + lr) * LSTR + lk]);
#pragma unroll
    for (int i = 0; i < 2; i++)
#pragma unroll
      for (int j = 0; j < 4; j++)
        acc[i][j] = __builtin_amdgcn_mfma_f32_16x16x32_bf16(af[i], bf[j], acc[i][j], 0, 0, 0);
    __syncthreads();
  }
#pragma unroll
  for (int i = 0; i < 2; i++)
#pragma unroll
    for (int j = 0; j < 4; j++) {
      int row = m0 + wr + i * 16 + (l >> 4) * 4;
      int col = n0 + wc + j * 16 + lr;
#pragma unroll
      for (int r = 0; r < 4; r++)
        Cv[(size_t)(row + r) * N + col] = acc[i][j][r];
    }
}

// ---------------- in-place rope on qproj (B,SQ,H,192): dims 128..191 per head ----------------
__global__ __launch_bounds__(256) void k_qrope(u16* __restrict__ q, const int* __restrict__ pos) {
  __shared__ float cs[32], sn[32];
  int bs = blockIdx.x, tid = threadIdx.x;
  if (tid < 32) {
    float invf = __expf(-(LOG10000 / 32.f) * (float)tid);
    float ang = (float)pos[bs] * invf;
    cs[tid] = cosf(ang); sn[tid] = sinf(ang);
  }
  __syncthreads();
  u16* base = q + (size_t)bs * 3072;
  int h0 = tid >> 5, p0 = tid & 31;
  int h1 = h0 + 8, p1 = p0;
  u16* r0p = base + h0 * 192 + 128;
  u16* r1p = base + h1 * 192 + 128;
  float e0 = bf2f(r0p[2 * p0]), o0 = bf2f(r0p[2 * p0 + 1]);
  float e1 = bf2f(r1p[2 * p1]), o1 = bf2f(r1p[2 * p1 + 1]);
  __syncthreads();
  r0p[p0]      = f2bf(e0 * cs[p0] - o0 * sn[p0]);
  r0p[p0 + 32] = f2bf(o0 * cs[p0] + e0 * sn[p0]);
  r1p[p1]      = f2bf(e1 * cs[p1] - o1 * sn[p1]);
  r1p[p1 + 32] = f2bf(o1 * cs[p1] + e1 * sn[p1]);
}

// ---- fused attention v12 (= R10 single-buffer, best measured) + v_cvt_pk P-packing ----
__global__ __launch_bounds__(512, 2) void k_attn(const u16* __restrict__ Qp, const u16* __restrict__ Ckv,
                                                 const u16* __restrict__ kropeb, const u16* __restrict__ VT,
                                                 u16* __restrict__ AO) {
  __shared__ u16 Ks[64 * 192];   // 24KB, XOR-swizzled
  __shared__ u16 Vs[128 * 64];   // 16KB, d-major, XOR-swizzled
  const int tid = threadIdx.x, l = tid & 63, w = tid >> 6;
  const int lr = l & 15, g = l >> 4, lk = g * 8;
  const int bid = blockIdx.x, bh = bid & 31, qt = bid >> 5;  // bh%8 fixes XCD for K/V L2 reuse
  const int b = bh >> 4, hh = bh & 15;
  const int m0 = qt * 128;
  const u32 swz = (u32)(lr & 7) << 3;

  // Q fragments (B-operand): wave w owns q-rows m0 + w*16 .. +15
  bf16x8 qa[6];
  {
    const u16* qrow = Qp + (size_t)(b * 2048 + m0 + w * 16 + lr) * 3072 + hh * 192;
#pragma unroll
    for (int kk = 0; kk < 6; kk++) qa[kk] = ld_frag(qrow + kk * 32 + lk);
  }

  // staging: K = 64x192 (3 chunks/thread @512), V = 128x64 d-major (2 chunks/thread)
  const u16* kptr[3]; int kstep[3]; u32 klds[3];
#pragma unroll
  for (int p = 0; p < 3; p++) {
    int c2 = tid + p * 512;
    int r = c2 / 24, cc = c2 - r * 24;
    klds[p] = (u32)(r * 192 + cc * 8) ^ ((u32)(r & 7) << 3);
    if (cc < 16) { kptr[p] = Ckv + ((size_t)(b * 2048 + r)) * 4096 + hh * 256 + cc * 8; kstep[p] = 64 * 4096; }
    else         { kptr[p] = kropeb + ((size_t)(b * 2048 + r)) * 64 + (cc - 16) * 8;    kstep[p] = 64 * 64; }
  }
  const u16* vptr[2]; u32 vlds[2];
#pragma unroll
  for (int p = 0; p < 2; p++) {
    int c2 = tid + p * 512;
    int d = c2 >> 3, cc = c2 & 7;
    vlds[p] = (u32)(d * 64 + cc * 8) ^ ((u32)(d & 7) << 3);
    vptr[p] = VT + ((size_t)bh * 128 + d) * 2048 + cc * 8;
  }
  u16x8 kreg[3], vreg[2];
#pragma unroll
  for (int p = 0; p < 3; p++) { kreg[p] = *(const u16x8*)kptr[p]; kptr[p] += kstep[p]; }
#pragma unroll
  for (int p = 0; p < 2; p++) { vreg[p] = *(const u16x8*)vptr[p]; vptr[p] += 64; }

  f32x4 oacc[8] = {};
  float lsum = 0.f;
  const int srcA = lr + ((l & 16) << 1);
  const int srcB = srcA + 16;
  const bool hi = (l & 32) != 0;

  for (int t = 0; t < 32; t++) {
    // write staged regs -> LDS (vmcnt wait auto-inserted for in-flight prefetch)
#pragma unroll
    for (int p = 0; p < 3; p++) *(u16x8*)&Ks[klds[p]] = kreg[p];
#pragma unroll
    for (int p = 0; p < 2; p++) *(u16x8*)&Vs[vlds[p]] = vreg[p];
    __syncthreads();
    if (t + 1 < 32) {  // issue next-tile loads; latency hides under compute below
#pragma unroll
      for (int p = 0; p < 3; p++) { kreg[p] = *(const u16x8*)kptr[p]; kptr[p] += kstep[p]; }
#pragma unroll
      for (int p = 0; p < 2; p++) { vreg[p] = *(const u16x8*)vptr[p]; vptr[p] += 64; }
    }
    // S^T = K * Q^T: lane holds q=lr, kv=16n+4g+r
    f32x4 sacc[4] = {};
    __builtin_amdgcn_s_setprio(1);
#pragma unroll
    for (int n = 0; n < 4; n++)
#pragma unroll
      for (int kk = 0; kk < 6; kk++)
        sacc[n] = __builtin_amdgcn_mfma_f32_16x16x32_bf16(
            ld_frag(&Ks[(u32)((n * 16 + lr) * 192 + kk * 32 + lk) ^ swz]), qa[kk], sacc[n], 0, 0, 0);
    __builtin_amdgcn_s_setprio(0);
    // P = exp(S): per-lane (one q-row); pack via native casts -> v_cvt_pk_bf16_f32
    u32 pw[4][2];
#pragma unroll
    for (int n = 0; n < 4; n++) {
      float p0 = __expf(sacc[n][0]), p1 = __expf(sacc[n][1]),
            p2 = __expf(sacc[n][2]), p3 = __expf(sacc[n][3]);
      lsum += (p0 + p1) + (p2 + p3);
      bf16x2 a01 = { (__bf16)p0, (__bf16)p1 };
      bf16x2 a23 = { (__bf16)p2, (__bf16)p3 };
      pw[n][0] = __builtin_bit_cast(u32, a01);
      pw[n][1] = __builtin_bit_cast(u32, a23);
    }
    // redistribute P to PV A-fragment layout (16 bpermutes, no LDS buffer)
    u32 pa32[2][4];
#pragma unroll
    for (int kk2 = 0; kk2 < 2; kk2++) {
      u32 t0a = __shfl(pw[2 * kk2][0], srcA), t1a = __shfl(pw[2 * kk2 + 1][0], srcA);
      u32 t0b = __shfl(pw[2 * kk2][1], srcA), t1b = __shfl(pw[2 * kk2 + 1][1], srcA);
      u32 t0c = __shfl(pw[2 * kk2][0], srcB), t1c = __shfl(pw[2 * kk2 + 1][0], srcB);
      u32 t0d = __shfl(pw[2 * kk2][1], srcB), t1d = __shfl(pw[2 * kk2 + 1][1], srcB);
      pa32[kk2][0] = hi ? t1a : t0a;
      pa32[kk2][1] = hi ? t1b : t0b;
      pa32[kk2][2] = hi ? t1c : t0c;
      pa32[kk2][3] = hi ? t1d : t0d;
    }
    // O += P * V
    __builtin_amdgcn_s_setprio(1);
#pragma unroll
    for (int kk2 = 0; kk2 < 2; kk2++) {
      u32x4 pv = { pa32[kk2][0], pa32[kk2][1], pa32[kk2][2], pa32[kk2][3] };
      bf16x8 paf = __builtin_bit_cast(bf16x8, pv);
#pragma unroll
      for (int n2 = 0; n2 < 8; n2++)
        oacc[n2] = __builtin_amdgcn_mfma_f32_16x16x32_bf16(
            paf, ld_frag(&Vs[(u32)((n2 * 16 + lr) * 64 + kk2 * 32 + lk) ^ swz]), oacc[n2], 0, 0, 0);
    }
    __builtin_amdgcn_s_setprio(0);
    __syncthreads();
  }
  // epilogue: lsum per q=lr; sum the 4 g-groups, redistribute to rows 4g+r
  float s = lsum;
  s += __shfl_xor(s, 16);
  s += __shfl_xor(s, 32);
  float rl = 1.f / s;
  float rlv[4];
#pragma unroll
  for (int r = 0; r < 4; r++) rlv[r] = __shfl(rl, g * 4 + r);
#pragma unroll
  for (int n2 = 0; n2 < 8; n2++)
#pragma unroll
    for (int r = 0; r < 4; r++) {
      int row = m0 + w * 16 + g * 4 + r;
      AO[((size_t)(b * 2048 + row) * 16 + hh) * 128 + n2 * 16 + lr] = f2bf(oacc[n2][r] * rlv[r]);
    }
}

extern "C" void kernel_launch(void* const* d_in, const int* in_sizes, int n_in,
                              void* d_out, int out_size, void* d_ws, size_t ws_size,
                              hipStream_t stream) {
  const float* q_in  = (const float*)d_in[0];
  const float* kv_in = (const float*)d_in[1];
  const int*   qpos  = (const int*)d_in[2];
  const int*   kpos  = (const int*)d_in[3];
  const float* Wqd   = (const float*)d_in[4];
  const float* qnw   = (const float*)d_in[5];
  const float* Wqu   = (const float*)d_in[6];
  const float* Wkvd  = (const float*)d_in[7];
  const float* kvnw  = (const float*)d_in[8];
  const float* Wkvu  = (const float*)d_in[9];
  const float* Wo    = (const float*)d_in[10];
  float* out = (float*)d_out;
  char* ws = (char*)d_ws;
  size_t off = 0;
  auto alloc = [&](size_t bytes) -> void* {
    void* p = ws + off; off += (bytes + 255) & ~(size_t)255; return p;
  };
  u16*   WqdT   = (u16*)alloc(256ull * 1024 * 2);
  u16*   WquT   = (u16*)alloc(3072ull * 256 * 2);
  u16*   WkvdT  = (u16*)alloc(128ull * 1024 * 2);
  u16*   WkvuT  = (u16*)alloc(4096ull * 32 * 2);
  u16*   WoT    = (u16*)alloc(1024ull * 2048 * 2);
  float* ckvf   = (float*)alloc(4096ull * 128 * 4);
  u16*   ckvn   = (u16*)alloc(4096ull * 32 * 2);
  u16*   kropeb = (u16*)alloc(4096ull * 64 * 2);
  u16*   Ckv    = (u16*)alloc(4096ull * 4096 * 2);
  u16*   VTb    = (u16*)alloc(32ull * 128 * 2048 * 2);
  float* cq     = (float*)alloc(4096ull * 256 * 4);
  u16*   cqn    = (u16*)alloc(4096ull * 256 * 2);
  u16*   qproj  = (u16*)alloc(4096ull * 3072 * 2);
  u16*   AOb    = (u16*)alloc(4096ull * 2048 * 2);
  (void)in_sizes; (void)n_in; (void)out_size; (void)ws_size;

  // 1: all 5 weight transposes in one launch
  k_wtrans5<<<3328, 256, 0, stream>>>(Wqd, Wqu, Wkvd, Wkvu, Wo, WqdT, WquT, WkvdT, WkvuT, WoT);
  // 2: both down-projections (f32-A, fused cvt) in one launch
  k_downs<<<384, 256, 0, stream>>>(q_in, kv_in, WqdT, WkvdT, cq, ckvf);
  // 3: both norms (kv rms+rope, q rms with 1/sqrt(192) folded) in one launch
  k_norms<<<2048, 256, 0, stream>>>(ckvf, kvnw, kpos, ckvn, kropeb, cq, qnw, cqn, 0.07216878364870322f);
  // 4: both up-projections (kv_up: K->Ckv + V->VT; q_up) in one launch
  k_ups<<<1792, 256, 0, stream>>>(ckvn, WkvuT, Ckv, VTb, cqn, WquT, qproj);
  // 5: q rope (in-place on qproj)
  k_qrope<<<4096, 256, 0, stream>>>(qproj, qpos);
  // 6: attention (512 threads: 8 waves x 16 q-rows, single-buffer LDS, in-reg P)
  k_attn<<<512, 512, 0, stream>>>(qproj, Ckv, kropeb, VTb, AOb);
  // 7: output projection
  k_gemmh<<<dim3(8, 64), 256, 0, stream>>>(AOb, WoT, out, 4096, 1024, 2048);
}